// Round 1
// baseline (18732.474 us; speedup 1.0000x reference)
//
#include <hip/hip_runtime.h>
#include <math.h>

// ---------------- constants ----------------
#define BB   2
#define CIO  64
#define TT   4096
#define S0   2048      // local level seq len
#define W0   512
#define HDN  8
#define SM   1025      // mid seq len (with prepended token)
#define W1   1024
#define HMID 16
#define DH   64
#define WIN  128
#define NW   16        // S0 / WIN
#define MAPD 1024

// ---------------- device helpers ----------------
__device__ __forceinline__ float gelu_tanh(float x) {
    float x3 = x * x * x;
    return 0.5f * x * (1.f + tanhf(0.7978845608028654f * (x + 0.044715f * x3)));
}

// ---------------- GEMM: C = (res?) + A[MxK] @ W[KxN] ----------------
// K % 16 == 0, N % 128 == 0 (all shapes in this model satisfy this).
__global__ __launch_bounds__(256) void gemm_f32(
    const float* __restrict__ A, const float* __restrict__ Wt,
    const float* __restrict__ res, float* __restrict__ C,
    int M, int N, int K) {
    __shared__ float As[16][136];
    __shared__ float Bs[16][128];
    const int tid = threadIdx.x;
    const int bm = blockIdx.y * 128, bn = blockIdx.x * 128;
    const int tr = (tid >> 4) << 3;
    const int tc = (tid & 15) << 3;
    float acc[8][8];
#pragma unroll
    for (int i = 0; i < 8; ++i)
#pragma unroll
        for (int j = 0; j < 8; ++j) acc[i][j] = 0.f;
    for (int k0 = 0; k0 < K; k0 += 16) {
#pragma unroll
        for (int i = 0; i < 8; ++i) {
            int e = tid + i * 256;
            int m = e >> 4, kk = e & 15;
            As[kk][m] = (bm + m < M) ? A[(size_t)(bm + m) * K + k0 + kk] : 0.f;
        }
#pragma unroll
        for (int i = 0; i < 8; ++i) {
            int e = tid + i * 256;
            int kk = e >> 7, n = e & 127;
            Bs[kk][n] = Wt[(size_t)(k0 + kk) * N + bn + n];
        }
        __syncthreads();
#pragma unroll
        for (int kk = 0; kk < 16; ++kk) {
            float a[8], b[8];
#pragma unroll
            for (int i = 0; i < 8; ++i) a[i] = As[kk][tr + i];
#pragma unroll
            for (int j = 0; j < 8; ++j) b[j] = Bs[kk][tc + j];
#pragma unroll
            for (int i = 0; i < 8; ++i)
#pragma unroll
                for (int j = 0; j < 8; ++j) acc[i][j] = fmaf(a[i], b[j], acc[i][j]);
        }
        __syncthreads();
    }
#pragma unroll
    for (int i = 0; i < 8; ++i) {
        int m = bm + tr + i;
        if (m >= M) break;
        size_t row = (size_t)m * N;
#pragma unroll
        for (int j = 0; j < 8; ++j) {
            int n = bn + tc + j;
            C[row + n] = (res ? res[row + n] : 0.f) + acc[i][j];
        }
    }
}

// ---------------- norms ----------------
// y = x * (sadd + scale[row/rows_per_group][c]) * rsqrt(mean(x^2)+1e-6)
__global__ __launch_bounds__(256) void rmsnorm_k(
    const float* __restrict__ X, const float* __restrict__ scale,
    float* __restrict__ Y, int C, int rows_per_group, float sadd) {
    int row = blockIdx.x, tid = threadIdx.x;
    const float* x = X + (size_t)row * C;
    float v[8];
    int cnt = C >> 8;
    float ss = 0.f;
    for (int i = 0; i < cnt; ++i) { v[i] = x[tid + (i << 8)]; ss += v[i] * v[i]; }
    __shared__ float red[256];
    red[tid] = ss; __syncthreads();
    for (int s2 = 128; s2; s2 >>= 1) { if (tid < s2) red[tid] += red[tid + s2]; __syncthreads(); }
    float inv = rsqrtf(red[0] / (float)C + 1e-6f);
    const float* sc = scale + (size_t)(row / rows_per_group) * C;
    float* y = Y + (size_t)row * C;
    for (int i = 0; i < cnt; ++i) {
        int c = tid + (i << 8);
        y[c] = v[i] * (sadd + sc[c]) * inv;
    }
}

__global__ __launch_bounds__(256) void layernorm_k(
    const float* __restrict__ X, const float* __restrict__ g,
    const float* __restrict__ bta, float* __restrict__ Y, int C) {
    int row = blockIdx.x, tid = threadIdx.x;
    const float* x = X + (size_t)row * C;
    float v[8];
    int cnt = C >> 8;
    float s = 0.f;
    for (int i = 0; i < cnt; ++i) { v[i] = x[tid + (i << 8)]; s += v[i]; }
    __shared__ float red[256];
    red[tid] = s; __syncthreads();
    for (int s2 = 128; s2; s2 >>= 1) { if (tid < s2) red[tid] += red[tid + s2]; __syncthreads(); }
    float m = red[0] / (float)C;
    __syncthreads();
    float s2s = 0.f;
    for (int i = 0; i < cnt; ++i) { float d = v[i] - m; s2s += d * d; }
    red[tid] = s2s; __syncthreads();
    for (int s2 = 128; s2; s2 >>= 1) { if (tid < s2) red[tid] += red[tid + s2]; __syncthreads(); }
    float inv = rsqrtf(red[0] / (float)C + 1e-5f);
    float* y = Y + (size_t)row * C;
    for (int i = 0; i < cnt; ++i) {
        int c = tid + (i << 8);
        y[c] = (v[i] - m) * inv * g[c] + bta[c];
    }
}

// ---------------- GLU (mode 0: gelu-tanh, 1: silu) ----------------
__global__ __launch_bounds__(256) void glu_k(
    const float* __restrict__ U, float* __restrict__ Yo,
    size_t total, int F, int mode) {
    size_t gidx = (size_t)blockIdx.x * 256 + threadIdx.x;
    if (gidx >= total) return;
    size_t r = gidx / (size_t)F;
    int c = (int)(gidx - r * F);
    const float* u = U + r * (size_t)(2 * F);
    float a = u[c], gg = u[F + c];
    float act = (mode == 0) ? gelu_tanh(gg) : gg / (1.f + expf(-gg));
    Yo[gidx] = a * act;
}

// ---------------- QKV split + RoPE (+ q scale 1/8) ----------------
__global__ __launch_bounds__(256) void qkv_split_rope(
    const float* __restrict__ QKV, float* __restrict__ Qo,
    float* __restrict__ Ko, float* __restrict__ Vo, int S, int H) {
    int g = blockIdx.x * 256 + threadIdx.x;
    int total = BB * S * H * 32;
    if (g >= total) return;
    int i = g & 31;
    int tix = g >> 5;
    int h = tix % H; tix /= H;
    int s = tix % S; int b = tix / S;
    int C = H * 64;
    const float* base = QKV + (size_t)(b * S + s) * 3 * C + h * 64;
    float q1 = base[i], q2 = base[32 + i];
    float k1 = base[C + i], k2 = base[C + 32 + i];
    float v1 = base[2 * C + i], v2 = base[2 * C + 32 + i];
    // inv_freq = 10000^(-i/32) = exp(-i * ln(1e4)/32)
    float inv = expf(-(float)i * 0.28782313662425575f);
    float ang = (float)s * inv;
    float sn, cs;
    sincosf(ang, &sn, &cs);
    size_t o = ((size_t)(b * H + h) * S + s) * 64 + i;
    Qo[o]      = (q1 * cs - q2 * sn) * 0.125f;
    Qo[o + 32] = (q2 * cs + q1 * sn) * 0.125f;
    Ko[o]      = k1 * cs - k2 * sn;
    Ko[o + 32] = k2 * cs + k1 * sn;
    Vo[o]      = v1;
    Vo[o + 32] = v2;
}

// ---------------- local attention QK: scores[bhn][128][384] ----------------
__global__ __launch_bounds__(256) void local_qk(
    const float* __restrict__ Q, const float* __restrict__ K,
    float* __restrict__ S) {
    __shared__ float Qs[128][65];
    __shared__ float Ks[64][65];
    int blk = blockIdx.x;
    int n = blk & (NW - 1);
    int h = (blk / NW) % HDN;
    int b = blk / (NW * HDN);
    const int tid = threadIdx.x;
    const float* Qbase = Q + ((size_t)(b * HDN + h) * S0 + n * WIN) * 64;
    for (int e = tid; e < 128 * 64; e += 256) {
        int q = e >> 6, d = e & 63;
        Qs[q][d] = Qbase[q * 64 + d];
    }
    const int tr = (tid >> 4) << 3;
    const int tc = (tid & 15) << 2;
    float* Srow = S + (size_t)blk * 128 * 384;
    for (int c = 0; c < 6; ++c) {
        __syncthreads();
        for (int e = tid; e < 64 * 64; e += 256) {
            int kk = e >> 6, d = e & 63;
            int kg = (n - 1) * WIN + c * 64 + kk;
            Ks[kk][d] = (kg >= 0 && kg < S0)
                ? K[((size_t)(b * HDN + h) * S0 + kg) * 64 + d] : 0.f;
        }
        __syncthreads();
        float acc[8][4];
#pragma unroll
        for (int i = 0; i < 8; ++i)
#pragma unroll
            for (int j = 0; j < 4; ++j) acc[i][j] = 0.f;
#pragma unroll 4
        for (int d = 0; d < 64; ++d) {
            float a[8], bb[4];
#pragma unroll
            for (int i = 0; i < 8; ++i) a[i] = Qs[tr + i][d];
#pragma unroll
            for (int j = 0; j < 4; ++j) bb[j] = Ks[tc + j][d];
#pragma unroll
            for (int i = 0; i < 8; ++i)
#pragma unroll
                for (int j = 0; j < 4; ++j) acc[i][j] = fmaf(a[i], bb[j], acc[i][j]);
        }
#pragma unroll
        for (int i = 0; i < 8; ++i)
#pragma unroll
            for (int j = 0; j < 4; ++j)
                Srow[(tr + i) * 384 + c * 64 + tc + j] = acc[i][j];
    }
}

// ---------------- local attention PV: O merged [B*S0, 512] ----------------
__global__ __launch_bounds__(256) void local_pv(
    const float* __restrict__ P, const float* __restrict__ V,
    float* __restrict__ O) {
    __shared__ float Ps[128][65];
    __shared__ float Vs[64][65];
    int blk = blockIdx.x;
    int n = blk & (NW - 1);
    int h = (blk / NW) % HDN;
    int b = blk / (NW * HDN);
    const int tid = threadIdx.x;
    const int tr = (tid >> 4) << 3;
    const int tc = (tid & 15) << 2;
    const float* Pbase = P + (size_t)blk * 128 * 384;
    float acc[8][4];
#pragma unroll
    for (int i = 0; i < 8; ++i)
#pragma unroll
        for (int j = 0; j < 4; ++j) acc[i][j] = 0.f;
    for (int c = 0; c < 6; ++c) {
        __syncthreads();
        for (int e = tid; e < 128 * 64; e += 256) {
            int q = e >> 6, kk = e & 63;
            Ps[q][kk] = Pbase[q * 384 + c * 64 + kk];
        }
        for (int e = tid; e < 64 * 64; e += 256) {
            int kk = e >> 6, d = e & 63;
            int kg = (n - 1) * WIN + c * 64 + kk;
            Vs[kk][d] = (kg >= 0 && kg < S0)
                ? V[((size_t)(b * HDN + h) * S0 + kg) * 64 + d] : 0.f;
        }
        __syncthreads();
#pragma unroll 4
        for (int kk = 0; kk < 64; ++kk) {
            float a[8], bb[4];
#pragma unroll
            for (int i = 0; i < 8; ++i) a[i] = Ps[tr + i][kk];
#pragma unroll
            for (int j = 0; j < 4; ++j) bb[j] = Vs[kk][tc + j];
#pragma unroll
            for (int i = 0; i < 8; ++i)
#pragma unroll
                for (int j = 0; j < 4; ++j) acc[i][j] = fmaf(a[i], bb[j], acc[i][j]);
        }
    }
#pragma unroll
    for (int i = 0; i < 8; ++i)
#pragma unroll
        for (int j = 0; j < 4; ++j)
            O[((size_t)b * S0 + n * WIN + tr + i) * W0 + h * 64 + tc + j] = acc[i][j];
}

// ---------------- mid attention QK (per batch): S[h][1025][1025] ----------------
__global__ __launch_bounds__(256) void mid_qk(
    const float* __restrict__ Q, const float* __restrict__ K,
    float* __restrict__ S, int b) {
    __shared__ float Qs[128][65];
    __shared__ float Ks[64][65];
    int qt = blockIdx.x;        // 0..8
    int h = blockIdx.y;         // 0..15
    int q0 = qt * 128;
    const int tid = threadIdx.x;
    for (int e = tid; e < 128 * 64; e += 256) {
        int q = q0 + (e >> 6), d = e & 63;
        Qs[e >> 6][d] = (q < SM)
            ? Q[((size_t)(b * HMID + h) * SM + q) * 64 + d] : 0.f;
    }
    const int tr = (tid >> 4) << 3;
    const int tc = (tid & 15) << 2;
    for (int c = 0; c < 17; ++c) {
        __syncthreads();
        for (int e = tid; e < 64 * 64; e += 256) {
            int kk = e >> 6, d = e & 63;
            int kg = c * 64 + kk;
            Ks[kk][d] = (kg < SM)
                ? K[((size_t)(b * HMID + h) * SM + kg) * 64 + d] : 0.f;
        }
        __syncthreads();
        float acc[8][4];
#pragma unroll
        for (int i = 0; i < 8; ++i)
#pragma unroll
            for (int j = 0; j < 4; ++j) acc[i][j] = 0.f;
#pragma unroll 4
        for (int d = 0; d < 64; ++d) {
            float a[8], bb[4];
#pragma unroll
            for (int i = 0; i < 8; ++i) a[i] = Qs[tr + i][d];
#pragma unroll
            for (int j = 0; j < 4; ++j) bb[j] = Ks[tc + j][d];
#pragma unroll
            for (int i = 0; i < 8; ++i)
#pragma unroll
                for (int j = 0; j < 4; ++j) acc[i][j] = fmaf(a[i], bb[j], acc[i][j]);
        }
#pragma unroll
        for (int i = 0; i < 8; ++i) {
            int q = q0 + tr + i;
            if (q >= SM) break;
#pragma unroll
            for (int j = 0; j < 4; ++j) {
                int k = c * 64 + tc + j;
                if (k < SM) S[((size_t)h * SM + q) * SM + k] = acc[i][j];
            }
        }
    }
}

// ---------------- mid attention PV (per batch): O[b*SM + q][1024] ----------------
__global__ __launch_bounds__(256) void mid_pv(
    const float* __restrict__ P, const float* __restrict__ V,
    float* __restrict__ O, int b) {
    __shared__ float Ps[128][65];
    __shared__ float Vs[64][65];
    int qt = blockIdx.x;
    int h = blockIdx.y;
    int q0 = qt * 128;
    const int tid = threadIdx.x;
    const int tr = (tid >> 4) << 3;
    const int tc = (tid & 15) << 2;
    float acc[8][4];
#pragma unroll
    for (int i = 0; i < 8; ++i)
#pragma unroll
        for (int j = 0; j < 4; ++j) acc[i][j] = 0.f;
    for (int c = 0; c < 17; ++c) {
        __syncthreads();
        for (int e = tid; e < 128 * 64; e += 256) {
            int q = q0 + (e >> 6);
            int col = c * 64 + (e & 63);
            Ps[e >> 6][e & 63] = (q < SM && col < SM)
                ? P[((size_t)h * SM + q) * SM + col] : 0.f;
        }
        for (int e = tid; e < 64 * 64; e += 256) {
            int kk = e >> 6, d = e & 63;
            int kg = c * 64 + kk;
            Vs[kk][d] = (kg < SM)
                ? V[((size_t)(b * HMID + h) * SM + kg) * 64 + d] : 0.f;
        }
        __syncthreads();
#pragma unroll 4
        for (int kk = 0; kk < 64; ++kk) {
            float a[8], bb[4];
#pragma unroll
            for (int i = 0; i < 8; ++i) a[i] = Ps[tr + i][kk];
#pragma unroll
            for (int j = 0; j < 4; ++j) bb[j] = Vs[kk][tc + j];
#pragma unroll
            for (int i = 0; i < 8; ++i)
#pragma unroll
                for (int j = 0; j < 4; ++j) acc[i][j] = fmaf(a[i], bb[j], acc[i][j]);
        }
    }
#pragma unroll
    for (int i = 0; i < 8; ++i) {
        int q = q0 + tr + i;
        if (q >= SM) break;
#pragma unroll
        for (int j = 0; j < 4; ++j)
            O[((size_t)b * SM + q) * W1 + h * 64 + tc + j] = acc[i][j];
    }
}

// ---------------- masked softmax, one wave per row ----------------
// mode 0: full; mode 1: local window mask (rows grouped 128/window)
__global__ __launch_bounds__(256) void softmax_rows(
    float* __restrict__ S, int rows, int width, int mode) {
    int wid = threadIdx.x >> 6, lane = threadIdx.x & 63;
    int row = blockIdx.x * 4 + wid;
    if (row >= rows) return;
    float* p = S + (size_t)row * width;
    int lo = 0, hi = width;
    if (mode == 1) {
        int n = (row >> 7) & (NW - 1);
        lo = (n == 0) ? WIN : 0;
        hi = (n == NW - 1) ? 2 * WIN : 3 * WIN;
    }
    float mx = -3.4e38f;
    for (int i = lane; i < width; i += 64)
        if (i >= lo && i < hi) mx = fmaxf(mx, p[i]);
#pragma unroll
    for (int o = 32; o; o >>= 1) mx = fmaxf(mx, __shfl_xor(mx, o));
    float sum = 0.f;
    for (int i = lane; i < width; i += 64) {
        float e = (i >= lo && i < hi) ? expf(p[i] - mx) : 0.f;
        p[i] = e;
        sum += e;
    }
#pragma unroll
    for (int o = 32; o; o >>= 1) sum += __shfl_xor(sum, o);
    float r = 1.f / sum;
    for (int i = lane; i < width; i += 64) p[i] *= r;
}

// ---------------- small glue kernels ----------------
__global__ __launch_bounds__(256) void patch_in_gather(
    const float* __restrict__ x, float* __restrict__ out) {
    int g = blockIdx.x * 256 + threadIdx.x;
    if (g >= BB * S0 * 128) return;
    int k = g & 127;
    int n = (g >> 7) & (S0 - 1);
    int b = g >> 18;   // /(128*2048)
    out[g] = x[(size_t)b * CIO * TT + (size_t)(k >> 1) * TT + 2 * n + (k & 1)];
}

__global__ __launch_bounds__(256) void time_embed(
    const float* __restrict__ t, const float* __restrict__ tw,
    float* __restrict__ te) {
    int g = blockIdx.x * 256 + threadIdx.x;
    if (g >= BB * MAPD) return;
    int b = g / MAPD, j = g % MAPD;
    float w = tw[(j < 512) ? j : j - 512];
    float ang = 6.283185307179586f * t[b] * w;
    te[g] = (j < 512) ? cosf(ang) : sinf(ang);
}

__global__ __launch_bounds__(256) void token_merge_gather(
    const float* __restrict__ A, float* __restrict__ out) {
    int g = blockIdx.x * 256 + threadIdx.x;
    if (g >= BB * 1024 * 1024) return;
    int k = g & 1023;
    int n = (g >> 10) & 1023;
    int b = g >> 20;
    out[g] = A[((size_t)b * S0 + 2 * n + (k & 1)) * W0 + (k >> 1)];
}

__global__ __launch_bounds__(256) void concat_mid(
    const float* __restrict__ pre, const float* __restrict__ Dsrc,
    float* __restrict__ Cm) {
    int g = blockIdx.x * 256 + threadIdx.x;
    if (g >= BB * SM * W1) return;
    int c = g & 1023;
    int row = g >> 10;
    int b = row / SM, r = row % SM;
    Cm[g] = (r == 0) ? pre[b * W1 + c]
                     : Dsrc[((size_t)b * 1024 + r - 1) * W1 + c];
}

__global__ __launch_bounds__(256) void gather_drop(
    const float* __restrict__ Dsrc, float* __restrict__ out) {
    int g = blockIdx.x * 256 + threadIdx.x;
    if (g >= BB * 1024 * W1) return;
    int c = g & 1023;
    int n = (g >> 10) & 1023;
    int b = g >> 20;
    out[g] = Dsrc[((size_t)b * SM + 1 + n) * W1 + c];
}

__global__ __launch_bounds__(256) void split_scatter_lerp(
    const float* __restrict__ y, const float* __restrict__ skip,
    const float* __restrict__ fac, float* __restrict__ xo) {
    int g = blockIdx.x * 256 + threadIdx.x;
    if (g >= BB * S0 * W0) return;
    int c = g & 511;
    int tk = (g >> 9) & (S0 - 1);
    int b = g >> 20;
    float yv = y[((size_t)b * 1024 + (tk >> 1)) * W1 + (c * 2 + (tk & 1))];
    float sk = skip[g];
    xo[g] = sk + fac[0] * (yv - sk);
}

__global__ __launch_bounds__(256) void patch_out_scatter(
    const float* __restrict__ y, float* __restrict__ out) {
    int g = blockIdx.x * 256 + threadIdx.x;
    if (g >= BB * CIO * TT) return;
    int tk = g & (TT - 1);
    int c = (g >> 12) & 63;
    int b = g >> 18;
    out[g] = y[((size_t)b * S0 + (tk >> 1)) * 128 + (c * 2 + (tk & 1))];
}

// ---------------- host orchestration ----------------
static inline void gemm(const float* A, const float* Wt, const float* res,
                        float* C, int M, int N, int K, hipStream_t st) {
    dim3 g(N / 128, (M + 127) / 128);
    gemm_f32<<<g, 256, 0, st>>>(A, Wt, res, C, M, N, K);
}

extern "C" void kernel_launch(void* const* d_in, const int* in_sizes, int n_in,
                              void* d_out, int out_size, void* d_ws, size_t ws_size,
                              hipStream_t stream) {
    const float* x          = (const float*)d_in[0];
    const float* t          = (const float*)d_in[1];
    const float* time_w     = (const float*)d_in[2];
    const float* time_in_w  = (const float*)d_in[3];
    const float* map_in_s   = (const float*)d_in[4];
    const float* map_norm_s = (const float*)d_in[5];
    const float* map_up_w   = (const float*)d_in[6];
    const float* map_down_w = (const float*)d_in[7];
    const float* map_out_s  = (const float*)d_in[8];
    const float* patch_in_w = (const float*)d_in[9];
    const float* dn_anorm_w = (const float*)d_in[10];
    const float* dn_qkv_w   = (const float*)d_in[11];
    const float* dn_o_w     = (const float*)d_in[12];
    const float* dn_fnorm_w = (const float*)d_in[13];
    const float* dn_ff1_w   = (const float*)d_in[14];
    const float* dn_ff2_w   = (const float*)d_in[15];
    const float* merge_w    = (const float*)d_in[16];
    const float* mid_map_w  = (const float*)d_in[17];
    const float* mid_pin_w  = (const float*)d_in[18];
    const float* mid_pout_w = (const float*)d_in[19];
    const float* mid_ln1_g  = (const float*)d_in[20];
    const float* mid_ln1_b  = (const float*)d_in[21];
    const float* mid_qkv_w  = (const float*)d_in[22];
    const float* mid_o_w    = (const float*)d_in[23];
    const float* mid_ln2_g  = (const float*)d_in[24];
    const float* mid_ln2_b  = (const float*)d_in[25];
    const float* mid_ff1_w  = (const float*)d_in[26];
    const float* mid_ff2_w  = (const float*)d_in[27];
    const float* mid_fn_g   = (const float*)d_in[28];
    const float* mid_fn_b   = (const float*)d_in[29];
    const float* split_w    = (const float*)d_in[30];
    const float* split_fac  = (const float*)d_in[31];
    const float* up_anorm_w = (const float*)d_in[32];
    const float* up_qkv_w   = (const float*)d_in[33];
    const float* up_o_w     = (const float*)d_in[34];
    const float* up_fnorm_w = (const float*)d_in[35];
    const float* up_ff1_w   = (const float*)d_in[36];
    const float* up_ff2_w   = (const float*)d_in[37];
    const float* out_norm_s = (const float*)d_in[38];
    const float* patch_out_w= (const float*)d_in[39];

    float* Wp = (float*)d_ws;
    size_t off = 0;
    auto alloc = [&](size_t n) { float* p = Wp + off; off += n; return p; };
    float* A   = alloc((size_t)4096 * 512);
    float* Bsk = alloc((size_t)4096 * 512);
    float* Cm  = alloc((size_t)2050 * 1024);
    float* D   = alloc((size_t)2050 * 1024);
    float* E   = alloc((size_t)16 * SM * SM);   // 16.81M floats; also qkv/ffu/scores
    float* Fq  = alloc((size_t)2099200);
    float* Fk  = alloc((size_t)2099200);
    float* Fv  = alloc((size_t)2099200);
    float* Hb  = alloc((size_t)8396800);
    float* Sma = alloc((size_t)32768);
    (void)ws_size; (void)in_sizes; (void)n_in; (void)out_size;

    float* te   = Sma;
    float* temb = Sma + 2048;
    float* mapx = Sma + 4096;
    float* maph = Sma + 6144;
    float* mapu = Sma + 8192;    // 2x2048
    float* mapg = Sma + 12288;   // 2x1024
    float* cond = Sma + 14336;
    float* sA   = Sma + 16384;
    float* sF   = Sma + 17408;
    float* pre  = Sma + 18432;

    // ---- patch in ----
    patch_in_gather<<<(BB * S0 * 128 + 255) / 256, 256, 0, stream>>>(x, E);
    gemm(E, patch_in_w, nullptr, A, 4096, 512, 128, stream);

    // ---- time embedding + mapping ----
    time_embed<<<(BB * MAPD + 255) / 256, 256, 0, stream>>>(t, time_w, te);
    gemm(te, time_in_w, nullptr, temb, 2, 1024, 1024, stream);
    rmsnorm_k<<<2, 256, 0, stream>>>(temb, map_in_s, mapx, 1024, 2, 0.f);
    for (int l = 0; l < 2; ++l) {
        rmsnorm_k<<<2, 256, 0, stream>>>(mapx, map_norm_s + (size_t)l * 1024, maph, 1024, 2, 0.f);
        gemm(maph, map_up_w + (size_t)l * 1024 * 2048, nullptr, mapu, 2, 2048, 1024, stream);
        glu_k<<<(2 * 1024 + 255) / 256, 256, 0, stream>>>(mapu, mapg, 2 * 1024, 1024, 0);
        gemm(mapg, map_down_w + (size_t)l * 1024 * 1024, mapx, mapx, 2, 1024, 1024, stream);
    }
    rmsnorm_k<<<2, 256, 0, stream>>>(mapx, map_out_s, cond, 1024, 2, 0.f);

    // ---- local level (shared for down/up) ----
    auto run_local = [&](const float* anorm, const float* qkvw, const float* ow,
                         const float* fnorm, const float* ff1, const float* ff2) {
        for (int l = 0; l < 2; ++l) {
            gemm(cond, anorm + (size_t)l * 1024 * 512, nullptr, sA, 2, 512, 1024, stream);
            rmsnorm_k<<<4096, 256, 0, stream>>>(A, sA, D, 512, 2048, 1.f);
            gemm(D, qkvw + (size_t)l * 512 * 1536, nullptr, E, 4096, 1536, 512, stream);
            qkv_split_rope<<<(BB * S0 * HDN * 32 + 255) / 256, 256, 0, stream>>>(E, Fq, Fk, Fv, S0, HDN);
            local_qk<<<BB * HDN * NW, 256, 0, stream>>>(Fq, Fk, E);
            softmax_rows<<<(BB * HDN * NW * 128 + 3) / 4, 256, 0, stream>>>(E, BB * HDN * NW * 128, 384, 1);
            local_pv<<<BB * HDN * NW, 256, 0, stream>>>(E, Fv, D);
            gemm(D, ow + (size_t)l * 512 * 512, A, A, 4096, 512, 512, stream);
            gemm(cond, fnorm + (size_t)l * 1024 * 512, nullptr, sF, 2, 512, 1024, stream);
            rmsnorm_k<<<4096, 256, 0, stream>>>(A, sF, D, 512, 2048, 1.f);
            gemm(D, ff1 + (size_t)l * 512 * 2048, nullptr, E, 4096, 2048, 512, stream);
            glu_k<<<(4096 * 1024 + 255) / 256, 256, 0, stream>>>(E, Hb, (size_t)4096 * 1024, 1024, 0);
            gemm(Hb, ff2 + (size_t)l * 1024 * 512, A, A, 4096, 512, 1024, stream);
        }
    };
    run_local(dn_anorm_w, dn_qkv_w, dn_o_w, dn_fnorm_w, dn_ff1_w, dn_ff2_w);

    // ---- skip save, merge, mid prep ----
    hipMemcpyAsync(Bsk, A, (size_t)4096 * 512 * 4, hipMemcpyDeviceToDevice, stream);
    token_merge_gather<<<(BB * 1024 * 1024 + 255) / 256, 256, 0, stream>>>(A, Hb);
    gemm(Hb, merge_w, nullptr, E, 2048, 1024, 1024, stream);
    gemm(E, mid_pin_w, nullptr, D, 2048, 1024, 1024, stream);
    gemm(cond, mid_map_w, nullptr, pre, 2, 1024, 1024, stream);
    concat_mid<<<(BB * SM * W1 + 255) / 256, 256, 0, stream>>>(pre, D, Cm);

    // ---- mid level ----
    for (int l = 0; l < 4; ++l) {
        layernorm_k<<<2050, 256, 0, stream>>>(Cm, mid_ln1_g + (size_t)l * 1024,
                                              mid_ln1_b + (size_t)l * 1024, D, 1024);
        gemm(D, mid_qkv_w + (size_t)l * 1024 * 3072, nullptr, E, 2050, 3072, 1024, stream);
        qkv_split_rope<<<(BB * SM * HMID * 32 + 255) / 256, 256, 0, stream>>>(E, Fq, Fk, Fv, SM, HMID);
        for (int b = 0; b < 2; ++b) {
            mid_qk<<<dim3(9, HMID), 256, 0, stream>>>(Fq, Fk, E, b);
            softmax_rows<<<(HMID * SM + 3) / 4, 256, 0, stream>>>(E, HMID * SM, SM, 0);
            mid_pv<<<dim3(9, HMID), 256, 0, stream>>>(E, Fv, D, b);
        }
        gemm(D, mid_o_w + (size_t)l * 1024 * 1024, Cm, Cm, 2050, 1024, 1024, stream);
        layernorm_k<<<2050, 256, 0, stream>>>(Cm, mid_ln2_g + (size_t)l * 1024,
                                              mid_ln2_b + (size_t)l * 1024, D, 1024);
        gemm(D, mid_ff1_w + (size_t)l * 1024 * 8192, nullptr, E, 2050, 8192, 1024, stream);
        glu_k<<<((size_t)2050 * 4096 + 255) / 256, 256, 0, stream>>>(E, Hb, (size_t)2050 * 4096, 4096, 1);
        gemm(Hb, mid_ff2_w + (size_t)l * 4096 * 1024, Cm, Cm, 2050, 1024, 4096, stream);
    }
    layernorm_k<<<2050, 256, 0, stream>>>(Cm, mid_fn_g, mid_fn_b, Cm, 1024);

    // ---- pout + token split + lerp skip ----
    gemm(Cm, mid_pout_w, nullptr, D, 2050, 1024, 1024, stream);
    gather_drop<<<(BB * 1024 * W1 + 255) / 256, 256, 0, stream>>>(D, Hb);
    gemm(Hb, split_w, nullptr, E, 2048, 1024, 1024, stream);
    split_scatter_lerp<<<(BB * S0 * W0 + 255) / 256, 256, 0, stream>>>(E, Bsk, split_fac, A);

    // ---- up level ----
    run_local(up_anorm_w, up_qkv_w, up_o_w, up_fnorm_w, up_ff1_w, up_ff2_w);

    // ---- out ----
    rmsnorm_k<<<4096, 256, 0, stream>>>(A, out_norm_s, D, 512, 4096, 0.f);
    gemm(D, patch_out_w, nullptr, E, 4096, 128, 512, stream);
    patch_out_scatter<<<(BB * CIO * TT + 255) / 256, 256, 0, stream>>>(E, (float*)d_out);
}

// Round 2
// 9257.948 us; speedup vs baseline: 2.0234x; 2.0234x over previous
//
#include <hip/hip_runtime.h>
#include <math.h>

// ---------------- constants ----------------
#define BB   2
#define CIO  64
#define TT   4096
#define S0   2048      // local level seq len
#define W0   512
#define HDN  8
#define SM   1025      // mid seq len (with prepended token)
#define W1   1024
#define HMID 16
#define WIN  128
#define NW   16        // S0 / WIN
#define MAPD 1024

typedef _Float16 f16;
typedef _Float16 half8 __attribute__((ext_vector_type(8)));
typedef _Float16 half2v __attribute__((ext_vector_type(2)));
typedef float floatx4 __attribute__((ext_vector_type(4)));

// ---------------- device helpers ----------------
__device__ __forceinline__ float gelu_tanh(float x) {
    float x3 = x * x * x;
    return 0.5f * x * (1.f + tanhf(0.7978845608028654f * (x + 0.044715f * x3)));
}
__device__ __forceinline__ float ldf(const float* p) { return *p; }
__device__ __forceinline__ float ldf(const f16* p)   { return (float)*p; }
__device__ __forceinline__ void stf(float* p, float v) { *p = v; }
__device__ __forceinline__ void stf(f16* p, float v)   { *p = (f16)v; }

// ---------------- weight transpose-cast: W[K][N] f32 -> Wt[N][K] f16 ------
// K, N multiples of 64.
__global__ __launch_bounds__(256) void wcast(
    const float* __restrict__ W, f16* __restrict__ Wt, int K, int N) {
    __shared__ float T[64][65];
    const int n0 = blockIdx.x * 64, k0 = blockIdx.y * 64;
    const int tid = threadIdx.x;
    for (int e = tid; e < 4096; e += 256) {
        int r = e >> 6, c = e & 63;
        T[r][c] = W[(size_t)(k0 + r) * N + n0 + c];
    }
    __syncthreads();
    for (int e = tid; e < 2048; e += 256) {
        int r = e >> 5, c2 = (e & 31) * 2;
        half2v p;
        p[0] = (f16)T[c2][r];
        p[1] = (f16)T[c2 + 1][r];
        *(half2v*)(Wt + (size_t)(n0 + r) * K + k0 + c2) = p;
    }
}

// ---------------- MFMA GEMM: C = (res?) + A[MxK]f16 @ Bt[NxK]f16^T --------
// K%32==0, N%128==0. Output fp32 (+optional fp32 residual) or f16.
template<bool HOUT>
__global__ __launch_bounds__(256) void gemm_h(
    const f16* __restrict__ A, const f16* __restrict__ Bt,
    const float* __restrict__ res, void* __restrict__ Cv,
    int M, int N, int K) {
    __shared__ __align__(16) f16 As[128 * 32];
    __shared__ __align__(16) f16 Bs[128 * 32];
    const int tid = threadIdx.x;
    const int wv = tid >> 6, ln = tid & 63;
    const int bm = blockIdx.y * 128, bn = blockIdx.x * 128;
    const int wr = (wv >> 1) * 64, wc = (wv & 1) * 64;
    floatx4 acc[4][4];
#pragma unroll
    for (int m = 0; m < 4; ++m)
#pragma unroll
        for (int n = 0; n < 4; ++n) acc[m][n] = (floatx4)0.f;
    const int r = ln & 15, kc = (ln >> 4) * 8;
    for (int k0 = 0; k0 < K; k0 += 32) {
#pragma unroll
        for (int i = 0; i < 2; ++i) {
            int off = i * 4096 + wv * 1024 + ln * 16;  // byte offset in 8KB tile
            int row = off >> 6, kb = (off & 63) >> 1;
            int gr = bm + row; gr = gr < M ? gr : M - 1;
            f16* gp = const_cast<f16*>(A) + (size_t)gr * K + k0 + kb;
            __builtin_amdgcn_global_load_lds(
                (__attribute__((address_space(1))) void*)gp,
                (__attribute__((address_space(3))) void*)(As + i * 2048 + wv * 512),
                16, 0, 0);
            f16* gq = const_cast<f16*>(Bt) + (size_t)(bn + row) * K + k0 + kb;
            __builtin_amdgcn_global_load_lds(
                (__attribute__((address_space(1))) void*)gq,
                (__attribute__((address_space(3))) void*)(Bs + i * 2048 + wv * 512),
                16, 0, 0);
        }
        __syncthreads();
        half8 af[4], bf[4];
#pragma unroll
        for (int m = 0; m < 4; ++m)
            af[m] = *(const half8*)(As + (wr + m * 16 + r) * 32 + kc);
#pragma unroll
        for (int n = 0; n < 4; ++n)
            bf[n] = *(const half8*)(Bs + (wc + n * 16 + r) * 32 + kc);
#pragma unroll
        for (int m = 0; m < 4; ++m)
#pragma unroll
            for (int n = 0; n < 4; ++n)
                acc[m][n] = __builtin_amdgcn_mfma_f32_16x16x32_f16(af[m], bf[n], acc[m][n], 0, 0, 0);
        __syncthreads();
    }
    float* Cf = (float*)Cv;
    f16*   Ch = (f16*)Cv;
#pragma unroll
    for (int m = 0; m < 4; ++m) {
        int rbase = bm + wr + m * 16 + ((ln >> 4) << 2);
#pragma unroll
        for (int j = 0; j < 4; ++j) {
            int row = rbase + j;
            if (row < M) {
                size_t ro = (size_t)row * N;
#pragma unroll
                for (int n = 0; n < 4; ++n) {
                    int col = bn + wc + n * 16 + (ln & 15);
                    float v = acc[m][n][j];
                    if (HOUT) Ch[ro + col] = (f16)v;
                    else      Cf[ro + col] = v + (res ? res[ro + col] : 0.f);
                }
            }
        }
    }
}

// ---------------- small fp32 GEMM (M=2 cond/mapping paths) ----------------
__global__ __launch_bounds__(256) void gemm_f32(
    const float* __restrict__ A, const float* __restrict__ Wt,
    const float* __restrict__ res, float* __restrict__ C,
    int M, int N, int K) {
    __shared__ float As[16][136];
    __shared__ float Bs[16][128];
    const int tid = threadIdx.x;
    const int bm = blockIdx.y * 128, bn = blockIdx.x * 128;
    const int tr = (tid >> 4) << 3;
    const int tc = (tid & 15) << 3;
    float acc[8][8];
#pragma unroll
    for (int i = 0; i < 8; ++i)
#pragma unroll
        for (int j = 0; j < 8; ++j) acc[i][j] = 0.f;
    for (int k0 = 0; k0 < K; k0 += 16) {
#pragma unroll
        for (int i = 0; i < 8; ++i) {
            int e = tid + i * 256;
            int m = e >> 4, kk = e & 15;
            As[kk][m] = (bm + m < M) ? A[(size_t)(bm + m) * K + k0 + kk] : 0.f;
        }
#pragma unroll
        for (int i = 0; i < 8; ++i) {
            int e = tid + i * 256;
            int kk = e >> 7, n = e & 127;
            Bs[kk][n] = Wt[(size_t)(k0 + kk) * N + bn + n];
        }
        __syncthreads();
#pragma unroll
        for (int kk = 0; kk < 16; ++kk) {
            float a[8], b[8];
#pragma unroll
            for (int i = 0; i < 8; ++i) a[i] = As[kk][tr + i];
#pragma unroll
            for (int j = 0; j < 8; ++j) b[j] = Bs[kk][tc + j];
#pragma unroll
            for (int i = 0; i < 8; ++i)
#pragma unroll
                for (int j = 0; j < 8; ++j) acc[i][j] = fmaf(a[i], b[j], acc[i][j]);
        }
        __syncthreads();
    }
#pragma unroll
    for (int i = 0; i < 8; ++i) {
        int m = bm + tr + i;
        if (m >= M) break;
        size_t row = (size_t)m * N;
#pragma unroll
        for (int j = 0; j < 8; ++j) {
            int n = bn + tc + j;
            C[row + n] = (res ? res[row + n] : 0.f) + acc[i][j];
        }
    }
}

// ---------------- norms ----------------
template<typename TO>
__global__ __launch_bounds__(256) void rmsnorm_k(
    const float* __restrict__ X, const float* __restrict__ scale,
    TO* __restrict__ Y, int C, int rows_per_group, float sadd) {
    int row = blockIdx.x, tid = threadIdx.x;
    const float* x = X + (size_t)row * C;
    float v[8];
    int cnt = C >> 8;
    float ss = 0.f;
    for (int i = 0; i < cnt; ++i) { v[i] = x[tid + (i << 8)]; ss += v[i] * v[i]; }
    __shared__ float red[256];
    red[tid] = ss; __syncthreads();
    for (int s2 = 128; s2; s2 >>= 1) { if (tid < s2) red[tid] += red[tid + s2]; __syncthreads(); }
    float inv = rsqrtf(red[0] / (float)C + 1e-6f);
    const float* sc = scale + (size_t)(row / rows_per_group) * C;
    TO* y = Y + (size_t)row * C;
    for (int i = 0; i < cnt; ++i) {
        int c = tid + (i << 8);
        stf(&y[c], v[i] * (sadd + sc[c]) * inv);
    }
}

__global__ __launch_bounds__(256) void layernorm_k(
    const float* __restrict__ X, const float* __restrict__ g,
    const float* __restrict__ bta, f16* __restrict__ Y, int C) {
    int row = blockIdx.x, tid = threadIdx.x;
    const float* x = X + (size_t)row * C;
    float v[8];
    int cnt = C >> 8;
    float s = 0.f;
    for (int i = 0; i < cnt; ++i) { v[i] = x[tid + (i << 8)]; s += v[i]; }
    __shared__ float red[256];
    red[tid] = s; __syncthreads();
    for (int s2 = 128; s2; s2 >>= 1) { if (tid < s2) red[tid] += red[tid + s2]; __syncthreads(); }
    float m = red[0] / (float)C;
    __syncthreads();
    float s2s = 0.f;
    for (int i = 0; i < cnt; ++i) { float d = v[i] - m; s2s += d * d; }
    red[tid] = s2s; __syncthreads();
    for (int s2 = 128; s2; s2 >>= 1) { if (tid < s2) red[tid] += red[tid + s2]; __syncthreads(); }
    float inv = rsqrtf(red[0] / (float)C + 1e-5f);
    f16* y = Y + (size_t)row * C;
    for (int i = 0; i < cnt; ++i) {
        int c = tid + (i << 8);
        y[c] = (f16)((v[i] - m) * inv * g[c] + bta[c]);
    }
}

// ---------------- GLU (mode 0: gelu-tanh, 1: silu) ----------------
template<typename TI, typename TO>
__global__ __launch_bounds__(256) void glu_k(
    const TI* __restrict__ U, TO* __restrict__ Yo,
    size_t total, int F, int mode) {
    size_t gidx = (size_t)blockIdx.x * 256 + threadIdx.x;
    if (gidx >= total) return;
    size_t r = gidx / (size_t)F;
    int c = (int)(gidx - r * F);
    const TI* u = U + r * (size_t)(2 * F);
    float a = ldf(&u[c]), gg = ldf(&u[F + c]);
    float act = (mode == 0) ? gelu_tanh(gg) : gg / (1.f + expf(-gg));
    stf(&Yo[gidx], a * act);
}

// ---------------- QKV split + RoPE (+ q scale 1/8) ----------------
__global__ __launch_bounds__(256) void qkv_split_rope(
    const float* __restrict__ QKV, float* __restrict__ Qo,
    float* __restrict__ Ko, float* __restrict__ Vo, int S, int H) {
    int g = blockIdx.x * 256 + threadIdx.x;
    int total = BB * S * H * 32;
    if (g >= total) return;
    int i = g & 31;
    int tix = g >> 5;
    int h = tix % H; tix /= H;
    int s = tix % S; int b = tix / S;
    int C = H * 64;
    const float* base = QKV + (size_t)(b * S + s) * 3 * C + h * 64;
    float q1 = base[i], q2 = base[32 + i];
    float k1 = base[C + i], k2 = base[C + 32 + i];
    float v1 = base[2 * C + i], v2 = base[2 * C + 32 + i];
    float inv = expf(-(float)i * 0.28782313662425575f);
    float ang = (float)s * inv;
    float sn, cs;
    sincosf(ang, &sn, &cs);
    size_t o = ((size_t)(b * H + h) * S + s) * 64 + i;
    Qo[o]      = (q1 * cs - q2 * sn) * 0.125f;
    Qo[o + 32] = (q2 * cs + q1 * sn) * 0.125f;
    Ko[o]      = k1 * cs - k2 * sn;
    Ko[o + 32] = k2 * cs + k1 * sn;
    Vo[o]      = v1;
    Vo[o + 32] = v2;
}

// ---------------- local attention QK: scores[bhn][128][384] ----------------
__global__ __launch_bounds__(256) void local_qk(
    const float* __restrict__ Q, const float* __restrict__ K,
    float* __restrict__ S) {
    __shared__ float Qs[128][65];
    __shared__ float Ks[64][65];
    int blk = blockIdx.x;
    int n = blk & (NW - 1);
    int h = (blk / NW) % HDN;
    int b = blk / (NW * HDN);
    const int tid = threadIdx.x;
    const float* Qbase = Q + ((size_t)(b * HDN + h) * S0 + n * WIN) * 64;
    for (int e = tid; e < 128 * 64; e += 256) {
        int q = e >> 6, d = e & 63;
        Qs[q][d] = Qbase[q * 64 + d];
    }
    const int tr = (tid >> 4) << 3;
    const int tc = (tid & 15) << 2;
    float* Srow = S + (size_t)blk * 128 * 384;
    for (int c = 0; c < 6; ++c) {
        __syncthreads();
        for (int e = tid; e < 64 * 64; e += 256) {
            int kk = e >> 6, d = e & 63;
            int kg = (n - 1) * WIN + c * 64 + kk;
            Ks[kk][d] = (kg >= 0 && kg < S0)
                ? K[((size_t)(b * HDN + h) * S0 + kg) * 64 + d] : 0.f;
        }
        __syncthreads();
        float acc[8][4];
#pragma unroll
        for (int i = 0; i < 8; ++i)
#pragma unroll
            for (int j = 0; j < 4; ++j) acc[i][j] = 0.f;
#pragma unroll 4
        for (int d = 0; d < 64; ++d) {
            float a[8], bb[4];
#pragma unroll
            for (int i = 0; i < 8; ++i) a[i] = Qs[tr + i][d];
#pragma unroll
            for (int j = 0; j < 4; ++j) bb[j] = Ks[tc + j][d];
#pragma unroll
            for (int i = 0; i < 8; ++i)
#pragma unroll
                for (int j = 0; j < 4; ++j) acc[i][j] = fmaf(a[i], bb[j], acc[i][j]);
        }
#pragma unroll
        for (int i = 0; i < 8; ++i)
#pragma unroll
            for (int j = 0; j < 4; ++j)
                Srow[(tr + i) * 384 + c * 64 + tc + j] = acc[i][j];
    }
}

// ---------------- local attention PV: O merged [B*S0, 512] f16 -------------
__global__ __launch_bounds__(256) void local_pv(
    const float* __restrict__ P, const float* __restrict__ V,
    f16* __restrict__ O) {
    __shared__ float Ps[128][65];
    __shared__ float Vs[64][65];
    int blk = blockIdx.x;
    int n = blk & (NW - 1);
    int h = (blk / NW) % HDN;
    int b = blk / (NW * HDN);
    const int tid = threadIdx.x;
    const int tr = (tid >> 4) << 3;
    const int tc = (tid & 15) << 2;
    const float* Pbase = P + (size_t)blk * 128 * 384;
    float acc[8][4];
#pragma unroll
    for (int i = 0; i < 8; ++i)
#pragma unroll
        for (int j = 0; j < 4; ++j) acc[i][j] = 0.f;
    for (int c = 0; c < 6; ++c) {
        __syncthreads();
        for (int e = tid; e < 128 * 64; e += 256) {
            int q = e >> 6, kk = e & 63;
            Ps[q][kk] = Pbase[q * 384 + c * 64 + kk];
        }
        for (int e = tid; e < 64 * 64; e += 256) {
            int kk = e >> 6, d = e & 63;
            int kg = (n - 1) * WIN + c * 64 + kk;
            Vs[kk][d] = (kg >= 0 && kg < S0)
                ? V[((size_t)(b * HDN + h) * S0 + kg) * 64 + d] : 0.f;
        }
        __syncthreads();
#pragma unroll 4
        for (int kk = 0; kk < 64; ++kk) {
            float a[8], bb[4];
#pragma unroll
            for (int i = 0; i < 8; ++i) a[i] = Ps[tr + i][kk];
#pragma unroll
            for (int j = 0; j < 4; ++j) bb[j] = Vs[kk][tc + j];
#pragma unroll
            for (int i = 0; i < 8; ++i)
#pragma unroll
                for (int j = 0; j < 4; ++j) acc[i][j] = fmaf(a[i], bb[j], acc[i][j]);
        }
    }
#pragma unroll
    for (int i = 0; i < 8; ++i)
#pragma unroll
        for (int j = 0; j < 4; ++j)
            O[((size_t)b * S0 + n * WIN + tr + i) * W0 + h * 64 + tc + j] = (f16)acc[i][j];
}

// ---------------- mid attention QK (per batch): S[h][1025][1025] -----------
__global__ __launch_bounds__(256) void mid_qk(
    const float* __restrict__ Q, const float* __restrict__ K,
    float* __restrict__ S, int b) {
    __shared__ float Qs[128][65];
    __shared__ float Ks[64][65];
    int qt = blockIdx.x;
    int h = blockIdx.y;
    int q0 = qt * 128;
    const int tid = threadIdx.x;
    for (int e = tid; e < 128 * 64; e += 256) {
        int q = q0 + (e >> 6), d = e & 63;
        Qs[e >> 6][d] = (q < SM)
            ? Q[((size_t)(b * HMID + h) * SM + q) * 64 + d] : 0.f;
    }
    const int tr = (tid >> 4) << 3;
    const int tc = (tid & 15) << 2;
    for (int c = 0; c < 17; ++c) {
        __syncthreads();
        for (int e = tid; e < 64 * 64; e += 256) {
            int kk = e >> 6, d = e & 63;
            int kg = c * 64 + kk;
            Ks[kk][d] = (kg < SM)
                ? K[((size_t)(b * HMID + h) * SM + kg) * 64 + d] : 0.f;
        }
        __syncthreads();
        float acc[8][4];
#pragma unroll
        for (int i = 0; i < 8; ++i)
#pragma unroll
            for (int j = 0; j < 4; ++j) acc[i][j] = 0.f;
#pragma unroll 4
        for (int d = 0; d < 64; ++d) {
            float a[8], bb[4];
#pragma unroll
            for (int i = 0; i < 8; ++i) a[i] = Qs[tr + i][d];
#pragma unroll
            for (int j = 0; j < 4; ++j) bb[j] = Ks[tc + j][d];
#pragma unroll
            for (int i = 0; i < 8; ++i)
#pragma unroll
                for (int j = 0; j < 4; ++j) acc[i][j] = fmaf(a[i], bb[j], acc[i][j]);
        }
#pragma unroll
        for (int i = 0; i < 8; ++i) {
            int q = q0 + tr + i;
            if (q >= SM) break;
#pragma unroll
            for (int j = 0; j < 4; ++j) {
                int k = c * 64 + tc + j;
                if (k < SM) S[((size_t)h * SM + q) * SM + k] = acc[i][j];
            }
        }
    }
}

// ---------------- mid attention PV (per batch): O[b*SM + q][1024] f16 ------
__global__ __launch_bounds__(256) void mid_pv(
    const float* __restrict__ P, const float* __restrict__ V,
    f16* __restrict__ O, int b) {
    __shared__ float Ps[128][65];
    __shared__ float Vs[64][65];
    int qt = blockIdx.x;
    int h = blockIdx.y;
    int q0 = qt * 128;
    const int tid = threadIdx.x;
    const int tr = (tid >> 4) << 3;
    const int tc = (tid & 15) << 2;
    float acc[8][4];
#pragma unroll
    for (int i = 0; i < 8; ++i)
#pragma unroll
        for (int j = 0; j < 4; ++j) acc[i][j] = 0.f;
    for (int c = 0; c < 17; ++c) {
        __syncthreads();
        for (int e = tid; e < 128 * 64; e += 256) {
            int q = q0 + (e >> 6);
            int col = c * 64 + (e & 63);
            Ps[e >> 6][e & 63] = (q < SM && col < SM)
                ? P[((size_t)h * SM + q) * SM + col] : 0.f;
        }
        for (int e = tid; e < 64 * 64; e += 256) {
            int kk = e >> 6, d = e & 63;
            int kg = c * 64 + kk;
            Vs[kk][d] = (kg < SM)
                ? V[((size_t)(b * HMID + h) * SM + kg) * 64 + d] : 0.f;
        }
        __syncthreads();
#pragma unroll 4
        for (int kk = 0; kk < 64; ++kk) {
            float a[8], bb[4];
#pragma unroll
            for (int i = 0; i < 8; ++i) a[i] = Ps[tr + i][kk];
#pragma unroll
            for (int j = 0; j < 4; ++j) bb[j] = Vs[kk][tc + j];
#pragma unroll
            for (int i = 0; i < 8; ++i)
#pragma unroll
                for (int j = 0; j < 4; ++j) acc[i][j] = fmaf(a[i], bb[j], acc[i][j]);
        }
    }
#pragma unroll
    for (int i = 0; i < 8; ++i) {
        int q = q0 + tr + i;
        if (q >= SM) break;
#pragma unroll
        for (int j = 0; j < 4; ++j)
            O[((size_t)b * SM + q) * W1 + h * 64 + tc + j] = (f16)acc[i][j];
    }
}

// ---------------- masked softmax, one wave per row ----------------
__global__ __launch_bounds__(256) void softmax_rows(
    float* __restrict__ S, int rows, int width, int mode) {
    int wid = threadIdx.x >> 6, lane = threadIdx.x & 63;
    int row = blockIdx.x * 4 + wid;
    if (row >= rows) return;
    float* p = S + (size_t)row * width;
    int lo = 0, hi = width;
    if (mode == 1) {
        int n = (row >> 7) & (NW - 1);
        lo = (n == 0) ? WIN : 0;
        hi = (n == NW - 1) ? 2 * WIN : 3 * WIN;
    }
    float mx = -3.4e38f;
    for (int i = lane; i < width; i += 64)
        if (i >= lo && i < hi) mx = fmaxf(mx, p[i]);
#pragma unroll
    for (int o = 32; o; o >>= 1) mx = fmaxf(mx, __shfl_xor(mx, o));
    float sum = 0.f;
    for (int i = lane; i < width; i += 64) {
        float e = (i >= lo && i < hi) ? expf(p[i] - mx) : 0.f;
        p[i] = e;
        sum += e;
    }
#pragma unroll
    for (int o = 32; o; o >>= 1) sum += __shfl_xor(sum, o);
    float r = 1.f / sum;
    for (int i = lane; i < width; i += 64) p[i] *= r;
}

// ---------------- small glue kernels ----------------
__global__ __launch_bounds__(256) void patch_in_gather(
    const float* __restrict__ x, f16* __restrict__ out) {
    int g = blockIdx.x * 256 + threadIdx.x;
    if (g >= BB * S0 * 128) return;
    int k = g & 127;
    int n = (g >> 7) & (S0 - 1);
    int b = g >> 18;
    out[g] = (f16)x[(size_t)b * CIO * TT + (size_t)(k >> 1) * TT + 2 * n + (k & 1)];
}

__global__ __launch_bounds__(256) void time_embed(
    const float* __restrict__ t, const float* __restrict__ tw,
    float* __restrict__ te) {
    int g = blockIdx.x * 256 + threadIdx.x;
    if (g >= BB * MAPD) return;
    int b = g / MAPD, j = g % MAPD;
    float w = tw[(j < 512) ? j : j - 512];
    float ang = 6.283185307179586f * t[b] * w;
    te[g] = (j < 512) ? cosf(ang) : sinf(ang);
}

__global__ __launch_bounds__(256) void token_merge_gather(
    const float* __restrict__ A, f16* __restrict__ out) {
    int g = blockIdx.x * 256 + threadIdx.x;
    if (g >= BB * 1024 * 1024) return;
    int k = g & 1023;
    int n = (g >> 10) & 1023;
    int b = g >> 20;
    out[g] = (f16)A[((size_t)b * S0 + 2 * n + (k & 1)) * W0 + (k >> 1)];
}

__global__ __launch_bounds__(256) void concat_mid(
    const float* __restrict__ pre, const float* __restrict__ Dsrc,
    float* __restrict__ Cm) {
    int g = blockIdx.x * 256 + threadIdx.x;
    if (g >= BB * SM * W1) return;
    int c = g & 1023;
    int row = g >> 10;
    int b = row / SM, r = row % SM;
    Cm[g] = (r == 0) ? pre[b * W1 + c]
                     : Dsrc[((size_t)b * 1024 + r - 1) * W1 + c];
}

__global__ __launch_bounds__(256) void gather_drop(
    const f16* __restrict__ Dsrc, f16* __restrict__ out) {
    int g = blockIdx.x * 256 + threadIdx.x;
    if (g >= BB * 1024 * W1) return;
    int c = g & 1023;
    int n = (g >> 10) & 1023;
    int b = g >> 20;
    out[g] = Dsrc[((size_t)b * SM + 1 + n) * W1 + c];
}

__global__ __launch_bounds__(256) void split_scatter_lerp(
    const float* __restrict__ y, const float* __restrict__ skip,
    const float* __restrict__ fac, float* __restrict__ xo) {
    int g = blockIdx.x * 256 + threadIdx.x;
    if (g >= BB * S0 * W0) return;
    int c = g & 511;
    int tk = (g >> 9) & (S0 - 1);
    int b = g >> 20;
    float yv = y[((size_t)b * 1024 + (tk >> 1)) * W1 + (c * 2 + (tk & 1))];
    float sk = skip[g];
    xo[g] = sk + fac[0] * (yv - sk);
}

__global__ __launch_bounds__(256) void patch_out_scatter(
    const float* __restrict__ y, float* __restrict__ out) {
    int g = blockIdx.x * 256 + threadIdx.x;
    if (g >= BB * CIO * TT) return;
    int tk = g & (TT - 1);
    int c = (g >> 12) & 63;
    int b = g >> 18;
    out[g] = y[((size_t)b * S0 + (tk >> 1)) * 128 + (c * 2 + (tk & 1))];
}

// ---------------- host orchestration ----------------
extern "C" void kernel_launch(void* const* d_in, const int* in_sizes, int n_in,
                              void* d_out, int out_size, void* d_ws, size_t ws_size,
                              hipStream_t stream) {
    const float* x          = (const float*)d_in[0];
    const float* t          = (const float*)d_in[1];
    const float* time_w     = (const float*)d_in[2];
    const float* time_in_w  = (const float*)d_in[3];
    const float* map_in_s   = (const float*)d_in[4];
    const float* map_norm_s = (const float*)d_in[5];
    const float* map_up_w   = (const float*)d_in[6];
    const float* map_down_w = (const float*)d_in[7];
    const float* map_out_s  = (const float*)d_in[8];
    const float* patch_in_w = (const float*)d_in[9];
    const float* dn_anorm_w = (const float*)d_in[10];
    const float* dn_qkv_w   = (const float*)d_in[11];
    const float* dn_o_w     = (const float*)d_in[12];
    const float* dn_fnorm_w = (const float*)d_in[13];
    const float* dn_ff1_w   = (const float*)d_in[14];
    const float* dn_ff2_w   = (const float*)d_in[15];
    const float* merge_w    = (const float*)d_in[16];
    const float* mid_map_w  = (const float*)d_in[17];
    const float* mid_pin_w  = (const float*)d_in[18];
    const float* mid_pout_w = (const float*)d_in[19];
    const float* mid_ln1_g  = (const float*)d_in[20];
    const float* mid_ln1_b  = (const float*)d_in[21];
    const float* mid_qkv_w  = (const float*)d_in[22];
    const float* mid_o_w    = (const float*)d_in[23];
    const float* mid_ln2_g  = (const float*)d_in[24];
    const float* mid_ln2_b  = (const float*)d_in[25];
    const float* mid_ff1_w  = (const float*)d_in[26];
    const float* mid_ff2_w  = (const float*)d_in[27];
    const float* mid_fn_g   = (const float*)d_in[28];
    const float* mid_fn_b   = (const float*)d_in[29];
    const float* split_w    = (const float*)d_in[30];
    const float* split_fac  = (const float*)d_in[31];
    const float* up_anorm_w = (const float*)d_in[32];
    const float* up_qkv_w   = (const float*)d_in[33];
    const float* up_o_w     = (const float*)d_in[34];
    const float* up_fnorm_w = (const float*)d_in[35];
    const float* up_ff1_w   = (const float*)d_in[36];
    const float* up_ff2_w   = (const float*)d_in[37];
    const float* out_norm_s = (const float*)d_in[38];
    const float* patch_out_w= (const float*)d_in[39];

    float* Wp = (float*)d_ws;
    size_t off = 0;
    auto alloc = [&](size_t n) { float* p = Wp + off; off += n; return p; };
    float* A   = alloc((size_t)4096 * 512);          // local residual (f32)
    float* Bsk = alloc((size_t)4096 * 512);          // skip
    float* Cm  = alloc((size_t)2050 * 1024);         // mid residual
    float* Df  = alloc((size_t)2050 * 1024);         // f32 temp
    float* E32 = alloc((size_t)16 * SM * SM);        // big f32 scratch
    float* Fq  = alloc((size_t)2099200);
    float* Fk  = alloc((size_t)2099200);
    float* Fv  = alloc((size_t)2099200);
    f16*  H1   = (f16*)alloc((size_t)8396800);       // 16.79M f16
    f16*  H2   = (f16*)alloc((size_t)4198400);       // 8.40M f16
    f16*  Wh   = (f16*)alloc((size_t)4194304);       // 8.39M f16 weight buf
    float* Sma = alloc((size_t)32768);
    (void)ws_size; (void)in_sizes; (void)n_in; (void)out_size;

    float* te   = Sma;
    float* temb = Sma + 2048;
    float* mapx = Sma + 4096;
    float* maph = Sma + 6144;
    float* mapu = Sma + 8192;
    float* mapg = Sma + 12288;
    float* cond = Sma + 14336;
    float* sA   = Sma + 16384;
    float* sF   = Sma + 17408;
    float* pre  = Sma + 18432;

    auto WC = [&](const float* W, int K, int N) {
        wcast<<<dim3(N / 64, K / 64), 256, 0, stream>>>(W, Wh, K, N);
    };
    auto GF = [&](const f16* Aa, const float* res, float* C, int M, int N, int K) {
        gemm_h<false><<<dim3(N / 128, (M + 127) / 128), 256, 0, stream>>>(Aa, Wh, res, C, M, N, K);
    };
    auto GH = [&](const f16* Aa, f16* C, int M, int N, int K) {
        gemm_h<true><<<dim3(N / 128, (M + 127) / 128), 256, 0, stream>>>(Aa, Wh, nullptr, C, M, N, K);
    };
    auto gemm32 = [&](const float* Aa, const float* Wt, const float* res,
                      float* C, int M, int N, int K) {
        gemm_f32<<<dim3(N / 128, (M + 127) / 128), 256, 0, stream>>>(Aa, Wt, res, C, M, N, K);
    };

    // ---- patch in ----
    patch_in_gather<<<(BB * S0 * 128 + 255) / 256, 256, 0, stream>>>(x, H2);
    WC(patch_in_w, 128, 512);
    GF(H2, nullptr, A, 4096, 512, 128);

    // ---- time embedding + mapping (tiny, f32) ----
    time_embed<<<(BB * MAPD + 255) / 256, 256, 0, stream>>>(t, time_w, te);
    gemm32(te, time_in_w, nullptr, temb, 2, 1024, 1024);
    rmsnorm_k<float><<<2, 256, 0, stream>>>(temb, map_in_s, mapx, 1024, 2, 0.f);
    for (int l = 0; l < 2; ++l) {
        rmsnorm_k<float><<<2, 256, 0, stream>>>(mapx, map_norm_s + (size_t)l * 1024, maph, 1024, 2, 0.f);
        gemm32(maph, map_up_w + (size_t)l * 1024 * 2048, nullptr, mapu, 2, 2048, 1024);
        glu_k<float, float><<<(2 * 1024 + 255) / 256, 256, 0, stream>>>(mapu, mapg, 2 * 1024, 1024, 0);
        gemm32(mapg, map_down_w + (size_t)l * 1024 * 1024, mapx, mapx, 2, 1024, 1024);
    }
    rmsnorm_k<float><<<2, 256, 0, stream>>>(mapx, map_out_s, cond, 1024, 2, 0.f);

    // ---- local level (shared for down/up) ----
    auto run_local = [&](const float* anorm, const float* qkvw, const float* ow,
                         const float* fnorm, const float* ff1, const float* ff2) {
        for (int l = 0; l < 2; ++l) {
            gemm32(cond, anorm + (size_t)l * 1024 * 512, nullptr, sA, 2, 512, 1024);
            rmsnorm_k<f16><<<4096, 256, 0, stream>>>(A, sA, H2, 512, 2048, 1.f);
            WC(qkvw + (size_t)l * 512 * 1536, 512, 1536);
            GF(H2, nullptr, E32, 4096, 1536, 512);
            qkv_split_rope<<<(BB * S0 * HDN * 32 + 255) / 256, 256, 0, stream>>>(E32, Fq, Fk, Fv, S0, HDN);
            local_qk<<<BB * HDN * NW, 256, 0, stream>>>(Fq, Fk, E32);
            softmax_rows<<<(BB * HDN * NW * 128 + 3) / 4, 256, 0, stream>>>(E32, BB * HDN * NW * 128, 384, 1);
            local_pv<<<BB * HDN * NW, 256, 0, stream>>>(E32, Fv, H2);
            WC(ow + (size_t)l * 512 * 512, 512, 512);
            GF(H2, A, A, 4096, 512, 512);
            gemm32(cond, fnorm + (size_t)l * 1024 * 512, nullptr, sF, 2, 512, 1024);
            rmsnorm_k<f16><<<4096, 256, 0, stream>>>(A, sF, H2, 512, 2048, 1.f);
            WC(ff1 + (size_t)l * 512 * 2048, 512, 2048);
            GH(H2, H1, 4096, 2048, 512);
            glu_k<f16, f16><<<(4096 * 1024 + 255) / 256, 256, 0, stream>>>(H1, H2, (size_t)4096 * 1024, 1024, 0);
            WC(ff2 + (size_t)l * 1024 * 512, 1024, 512);
            GF(H2, A, A, 4096, 512, 1024);
        }
    };
    run_local(dn_anorm_w, dn_qkv_w, dn_o_w, dn_fnorm_w, dn_ff1_w, dn_ff2_w);

    // ---- skip save, merge, mid prep ----
    hipMemcpyAsync(Bsk, A, (size_t)4096 * 512 * 4, hipMemcpyDeviceToDevice, stream);
    token_merge_gather<<<(BB * 1024 * 1024 + 255) / 256, 256, 0, stream>>>(A, H2);
    WC(merge_w, 1024, 1024);
    GH(H2, H1, 2048, 1024, 1024);
    WC(mid_pin_w, 1024, 1024);
    GF(H1, nullptr, Df, 2048, 1024, 1024);
    gemm32(cond, mid_map_w, nullptr, pre, 2, 1024, 1024);
    concat_mid<<<(BB * SM * W1 + 255) / 256, 256, 0, stream>>>(pre, Df, Cm);

    // ---- mid level ----
    for (int l = 0; l < 4; ++l) {
        layernorm_k<<<2050, 256, 0, stream>>>(Cm, mid_ln1_g + (size_t)l * 1024,
                                              mid_ln1_b + (size_t)l * 1024, H2, 1024);
        WC(mid_qkv_w + (size_t)l * 1024 * 3072, 1024, 3072);
        GF(H2, nullptr, E32, 2050, 3072, 1024);
        qkv_split_rope<<<(BB * SM * HMID * 32 + 255) / 256, 256, 0, stream>>>(E32, Fq, Fk, Fv, SM, HMID);
        for (int b = 0; b < 2; ++b) {
            mid_qk<<<dim3(9, HMID), 256, 0, stream>>>(Fq, Fk, E32, b);
            softmax_rows<<<(HMID * SM + 3) / 4, 256, 0, stream>>>(E32, HMID * SM, SM, 0);
            mid_pv<<<dim3(9, HMID), 256, 0, stream>>>(E32, Fv, H2, b);
        }
        WC(mid_o_w + (size_t)l * 1024 * 1024, 1024, 1024);
        GF(H2, Cm, Cm, 2050, 1024, 1024);
        layernorm_k<<<2050, 256, 0, stream>>>(Cm, mid_ln2_g + (size_t)l * 1024,
                                              mid_ln2_b + (size_t)l * 1024, H2, 1024);
        WC(mid_ff1_w + (size_t)l * 1024 * 8192, 1024, 8192);
        GH(H2, H1, 2050, 8192, 1024);
        glu_k<f16, f16><<<(int)(((size_t)2050 * 4096 + 255) / 256), 256, 0, stream>>>(H1, H2, (size_t)2050 * 4096, 4096, 1);
        WC(mid_ff2_w + (size_t)l * 4096 * 1024, 4096, 1024);
        GF(H2, Cm, Cm, 2050, 1024, 4096);
    }
    layernorm_k<<<2050, 256, 0, stream>>>(Cm, mid_fn_g, mid_fn_b, H2, 1024);

    // ---- pout + token split + lerp skip ----
    WC(mid_pout_w, 1024, 1024);
    GH(H2, H1, 2050, 1024, 1024);
    gather_drop<<<(BB * 1024 * W1 + 255) / 256, 256, 0, stream>>>(H1, H2);
    WC(split_w, 1024, 1024);
    GF(H2, nullptr, Df, 2048, 1024, 1024);
    split_scatter_lerp<<<(BB * S0 * W0 + 255) / 256, 256, 0, stream>>>(Df, Bsk, split_fac, A);

    // ---- up level ----
    run_local(up_anorm_w, up_qkv_w, up_o_w, up_fnorm_w, up_ff1_w, up_ff2_w);

    // ---- out ----
    rmsnorm_k<f16><<<4096, 256, 0, stream>>>(A, out_norm_s, H2, 512, 4096, 0.f);
    WC(patch_out_w, 512, 128);
    GF(H2, nullptr, Df, 4096, 128, 512);
    patch_out_scatter<<<(BB * CIO * TT + 255) / 256, 256, 0, stream>>>(Df, (float*)d_out);
}

// Round 3
// 4706.458 us; speedup vs baseline: 3.9802x; 1.9671x over previous
//
#include <hip/hip_runtime.h>
#include <math.h>

// ---------------- constants ----------------
#define BB   2
#define CIO  64
#define TT   4096
#define S0   2048      // local level seq len
#define W0   512
#define HDN  8
#define SM   1025      // mid seq len (with prepended token)
#define SMP  1088      // padded mid seq (17*64)
#define W1   1024
#define HMID 16
#define WIN  128
#define NW   16        // S0 / WIN
#define MAPD 1024

typedef _Float16 f16;
typedef _Float16 half8 __attribute__((ext_vector_type(8)));
typedef _Float16 half2v __attribute__((ext_vector_type(2)));
typedef float floatx4 __attribute__((ext_vector_type(4)));

// ---------------- device helpers ----------------
__device__ __forceinline__ float gelu_tanh(float x) {
    float x3 = x * x * x;
    return 0.5f * x * (1.f + tanhf(0.7978845608028654f * (x + 0.044715f * x3)));
}

// ---------------- weight transpose-cast: W[K][N] f32 -> Wt[N][K] f16 ------
__global__ __launch_bounds__(256) void wcast(
    const float* __restrict__ W, f16* __restrict__ Wt, int K, int N) {
    __shared__ float T[64][65];
    const int n0 = blockIdx.x * 64, k0 = blockIdx.y * 64;
    const int tid = threadIdx.x;
    for (int e = tid; e < 4096; e += 256) {
        int r = e >> 6, c = e & 63;
        T[r][c] = W[(size_t)(k0 + r) * N + n0 + c];
    }
    __syncthreads();
    for (int e = tid; e < 2048; e += 256) {
        int r = e >> 5, c2 = (e & 31) * 2;
        half2v p;
        p[0] = (f16)T[c2][r];
        p[1] = (f16)T[c2 + 1][r];
        *(half2v*)(Wt + (size_t)(n0 + r) * K + k0 + c2) = p;
    }
}

// ---------------- MFMA GEMM: C = (res?) + A[MxK]f16 @ Bt[NxK]f16^T --------
template<bool HOUT>
__global__ __launch_bounds__(256) void gemm_h(
    const f16* __restrict__ A, const f16* __restrict__ Bt,
    const float* __restrict__ res, void* __restrict__ Cv,
    int M, int N, int K) {
    __shared__ __align__(16) f16 As[128 * 32];
    __shared__ __align__(16) f16 Bs[128 * 32];
    const int tid = threadIdx.x;
    const int wv = tid >> 6, ln = tid & 63;
    const int bm = blockIdx.y * 128, bn = blockIdx.x * 128;
    const int wr = (wv >> 1) * 64, wc = (wv & 1) * 64;
    floatx4 acc[4][4];
#pragma unroll
    for (int m = 0; m < 4; ++m)
#pragma unroll
        for (int n = 0; n < 4; ++n) acc[m][n] = (floatx4)0.f;
    const int r = ln & 15, kc = (ln >> 4) * 8;
    for (int k0 = 0; k0 < K; k0 += 32) {
#pragma unroll
        for (int i = 0; i < 2; ++i) {
            int off = i * 4096 + wv * 1024 + ln * 16;
            int row = off >> 6, kb = (off & 63) >> 1;
            int gr = bm + row; gr = gr < M ? gr : M - 1;
            f16* gp = const_cast<f16*>(A) + (size_t)gr * K + k0 + kb;
            __builtin_amdgcn_global_load_lds(
                (__attribute__((address_space(1))) void*)gp,
                (__attribute__((address_space(3))) void*)(As + i * 2048 + wv * 512),
                16, 0, 0);
            f16* gq = const_cast<f16*>(Bt) + (size_t)(bn + row) * K + k0 + kb;
            __builtin_amdgcn_global_load_lds(
                (__attribute__((address_space(1))) void*)gq,
                (__attribute__((address_space(3))) void*)(Bs + i * 2048 + wv * 512),
                16, 0, 0);
        }
        __syncthreads();
        half8 af[4], bf[4];
#pragma unroll
        for (int m = 0; m < 4; ++m)
            af[m] = *(const half8*)(As + (wr + m * 16 + r) * 32 + kc);
#pragma unroll
        for (int n = 0; n < 4; ++n)
            bf[n] = *(const half8*)(Bs + (wc + n * 16 + r) * 32 + kc);
#pragma unroll
        for (int m = 0; m < 4; ++m)
#pragma unroll
            for (int n = 0; n < 4; ++n)
                acc[m][n] = __builtin_amdgcn_mfma_f32_16x16x32_f16(af[m], bf[n], acc[m][n], 0, 0, 0);
        __syncthreads();
    }
    float* Cf = (float*)Cv;
    f16*   Ch = (f16*)Cv;
#pragma unroll
    for (int m = 0; m < 4; ++m) {
        int rbase = bm + wr + m * 16 + ((ln >> 4) << 2);
#pragma unroll
        for (int j = 0; j < 4; ++j) {
            int row = rbase + j;
            if (row < M) {
                size_t ro = (size_t)row * N;
#pragma unroll
                for (int n = 0; n < 4; ++n) {
                    int col = bn + wc + n * 16 + (ln & 15);
                    float v = acc[m][n][j];
                    if (HOUT) Ch[ro + col] = (f16)v;
                    else      Cf[ro + col] = v + (res ? res[ro + col] : 0.f);
                }
            }
        }
    }
}

// ---------------- small fp32 GEMM (M=2 cond/mapping paths) ----------------
__global__ __launch_bounds__(256) void gemm_f32(
    const float* __restrict__ A, const float* __restrict__ Wt,
    const float* __restrict__ res, float* __restrict__ C,
    int M, int N, int K) {
    __shared__ float As[16][136];
    __shared__ float Bs[16][128];
    const int tid = threadIdx.x;
    const int bm = blockIdx.y * 128, bn = blockIdx.x * 128;
    const int tr = (tid >> 4) << 3;
    const int tc = (tid & 15) << 3;
    float acc[8][8];
#pragma unroll
    for (int i = 0; i < 8; ++i)
#pragma unroll
        for (int j = 0; j < 8; ++j) acc[i][j] = 0.f;
    for (int k0 = 0; k0 < K; k0 += 16) {
#pragma unroll
        for (int i = 0; i < 8; ++i) {
            int e = tid + i * 256;
            int m = e >> 4, kk = e & 15;
            As[kk][m] = (bm + m < M) ? A[(size_t)(bm + m) * K + k0 + kk] : 0.f;
        }
#pragma unroll
        for (int i = 0; i < 8; ++i) {
            int e = tid + i * 256;
            int kk = e >> 7, n = e & 127;
            Bs[kk][n] = Wt[(size_t)(k0 + kk) * N + bn + n];
        }
        __syncthreads();
#pragma unroll
        for (int kk = 0; kk < 16; ++kk) {
            float a[8], b[8];
#pragma unroll
            for (int i = 0; i < 8; ++i) a[i] = As[kk][tr + i];
#pragma unroll
            for (int j = 0; j < 8; ++j) b[j] = Bs[kk][tc + j];
#pragma unroll
            for (int i = 0; i < 8; ++i)
#pragma unroll
                for (int j = 0; j < 8; ++j) acc[i][j] = fmaf(a[i], b[j], acc[i][j]);
        }
        __syncthreads();
    }
#pragma unroll
    for (int i = 0; i < 8; ++i) {
        int m = bm + tr + i;
        if (m >= M) break;
        size_t row = (size_t)m * N;
#pragma unroll
        for (int j = 0; j < 8; ++j) {
            int n = bn + tc + j;
            C[row + n] = (res ? res[row + n] : 0.f) + acc[i][j];
        }
    }
}

// ---------------- norms ----------------
__device__ __forceinline__ void stf(float* p, float v) { *p = v; }
__device__ __forceinline__ void stf(f16* p, float v)   { *p = (f16)v; }

template<typename TO>
__global__ __launch_bounds__(256) void rmsnorm_k(
    const float* __restrict__ X, const float* __restrict__ scale,
    TO* __restrict__ Y, int C, int rows_per_group, float sadd) {
    int row = blockIdx.x, tid = threadIdx.x;
    const float* x = X + (size_t)row * C;
    float v[8];
    int cnt = C >> 8;
    float ss = 0.f;
    for (int i = 0; i < cnt; ++i) { v[i] = x[tid + (i << 8)]; ss += v[i] * v[i]; }
    __shared__ float red[256];
    red[tid] = ss; __syncthreads();
    for (int s2 = 128; s2; s2 >>= 1) { if (tid < s2) red[tid] += red[tid + s2]; __syncthreads(); }
    float inv = rsqrtf(red[0] / (float)C + 1e-6f);
    const float* sc = scale + (size_t)(row / rows_per_group) * C;
    TO* y = Y + (size_t)row * C;
    for (int i = 0; i < cnt; ++i) {
        int c = tid + (i << 8);
        stf(&y[c], v[i] * (sadd + sc[c]) * inv);
    }
}

__global__ __launch_bounds__(256) void layernorm_k(
    const float* __restrict__ X, const float* __restrict__ g,
    const float* __restrict__ bta, f16* __restrict__ Y, int C) {
    int row = blockIdx.x, tid = threadIdx.x;
    const float* x = X + (size_t)row * C;
    float v[8];
    int cnt = C >> 8;
    float s = 0.f;
    for (int i = 0; i < cnt; ++i) { v[i] = x[tid + (i << 8)]; s += v[i]; }
    __shared__ float red[256];
    red[tid] = s; __syncthreads();
    for (int s2 = 128; s2; s2 >>= 1) { if (tid < s2) red[tid] += red[tid + s2]; __syncthreads(); }
    float m = red[0] / (float)C;
    __syncthreads();
    float s2s = 0.f;
    for (int i = 0; i < cnt; ++i) { float d = v[i] - m; s2s += d * d; }
    red[tid] = s2s; __syncthreads();
    for (int s2 = 128; s2; s2 >>= 1) { if (tid < s2) red[tid] += red[tid + s2]; __syncthreads(); }
    float inv = rsqrtf(red[0] / (float)C + 1e-5f);
    f16* y = Y + (size_t)row * C;
    for (int i = 0; i < cnt; ++i) {
        int c = tid + (i << 8);
        y[c] = (f16)((v[i] - m) * inv * g[c] + bta[c]);
    }
}

// ---------------- GLU ----------------
// scalar f32 version (tiny mapping path)
__global__ __launch_bounds__(256) void glu_k(
    const float* __restrict__ U, float* __restrict__ Yo,
    size_t total, int F, int mode) {
    size_t gidx = (size_t)blockIdx.x * 256 + threadIdx.x;
    if (gidx >= total) return;
    size_t r = gidx / (size_t)F;
    int c = (int)(gidx - r * F);
    const float* u = U + r * (size_t)(2 * F);
    float a = u[c], gg = u[F + c];
    float act = (mode == 0) ? gelu_tanh(gg) : gg / (1.f + expf(-gg));
    Yo[gidx] = a * act;
}

// vectorized f16 version: each thread does 8 contiguous elements
__global__ __launch_bounds__(256) void glu_h8(
    const f16* __restrict__ U, f16* __restrict__ Yo,
    size_t total8, int F8, int mode) {
    size_t gi = (size_t)blockIdx.x * 256 + threadIdx.x;
    if (gi >= total8) return;
    size_t r = gi / (size_t)F8;
    int c = (int)(gi - r * (size_t)F8);
    const f16* u = U + r * (size_t)F8 * 16;
    half8 av = *(const half8*)(u + c * 8);
    half8 gv = *(const half8*)(u + F8 * 8 + c * 8);
    half8 y;
#pragma unroll
    for (int j = 0; j < 8; ++j) {
        float a = (float)av[j], gg = (float)gv[j];
        float act = (mode == 0) ? gelu_tanh(gg) : gg / (1.f + __expf(-gg));
        y[j] = (f16)(a * act);
    }
    *(half8*)(Yo + gi * 8) = y;
}

// ---------------- QKV split + RoPE (+ q scale 1/8), f16 out ---------------
__global__ __launch_bounds__(256) void qkv_split_rope(
    const float* __restrict__ QKV, f16* __restrict__ Qo,
    f16* __restrict__ Ko, f16* __restrict__ Vo, int S, int H) {
    int g = blockIdx.x * 256 + threadIdx.x;
    int total = BB * S * H * 32;
    if (g >= total) return;
    int i = g & 31;
    int tix = g >> 5;
    int h = tix % H; tix /= H;
    int s = tix % S; int b = tix / S;
    int C = H * 64;
    const float* base = QKV + (size_t)(b * S + s) * 3 * C + h * 64;
    float q1 = base[i], q2 = base[32 + i];
    float k1 = base[C + i], k2 = base[C + 32 + i];
    float v1 = base[2 * C + i], v2 = base[2 * C + 32 + i];
    float inv = expf(-(float)i * 0.28782313662425575f);
    float ang = (float)s * inv;
    float sn, cs;
    sincosf(ang, &sn, &cs);
    size_t o = ((size_t)(b * H + h) * S + s) * 64 + i;
    Qo[o]      = (f16)((q1 * cs - q2 * sn) * 0.125f);
    Qo[o + 32] = (f16)((q2 * cs + q1 * sn) * 0.125f);
    Ko[o]      = (f16)(k1 * cs - k2 * sn);
    Ko[o + 32] = (f16)(k2 * cs + k1 * sn);
    Vo[o]      = (f16)v1;
    Vo[o + 32] = (f16)v2;
}

// ---------------- V transpose: V[bh][S][64] -> Vt[bh][64][Spad] -----------
__global__ __launch_bounds__(256) void vtrans(
    const f16* __restrict__ V, f16* __restrict__ Vt, int S, int Spad) {
    __shared__ f16 T[64][72];
    const int tid = threadIdx.x;
    const int k0 = blockIdx.x * 64;
    const f16* Vb = V + (size_t)blockIdx.y * S * 64;
    f16* Vtb = Vt + (size_t)blockIdx.y * 64 * Spad;
    for (int c = tid; c < 512; c += 256) {
        int kk = c >> 3, d8 = (c & 7) * 8;
        int kg = k0 + kk; kg = kg < S ? kg : S - 1;
        half8 v = *(const half8*)(Vb + (size_t)kg * 64 + d8);
        if (k0 + kk >= S) {
#pragma unroll
            for (int j = 0; j < 8; ++j) v[j] = (f16)0.f;
        }
        *(half8*)(&T[kk][d8]) = v;
    }
    __syncthreads();
    for (int c = tid; c < 512; c += 256) {
        int d = c >> 3, k8 = (c & 7) * 8;
        half8 o;
#pragma unroll
        for (int j = 0; j < 8; ++j) o[j] = T[k8 + j][d];
        *(half8*)(Vtb + (size_t)d * Spad + k0 + k8) = o;
    }
}

// ---------------- fused flash attention -----------------------------------
// Q,K: [BH][S][64] f16 (Q pre-scaled). Vt: [BH][64][Spad] f16.
// O: [B][S][H*64] f16. win=0: full attention; win>0: local window (q-tile==win==128).
__global__ __launch_bounds__(256) void fattn(
    const f16* __restrict__ Q, const f16* __restrict__ K,
    const f16* __restrict__ Vt, f16* __restrict__ O,
    int S, int Spad, int H, int win) {
    __shared__ __align__(16) f16 Ks[64][72];
    __shared__ __align__(16) f16 Vs[64][72];
    __shared__ __align__(16) f16 Ps[4][32][72];
    const int tid = threadIdx.x;
    const int wv = tid >> 6, ln = tid & 63;
    const int r15 = ln & 15, g = ln >> 4;
    const int bh = blockIdx.y;
    const int b = bh / H, h = bh % H;
    const int q0 = (int)blockIdx.x * 128;
    const f16* Qb = Q + (size_t)bh * S * 64;
    const f16* Kb = K + (size_t)bh * S * 64;
    const f16* Vtb = Vt + (size_t)bh * 64 * Spad;

    half8 aq[2][2];
#pragma unroll
    for (int m = 0; m < 2; ++m) {
        int q = q0 + wv * 32 + m * 16 + r15;
        q = q < S ? q : S - 1;
#pragma unroll
        for (int ks = 0; ks < 2; ++ks)
            aq[m][ks] = *(const half8*)(Qb + (size_t)q * 64 + ks * 32 + g * 8);
    }
    floatx4 o[2][4];
#pragma unroll
    for (int m = 0; m < 2; ++m)
#pragma unroll
        for (int n = 0; n < 4; ++n) o[m][n] = (floatx4)0.f;
    float mst[2][4], lst[2][4];
#pragma unroll
    for (int m = 0; m < 2; ++m)
#pragma unroll
        for (int j = 0; j < 4; ++j) { mst[m][j] = -3.0e38f; lst[m][j] = 0.f; }

    int klo = 0, khi = S;
    if (win) {
        int n = (int)blockIdx.x;
        klo = (n - 1) * win; if (klo < 0) klo = 0;
        khi = (n + 2) * win; if (khi > S) khi = S;
    }
    for (int kb = klo; kb < khi; kb += 64) {
        __syncthreads();
#pragma unroll
        for (int i = 0; i < 2; ++i) {
            int c = tid + i * 256;
            int rr = c >> 3, c8 = (c & 7) * 8;
            int kg = kb + rr; kg = kg < S ? kg : S - 1;
            *(half8*)(&Ks[rr][c8]) = *(const half8*)(Kb + (size_t)kg * 64 + c8);
            *(half8*)(&Vs[rr][c8]) = *(const half8*)(Vtb + (size_t)rr * Spad + kb + c8);
        }
        __syncthreads();
        // QK^T
        floatx4 s[2][4];
#pragma unroll
        for (int m = 0; m < 2; ++m)
#pragma unroll
            for (int n = 0; n < 4; ++n) s[m][n] = (floatx4)0.f;
#pragma unroll
        for (int ks = 0; ks < 2; ++ks) {
            half8 bk[4];
#pragma unroll
            for (int n = 0; n < 4; ++n)
                bk[n] = *(const half8*)(&Ks[n * 16 + r15][ks * 32 + g * 8]);
#pragma unroll
            for (int m = 0; m < 2; ++m)
#pragma unroll
                for (int n = 0; n < 4; ++n)
                    s[m][n] = __builtin_amdgcn_mfma_f32_16x16x32_f16(aq[m][ks], bk[n], s[m][n], 0, 0, 0);
        }
        // tail mask (mid only: kk >= S)
        if (kb + 64 > S) {
#pragma unroll
            for (int n = 0; n < 4; ++n)
                if (kb + n * 16 + r15 >= S) {
#pragma unroll
                    for (int m = 0; m < 2; ++m) s[m][n] = (floatx4)(-3.0e38f);
                }
        }
        // online softmax
#pragma unroll
        for (int m = 0; m < 2; ++m) {
#pragma unroll
            for (int j = 0; j < 4; ++j) {
                float tm = fmaxf(fmaxf(s[m][0][j], s[m][1][j]), fmaxf(s[m][2][j], s[m][3][j]));
                tm = fmaxf(tm, __shfl_xor(tm, 1));
                tm = fmaxf(tm, __shfl_xor(tm, 2));
                tm = fmaxf(tm, __shfl_xor(tm, 4));
                tm = fmaxf(tm, __shfl_xor(tm, 8));
                float mn = fmaxf(mst[m][j], tm);
                float sc = __expf(mst[m][j] - mn);
                mst[m][j] = mn;
                float ts = 0.f;
#pragma unroll
                for (int n = 0; n < 4; ++n) {
                    float p = __expf(s[m][n][j] - mn);
                    s[m][n][j] = p;
                    ts += p;
                }
                ts += __shfl_xor(ts, 1);
                ts += __shfl_xor(ts, 2);
                ts += __shfl_xor(ts, 4);
                ts += __shfl_xor(ts, 8);
                lst[m][j] = lst[m][j] * sc + ts;
#pragma unroll
                for (int n = 0; n < 4; ++n) o[m][n][j] *= sc;
            }
        }
        // P -> LDS (wave-private) in A-frag layout
#pragma unroll
        for (int m = 0; m < 2; ++m)
#pragma unroll
            for (int n = 0; n < 4; ++n)
#pragma unroll
                for (int j = 0; j < 4; ++j)
                    Ps[wv][m * 16 + g * 4 + j][n * 16 + r15] = (f16)s[m][n][j];
        // PV
#pragma unroll
        for (int ks = 0; ks < 2; ++ks) {
            half8 pa[2], bv[4];
#pragma unroll
            for (int m = 0; m < 2; ++m)
                pa[m] = *(const half8*)(&Ps[wv][m * 16 + r15][ks * 32 + g * 8]);
#pragma unroll
            for (int n = 0; n < 4; ++n)
                bv[n] = *(const half8*)(&Vs[n * 16 + r15][ks * 32 + g * 8]);
#pragma unroll
            for (int m = 0; m < 2; ++m)
#pragma unroll
                for (int n = 0; n < 4; ++n)
                    o[m][n] = __builtin_amdgcn_mfma_f32_16x16x32_f16(pa[m], bv[n], o[m][n], 0, 0, 0);
        }
    }
    const int HC = H * 64;
#pragma unroll
    for (int m = 0; m < 2; ++m)
#pragma unroll
        for (int j = 0; j < 4; ++j) {
            int q = q0 + wv * 32 + m * 16 + g * 4 + j;
            if (q < S) {
                float inv = 1.f / lst[m][j];
                size_t ro = ((size_t)b * S + q) * HC + h * 64;
#pragma unroll
                for (int n = 0; n < 4; ++n)
                    O[ro + n * 16 + r15] = (f16)(o[m][n][j] * inv);
            }
        }
}

// ---------------- small glue kernels ----------------
__global__ __launch_bounds__(256) void patch_in_gather(
    const float* __restrict__ x, f16* __restrict__ out) {
    int g = blockIdx.x * 256 + threadIdx.x;
    if (g >= BB * S0 * 128) return;
    int k = g & 127;
    int n = (g >> 7) & (S0 - 1);
    int b = g >> 18;
    out[g] = (f16)x[(size_t)b * CIO * TT + (size_t)(k >> 1) * TT + 2 * n + (k & 1)];
}

__global__ __launch_bounds__(256) void time_embed(
    const float* __restrict__ t, const float* __restrict__ tw,
    float* __restrict__ te) {
    int g = blockIdx.x * 256 + threadIdx.x;
    if (g >= BB * MAPD) return;
    int b = g / MAPD, j = g % MAPD;
    float w = tw[(j < 512) ? j : j - 512];
    float ang = 6.283185307179586f * t[b] * w;
    te[g] = (j < 512) ? cosf(ang) : sinf(ang);
}

__global__ __launch_bounds__(256) void token_merge_gather(
    const float* __restrict__ A, f16* __restrict__ out) {
    int g = blockIdx.x * 256 + threadIdx.x;
    if (g >= BB * 1024 * 1024) return;
    int k = g & 1023;
    int n = (g >> 10) & 1023;
    int b = g >> 20;
    out[g] = (f16)A[((size_t)b * S0 + 2 * n + (k & 1)) * W0 + (k >> 1)];
}

__global__ __launch_bounds__(256) void concat_mid(
    const float* __restrict__ pre, const float* __restrict__ Dsrc,
    float* __restrict__ Cm) {
    int g = blockIdx.x * 256 + threadIdx.x;
    if (g >= BB * SM * W1) return;
    int c = g & 1023;
    int row = g >> 10;
    int b = row / SM, r = row % SM;
    Cm[g] = (r == 0) ? pre[b * W1 + c]
                     : Dsrc[((size_t)b * 1024 + r - 1) * W1 + c];
}

__global__ __launch_bounds__(256) void gather_drop(
    const f16* __restrict__ Dsrc, f16* __restrict__ out) {
    int g = blockIdx.x * 256 + threadIdx.x;
    if (g >= BB * 1024 * W1) return;
    int c = g & 1023;
    int n = (g >> 10) & 1023;
    int b = g >> 20;
    out[g] = Dsrc[((size_t)b * SM + 1 + n) * W1 + c];
}

__global__ __launch_bounds__(256) void split_scatter_lerp(
    const float* __restrict__ y, const float* __restrict__ skip,
    const float* __restrict__ fac, float* __restrict__ xo) {
    int g = blockIdx.x * 256 + threadIdx.x;
    if (g >= BB * S0 * W0) return;
    int c = g & 511;
    int tk = (g >> 9) & (S0 - 1);
    int b = g >> 20;
    float yv = y[((size_t)b * 1024 + (tk >> 1)) * W1 + (c * 2 + (tk & 1))];
    float sk = skip[g];
    xo[g] = sk + fac[0] * (yv - sk);
}

__global__ __launch_bounds__(256) void patch_out_scatter(
    const float* __restrict__ y, float* __restrict__ out) {
    int g = blockIdx.x * 256 + threadIdx.x;
    if (g >= BB * CIO * TT) return;
    int tk = g & (TT - 1);
    int c = (g >> 12) & 63;
    int b = g >> 18;
    out[g] = y[((size_t)b * S0 + (tk >> 1)) * 128 + (c * 2 + (tk & 1))];
}

// ---------------- host orchestration ----------------
extern "C" void kernel_launch(void* const* d_in, const int* in_sizes, int n_in,
                              void* d_out, int out_size, void* d_ws, size_t ws_size,
                              hipStream_t stream) {
    const float* x          = (const float*)d_in[0];
    const float* t          = (const float*)d_in[1];
    const float* time_w     = (const float*)d_in[2];
    const float* time_in_w  = (const float*)d_in[3];
    const float* map_in_s   = (const float*)d_in[4];
    const float* map_norm_s = (const float*)d_in[5];
    const float* map_up_w   = (const float*)d_in[6];
    const float* map_down_w = (const float*)d_in[7];
    const float* map_out_s  = (const float*)d_in[8];
    const float* patch_in_w = (const float*)d_in[9];
    const float* dn_anorm_w = (const float*)d_in[10];
    const float* dn_qkv_w   = (const float*)d_in[11];
    const float* dn_o_w     = (const float*)d_in[12];
    const float* dn_fnorm_w = (const float*)d_in[13];
    const float* dn_ff1_w   = (const float*)d_in[14];
    const float* dn_ff2_w   = (const float*)d_in[15];
    const float* merge_w    = (const float*)d_in[16];
    const float* mid_map_w  = (const float*)d_in[17];
    const float* mid_pin_w  = (const float*)d_in[18];
    const float* mid_pout_w = (const float*)d_in[19];
    const float* mid_ln1_g  = (const float*)d_in[20];
    const float* mid_ln1_b  = (const float*)d_in[21];
    const float* mid_qkv_w  = (const float*)d_in[22];
    const float* mid_o_w    = (const float*)d_in[23];
    const float* mid_ln2_g  = (const float*)d_in[24];
    const float* mid_ln2_b  = (const float*)d_in[25];
    const float* mid_ff1_w  = (const float*)d_in[26];
    const float* mid_ff2_w  = (const float*)d_in[27];
    const float* mid_fn_g   = (const float*)d_in[28];
    const float* mid_fn_b   = (const float*)d_in[29];
    const float* split_w    = (const float*)d_in[30];
    const float* split_fac  = (const float*)d_in[31];
    const float* up_anorm_w = (const float*)d_in[32];
    const float* up_qkv_w   = (const float*)d_in[33];
    const float* up_o_w     = (const float*)d_in[34];
    const float* up_fnorm_w = (const float*)d_in[35];
    const float* up_ff1_w   = (const float*)d_in[36];
    const float* up_ff2_w   = (const float*)d_in[37];
    const float* out_norm_s = (const float*)d_in[38];
    const float* patch_out_w= (const float*)d_in[39];

    float* Wp = (float*)d_ws;
    size_t off = 0;
    auto alloc = [&](size_t n) { float* p = Wp + off; off += n; return p; };
    float* A   = alloc((size_t)4096 * 512);          // local residual (f32)
    float* Bsk = alloc((size_t)4096 * 512);          // skip
    float* Cm  = alloc((size_t)2050 * 1024);         // mid residual
    float* Df  = alloc((size_t)2050 * 1024);         // f32 temp
    float* E32 = alloc((size_t)2050 * 3072);         // QKV f32 out
    f16*  Fq   = (f16*)alloc((size_t)1049600);       // 2.1M halves
    f16*  Fk   = (f16*)alloc((size_t)1049600);
    f16*  Fv   = (f16*)alloc((size_t)1049600);
    f16*  Fvt  = (f16*)alloc((size_t)1114112);       // 2.23M halves
    f16*  H1   = (f16*)alloc((size_t)8396800);       // 16.79M halves
    f16*  H2   = (f16*)alloc((size_t)4198400);       // 8.40M halves
    f16*  Wh   = (f16*)alloc((size_t)4194304);       // 8.39M halves
    float* Sma = alloc((size_t)32768);
    (void)ws_size; (void)in_sizes; (void)n_in; (void)out_size;

    float* te   = Sma;
    float* temb = Sma + 2048;
    float* mapx = Sma + 4096;
    float* maph = Sma + 6144;
    float* mapu = Sma + 8192;
    float* mapg = Sma + 12288;
    float* cond = Sma + 14336;
    float* sA   = Sma + 16384;
    float* sF   = Sma + 17408;
    float* pre  = Sma + 18432;

    auto WC = [&](const float* W, int K, int N) {
        wcast<<<dim3(N / 64, K / 64), 256, 0, stream>>>(W, Wh, K, N);
    };
    auto GF = [&](const f16* Aa, const float* res, float* C, int M, int N, int K) {
        gemm_h<false><<<dim3(N / 128, (M + 127) / 128), 256, 0, stream>>>(Aa, Wh, res, C, M, N, K);
    };
    auto GH = [&](const f16* Aa, f16* C, int M, int N, int K) {
        gemm_h<true><<<dim3(N / 128, (M + 127) / 128), 256, 0, stream>>>(Aa, Wh, nullptr, C, M, N, K);
    };
    auto gemm32 = [&](const float* Aa, const float* Wt, const float* res,
                      float* C, int M, int N, int K) {
        gemm_f32<<<dim3(N / 128, (M + 127) / 128), 256, 0, stream>>>(Aa, Wt, res, C, M, N, K);
    };

    // ---- patch in ----
    patch_in_gather<<<(BB * S0 * 128 + 255) / 256, 256, 0, stream>>>(x, H2);
    WC(patch_in_w, 128, 512);
    GF(H2, nullptr, A, 4096, 512, 128);

    // ---- time embedding + mapping (tiny, f32) ----
    time_embed<<<(BB * MAPD + 255) / 256, 256, 0, stream>>>(t, time_w, te);
    gemm32(te, time_in_w, nullptr, temb, 2, 1024, 1024);
    rmsnorm_k<float><<<2, 256, 0, stream>>>(temb, map_in_s, mapx, 1024, 2, 0.f);
    for (int l = 0; l < 2; ++l) {
        rmsnorm_k<float><<<2, 256, 0, stream>>>(mapx, map_norm_s + (size_t)l * 1024, maph, 1024, 2, 0.f);
        gemm32(maph, map_up_w + (size_t)l * 1024 * 2048, nullptr, mapu, 2, 2048, 1024);
        glu_k<<<(2 * 1024 + 255) / 256, 256, 0, stream>>>(mapu, mapg, 2 * 1024, 1024, 0);
        gemm32(mapg, map_down_w + (size_t)l * 1024 * 1024, mapx, mapx, 2, 1024, 1024);
    }
    rmsnorm_k<float><<<2, 256, 0, stream>>>(mapx, map_out_s, cond, 1024, 2, 0.f);

    // ---- local level (shared for down/up) ----
    auto run_local = [&](const float* anorm, const float* qkvw, const float* ow,
                         const float* fnorm, const float* ff1, const float* ff2) {
        for (int l = 0; l < 2; ++l) {
            gemm32(cond, anorm + (size_t)l * 1024 * 512, nullptr, sA, 2, 512, 1024);
            rmsnorm_k<f16><<<4096, 256, 0, stream>>>(A, sA, H2, 512, 2048, 1.f);
            WC(qkvw + (size_t)l * 512 * 1536, 512, 1536);
            GF(H2, nullptr, E32, 4096, 1536, 512);
            qkv_split_rope<<<(BB * S0 * HDN * 32 + 255) / 256, 256, 0, stream>>>(E32, Fq, Fk, Fv, S0, HDN);
            vtrans<<<dim3(S0 / 64, BB * HDN), 256, 0, stream>>>(Fv, Fvt, S0, S0);
            fattn<<<dim3(S0 / 128, BB * HDN), 256, 0, stream>>>(Fq, Fk, Fvt, H2, S0, S0, HDN, WIN);
            WC(ow + (size_t)l * 512 * 512, 512, 512);
            GF(H2, A, A, 4096, 512, 512);
            gemm32(cond, fnorm + (size_t)l * 1024 * 512, nullptr, sF, 2, 512, 1024);
            rmsnorm_k<f16><<<4096, 256, 0, stream>>>(A, sF, H2, 512, 2048, 1.f);
            WC(ff1 + (size_t)l * 512 * 2048, 512, 2048);
            GH(H2, H1, 4096, 2048, 512);
            glu_h8<<<(4096 * 128 + 255) / 256, 256, 0, stream>>>(H1, H2, (size_t)4096 * 128, 128, 0);
            WC(ff2 + (size_t)l * 1024 * 512, 1024, 512);
            GF(H2, A, A, 4096, 512, 1024);
        }
    };
    run_local(dn_anorm_w, dn_qkv_w, dn_o_w, dn_fnorm_w, dn_ff1_w, dn_ff2_w);

    // ---- skip save, merge, mid prep ----
    hipMemcpyAsync(Bsk, A, (size_t)4096 * 512 * 4, hipMemcpyDeviceToDevice, stream);
    token_merge_gather<<<(BB * 1024 * 1024 + 255) / 256, 256, 0, stream>>>(A, H2);
    WC(merge_w, 1024, 1024);
    GH(H2, H1, 2048, 1024, 1024);
    WC(mid_pin_w, 1024, 1024);
    GF(H1, nullptr, Df, 2048, 1024, 1024);
    gemm32(cond, mid_map_w, nullptr, pre, 2, 1024, 1024);
    concat_mid<<<(BB * SM * W1 + 255) / 256, 256, 0, stream>>>(pre, Df, Cm);

    // ---- mid level ----
    for (int l = 0; l < 4; ++l) {
        layernorm_k<<<2050, 256, 0, stream>>>(Cm, mid_ln1_g + (size_t)l * 1024,
                                              mid_ln1_b + (size_t)l * 1024, H2, 1024);
        WC(mid_qkv_w + (size_t)l * 1024 * 3072, 1024, 3072);
        GF(H2, nullptr, E32, 2050, 3072, 1024);
        qkv_split_rope<<<(BB * SM * HMID * 32 + 255) / 256, 256, 0, stream>>>(E32, Fq, Fk, Fv, SM, HMID);
        vtrans<<<dim3(SMP / 64, BB * HMID), 256, 0, stream>>>(Fv, Fvt, SM, SMP);
        fattn<<<dim3(9, BB * HMID), 256, 0, stream>>>(Fq, Fk, Fvt, H2, SM, SMP, HMID, 0);
        WC(mid_o_w + (size_t)l * 1024 * 1024, 1024, 1024);
        GF(H2, Cm, Cm, 2050, 1024, 1024);
        layernorm_k<<<2050, 256, 0, stream>>>(Cm, mid_ln2_g + (size_t)l * 1024,
                                              mid_ln2_b + (size_t)l * 1024, H2, 1024);
        WC(mid_ff1_w + (size_t)l * 1024 * 8192, 1024, 8192);
        GH(H2, H1, 2050, 8192, 1024);
        glu_h8<<<(int)(((size_t)2050 * 512 + 255) / 256), 256, 0, stream>>>(H1, H2, (size_t)2050 * 512, 512, 1);
        WC(mid_ff2_w + (size_t)l * 4096 * 1024, 4096, 1024);
        GF(H2, Cm, Cm, 2050, 1024, 4096);
    }
    layernorm_k<<<2050, 256, 0, stream>>>(Cm, mid_fn_g, mid_fn_b, H2, 1024);

    // ---- pout + token split + lerp skip ----
    WC(mid_pout_w, 1024, 1024);
    GH(H2, H1, 2050, 1024, 1024);
    gather_drop<<<(BB * 1024 * W1 + 255) / 256, 256, 0, stream>>>(H1, H2);
    WC(split_w, 1024, 1024);
    GF(H2, nullptr, Df, 2048, 1024, 1024);
    split_scatter_lerp<<<(BB * S0 * W0 + 255) / 256, 256, 0, stream>>>(Df, Bsk, split_fac, A);

    // ---- up level ----
    run_local(up_anorm_w, up_qkv_w, up_o_w, up_fnorm_w, up_ff1_w, up_ff2_w);

    // ---- out ----
    rmsnorm_k<f16><<<4096, 256, 0, stream>>>(A, out_norm_s, H2, 512, 4096, 0.f);
    WC(patch_out_w, 512, 128);
    GF(H2, nullptr, Df, 4096, 128, 512);
    patch_out_scatter<<<(BB * CIO * TT + 255) / 256, 256, 0, stream>>>(Df, (float*)d_out);
}

// Round 4
// 2649.454 us; speedup vs baseline: 7.0703x; 1.7764x over previous
//
#include <hip/hip_runtime.h>
#include <math.h>

// ---------------- constants ----------------
#define BB   2
#define CIO  64
#define TT   4096
#define S0   2048      // local level seq len
#define W0   512
#define HDN  8
#define SM   1025      // mid seq len (with prepended token)
#define SMP  1088      // padded mid seq (17*64)
#define W1   1024
#define HMID 16
#define WIN  128
#define NW   16        // S0 / WIN
#define MAPD 1024
#define KSPL 16        // split-K factor for M=2 GEMV

typedef _Float16 f16;
typedef _Float16 half8 __attribute__((ext_vector_type(8)));
typedef _Float16 half2v __attribute__((ext_vector_type(2)));
typedef float floatx4 __attribute__((ext_vector_type(4)));

// ---------------- device helpers ----------------
__device__ __forceinline__ float gelu_tanh(float x) {
    float x3 = x * x * x;
    return 0.5f * x * (1.f + tanhf(0.7978845608028654f * (x + 0.044715f * x3)));
}

// ---------------- weight transpose-cast: W[K][N] f32 -> Wt[N][K] f16 ------
__global__ __launch_bounds__(256) void wcast(
    const float* __restrict__ W, f16* __restrict__ Wt, int K, int N) {
    __shared__ float T[64][65];
    const int n0 = blockIdx.x * 64, k0 = blockIdx.y * 64;
    const int tid = threadIdx.x;
    for (int e = tid; e < 4096; e += 256) {
        int r = e >> 6, c = e & 63;
        T[r][c] = W[(size_t)(k0 + r) * N + n0 + c];
    }
    __syncthreads();
    for (int e = tid; e < 2048; e += 256) {
        int r = e >> 5, c2 = (e & 31) * 2;
        half2v p;
        p[0] = (f16)T[c2][r];
        p[1] = (f16)T[c2 + 1][r];
        *(half2v*)(Wt + (size_t)(n0 + r) * K + k0 + c2) = p;
    }
}

// ---------------- MFMA GEMM: C = (res?) + A[MxK]f16 @ Bt[NxK]f16^T --------
template<bool HOUT>
__global__ __launch_bounds__(256) void gemm_h(
    const f16* __restrict__ A, const f16* __restrict__ Bt,
    const float* __restrict__ res, void* __restrict__ Cv,
    int M, int N, int K) {
    __shared__ __align__(16) f16 As[128 * 32];
    __shared__ __align__(16) f16 Bs[128 * 32];
    const int tid = threadIdx.x;
    const int wv = tid >> 6, ln = tid & 63;
    const int bm = blockIdx.y * 128, bn = blockIdx.x * 128;
    const int wr = (wv >> 1) * 64, wc = (wv & 1) * 64;
    floatx4 acc[4][4];
#pragma unroll
    for (int m = 0; m < 4; ++m)
#pragma unroll
        for (int n = 0; n < 4; ++n) acc[m][n] = (floatx4)0.f;
    const int r = ln & 15, kc = (ln >> 4) * 8;
    for (int k0 = 0; k0 < K; k0 += 32) {
#pragma unroll
        for (int i = 0; i < 2; ++i) {
            int off = i * 4096 + wv * 1024 + ln * 16;
            int row = off >> 6, kb = (off & 63) >> 1;
            int gr = bm + row; gr = gr < M ? gr : M - 1;
            f16* gp = const_cast<f16*>(A) + (size_t)gr * K + k0 + kb;
            __builtin_amdgcn_global_load_lds(
                (__attribute__((address_space(1))) void*)gp,
                (__attribute__((address_space(3))) void*)(As + i * 2048 + wv * 512),
                16, 0, 0);
            f16* gq = const_cast<f16*>(Bt) + (size_t)(bn + row) * K + k0 + kb;
            __builtin_amdgcn_global_load_lds(
                (__attribute__((address_space(1))) void*)gq,
                (__attribute__((address_space(3))) void*)(Bs + i * 2048 + wv * 512),
                16, 0, 0);
        }
        __syncthreads();
        half8 af[4], bf[4];
#pragma unroll
        for (int m = 0; m < 4; ++m)
            af[m] = *(const half8*)(As + (wr + m * 16 + r) * 32 + kc);
#pragma unroll
        for (int n = 0; n < 4; ++n)
            bf[n] = *(const half8*)(Bs + (wc + n * 16 + r) * 32 + kc);
#pragma unroll
        for (int m = 0; m < 4; ++m)
#pragma unroll
            for (int n = 0; n < 4; ++n)
                acc[m][n] = __builtin_amdgcn_mfma_f32_16x16x32_f16(af[m], bf[n], acc[m][n], 0, 0, 0);
        __syncthreads();
    }
    float* Cf = (float*)Cv;
    f16*   Ch = (f16*)Cv;
#pragma unroll
    for (int m = 0; m < 4; ++m) {
        int rbase = bm + wr + m * 16 + ((ln >> 4) << 2);
#pragma unroll
        for (int j = 0; j < 4; ++j) {
            int row = rbase + j;
            if (row < M) {
                size_t ro = (size_t)row * N;
#pragma unroll
                for (int n = 0; n < 4; ++n) {
                    int col = bn + wc + n * 16 + (ln & 15);
                    float v = acc[m][n][j];
                    if (HOUT) Ch[ro + col] = (f16)v;
                    else      Cf[ro + col] = v + (res ? res[ro + col] : 0.f);
                }
            }
        }
    }
}

// ---------------- split-K GEMV for M=2: C[2][N] = A[2][K] @ W[K][N] -------
__global__ __launch_bounds__(256) void gemv2_part(
    const float* __restrict__ A, const float* __restrict__ W,
    float* __restrict__ P, int N, int K) {
    int n = blockIdx.x * 256 + threadIdx.x;
    if (n >= N) return;
    int Kc = K / KSPL;
    int k0 = blockIdx.y * Kc;
    float acc0 = 0.f, acc1 = 0.f;
    const float* Wp = W + (size_t)k0 * N + n;
    const float* a0 = A + k0;
    const float* a1 = A + K + k0;
#pragma unroll 4
    for (int k = 0; k < Kc; ++k) {
        float w = Wp[(size_t)k * N];
        acc0 = fmaf(a0[k], w, acc0);
        acc1 = fmaf(a1[k], w, acc1);
    }
    P[((size_t)blockIdx.y * 2 + 0) * N + n] = acc0;
    P[((size_t)blockIdx.y * 2 + 1) * N + n] = acc1;
}

__global__ __launch_bounds__(256) void gemv2_red(
    const float* __restrict__ P, const float* __restrict__ res,
    float* __restrict__ C, int N) {
    int g = blockIdx.x * 256 + threadIdx.x;
    if (g >= 2 * N) return;
    int m = g / N, n = g - m * N;
    float s = res ? res[g] : 0.f;
#pragma unroll
    for (int ky = 0; ky < KSPL; ++ky)
        s += P[((size_t)ky * 2 + m) * N + n];
    C[g] = s;
}

// ---------------- norms ----------------
__device__ __forceinline__ void stf(float* p, float v) { *p = v; }
__device__ __forceinline__ void stf(f16* p, float v)   { *p = (f16)v; }

template<typename TO>
__global__ __launch_bounds__(256) void rmsnorm_k(
    const float* __restrict__ X, const float* __restrict__ scale,
    TO* __restrict__ Y, int C, int rows_per_group, float sadd) {
    int row = blockIdx.x, tid = threadIdx.x;
    const float* x = X + (size_t)row * C;
    float v[8];
    int cnt = C >> 8;
    float ss = 0.f;
    for (int i = 0; i < cnt; ++i) { v[i] = x[tid + (i << 8)]; ss += v[i] * v[i]; }
    __shared__ float red[256];
    red[tid] = ss; __syncthreads();
    for (int s2 = 128; s2; s2 >>= 1) { if (tid < s2) red[tid] += red[tid + s2]; __syncthreads(); }
    float inv = rsqrtf(red[0] / (float)C + 1e-6f);
    const float* sc = scale + (size_t)(row / rows_per_group) * C;
    TO* y = Y + (size_t)row * C;
    for (int i = 0; i < cnt; ++i) {
        int c = tid + (i << 8);
        stf(&y[c], v[i] * (sadd + sc[c]) * inv);
    }
}

__global__ __launch_bounds__(256) void layernorm_k(
    const float* __restrict__ X, const float* __restrict__ g,
    const float* __restrict__ bta, f16* __restrict__ Y, int C) {
    int row = blockIdx.x, tid = threadIdx.x;
    const float* x = X + (size_t)row * C;
    float v[8];
    int cnt = C >> 8;
    float s = 0.f;
    for (int i = 0; i < cnt; ++i) { v[i] = x[tid + (i << 8)]; s += v[i]; }
    __shared__ float red[256];
    red[tid] = s; __syncthreads();
    for (int s2 = 128; s2; s2 >>= 1) { if (tid < s2) red[tid] += red[tid + s2]; __syncthreads(); }
    float m = red[0] / (float)C;
    __syncthreads();
    float s2s = 0.f;
    for (int i = 0; i < cnt; ++i) { float d = v[i] - m; s2s += d * d; }
    red[tid] = s2s; __syncthreads();
    for (int s2 = 128; s2; s2 >>= 1) { if (tid < s2) red[tid] += red[tid + s2]; __syncthreads(); }
    float inv = rsqrtf(red[0] / (float)C + 1e-5f);
    f16* y = Y + (size_t)row * C;
    for (int i = 0; i < cnt; ++i) {
        int c = tid + (i << 8);
        y[c] = (f16)((v[i] - m) * inv * g[c] + bta[c]);
    }
}

// ---------------- GLU ----------------
__global__ __launch_bounds__(256) void glu_k(
    const float* __restrict__ U, float* __restrict__ Yo,
    size_t total, int F, int mode) {
    size_t gidx = (size_t)blockIdx.x * 256 + threadIdx.x;
    if (gidx >= total) return;
    size_t r = gidx / (size_t)F;
    int c = (int)(gidx - r * F);
    const float* u = U + r * (size_t)(2 * F);
    float a = u[c], gg = u[F + c];
    float act = (mode == 0) ? gelu_tanh(gg) : gg / (1.f + expf(-gg));
    Yo[gidx] = a * act;
}

__global__ __launch_bounds__(256) void glu_h8(
    const f16* __restrict__ U, f16* __restrict__ Yo,
    size_t total8, int F8, int mode) {
    size_t gi = (size_t)blockIdx.x * 256 + threadIdx.x;
    if (gi >= total8) return;
    size_t r = gi / (size_t)F8;
    int c = (int)(gi - r * (size_t)F8);
    const f16* u = U + r * (size_t)F8 * 16;
    half8 av = *(const half8*)(u + c * 8);
    half8 gv = *(const half8*)(u + F8 * 8 + c * 8);
    half8 y;
#pragma unroll
    for (int j = 0; j < 8; ++j) {
        float a = (float)av[j], gg = (float)gv[j];
        float act = (mode == 0) ? gelu_tanh(gg) : gg / (1.f + __expf(-gg));
        y[j] = (f16)(a * act);
    }
    *(half8*)(Yo + gi * 8) = y;
}

// ---------------- QKV split + RoPE (+ q scale 1/8), f16 out ---------------
__global__ __launch_bounds__(256) void qkv_split_rope(
    const float* __restrict__ QKV, f16* __restrict__ Qo,
    f16* __restrict__ Ko, f16* __restrict__ Vo, int S, int H) {
    int g = blockIdx.x * 256 + threadIdx.x;
    int total = BB * S * H * 32;
    if (g >= total) return;
    int i = g & 31;
    int tix = g >> 5;
    int h = tix % H; tix /= H;
    int s = tix % S; int b = tix / S;
    int C = H * 64;
    const float* base = QKV + (size_t)(b * S + s) * 3 * C + h * 64;
    float q1 = base[i], q2 = base[32 + i];
    float k1 = base[C + i], k2 = base[C + 32 + i];
    float v1 = base[2 * C + i], v2 = base[2 * C + 32 + i];
    float inv = expf(-(float)i * 0.28782313662425575f);
    float ang = (float)s * inv;
    float sn, cs;
    sincosf(ang, &sn, &cs);
    size_t o = ((size_t)(b * H + h) * S + s) * 64 + i;
    Qo[o]      = (f16)((q1 * cs - q2 * sn) * 0.125f);
    Qo[o + 32] = (f16)((q2 * cs + q1 * sn) * 0.125f);
    Ko[o]      = (f16)(k1 * cs - k2 * sn);
    Ko[o + 32] = (f16)(k2 * cs + k1 * sn);
    Vo[o]      = (f16)v1;
    Vo[o + 32] = (f16)v2;
}

// ---------------- V transpose: V[bh][S][64] -> Vt[bh][64][Spad] -----------
__global__ __launch_bounds__(256) void vtrans(
    const f16* __restrict__ V, f16* __restrict__ Vt, int S, int Spad) {
    __shared__ f16 T[64][72];
    const int tid = threadIdx.x;
    const int k0 = blockIdx.x * 64;
    const f16* Vb = V + (size_t)blockIdx.y * S * 64;
    f16* Vtb = Vt + (size_t)blockIdx.y * 64 * Spad;
    for (int c = tid; c < 512; c += 256) {
        int kk = c >> 3, d8 = (c & 7) * 8;
        int kg = k0 + kk; kg = kg < S ? kg : S - 1;
        half8 v = *(const half8*)(Vb + (size_t)kg * 64 + d8);
        if (k0 + kk >= S) {
#pragma unroll
            for (int j = 0; j < 8; ++j) v[j] = (f16)0.f;
        }
        *(half8*)(&T[kk][d8]) = v;
    }
    __syncthreads();
    for (int c = tid; c < 512; c += 256) {
        int d = c >> 3, k8 = (c & 7) * 8;
        half8 o;
#pragma unroll
        for (int j = 0; j < 8; ++j) o[j] = T[k8 + j][d];
        *(half8*)(Vtb + (size_t)d * Spad + k0 + k8) = o;
    }
}

// ---------------- fused flash attention -----------------------------------
__global__ __launch_bounds__(256) void fattn(
    const f16* __restrict__ Q, const f16* __restrict__ K,
    const f16* __restrict__ Vt, f16* __restrict__ O,
    int S, int Spad, int H, int win) {
    __shared__ __align__(16) f16 Ks[64][72];
    __shared__ __align__(16) f16 Vs[64][72];
    __shared__ __align__(16) f16 Ps[4][32][72];
    const int tid = threadIdx.x;
    const int wv = tid >> 6, ln = tid & 63;
    const int r15 = ln & 15, g = ln >> 4;
    const int bh = blockIdx.y;
    const int b = bh / H, h = bh % H;
    const int q0 = (int)blockIdx.x * 128;
    const f16* Qb = Q + (size_t)bh * S * 64;
    const f16* Kb = K + (size_t)bh * S * 64;
    const f16* Vtb = Vt + (size_t)bh * 64 * Spad;

    half8 aq[2][2];
#pragma unroll
    for (int m = 0; m < 2; ++m) {
        int q = q0 + wv * 32 + m * 16 + r15;
        q = q < S ? q : S - 1;
#pragma unroll
        for (int ks = 0; ks < 2; ++ks)
            aq[m][ks] = *(const half8*)(Qb + (size_t)q * 64 + ks * 32 + g * 8);
    }
    floatx4 o[2][4];
#pragma unroll
    for (int m = 0; m < 2; ++m)
#pragma unroll
        for (int n = 0; n < 4; ++n) o[m][n] = (floatx4)0.f;
    float mst[2][4], lst[2][4];
#pragma unroll
    for (int m = 0; m < 2; ++m)
#pragma unroll
        for (int j = 0; j < 4; ++j) { mst[m][j] = -3.0e38f; lst[m][j] = 0.f; }

    int klo = 0, khi = S;
    if (win) {
        int n = (int)blockIdx.x;
        klo = (n - 1) * win; if (klo < 0) klo = 0;
        khi = (n + 2) * win; if (khi > S) khi = S;
    }
    for (int kb = klo; kb < khi; kb += 64) {
        __syncthreads();
#pragma unroll
        for (int i = 0; i < 2; ++i) {
            int c = tid + i * 256;
            int rr = c >> 3, c8 = (c & 7) * 8;
            int kg = kb + rr; kg = kg < S ? kg : S - 1;
            *(half8*)(&Ks[rr][c8]) = *(const half8*)(Kb + (size_t)kg * 64 + c8);
            *(half8*)(&Vs[rr][c8]) = *(const half8*)(Vtb + (size_t)rr * Spad + kb + c8);
        }
        __syncthreads();
        floatx4 s[2][4];
#pragma unroll
        for (int m = 0; m < 2; ++m)
#pragma unroll
            for (int n = 0; n < 4; ++n) s[m][n] = (floatx4)0.f;
#pragma unroll
        for (int ks = 0; ks < 2; ++ks) {
            half8 bk[4];
#pragma unroll
            for (int n = 0; n < 4; ++n)
                bk[n] = *(const half8*)(&Ks[n * 16 + r15][ks * 32 + g * 8]);
#pragma unroll
            for (int m = 0; m < 2; ++m)
#pragma unroll
                for (int n = 0; n < 4; ++n)
                    s[m][n] = __builtin_amdgcn_mfma_f32_16x16x32_f16(aq[m][ks], bk[n], s[m][n], 0, 0, 0);
        }
        if (kb + 64 > S) {
#pragma unroll
            for (int n = 0; n < 4; ++n)
                if (kb + n * 16 + r15 >= S) {
#pragma unroll
                    for (int m = 0; m < 2; ++m) s[m][n] = (floatx4)(-3.0e38f);
                }
        }
#pragma unroll
        for (int m = 0; m < 2; ++m) {
#pragma unroll
            for (int j = 0; j < 4; ++j) {
                float tm = fmaxf(fmaxf(s[m][0][j], s[m][1][j]), fmaxf(s[m][2][j], s[m][3][j]));
                tm = fmaxf(tm, __shfl_xor(tm, 1));
                tm = fmaxf(tm, __shfl_xor(tm, 2));
                tm = fmaxf(tm, __shfl_xor(tm, 4));
                tm = fmaxf(tm, __shfl_xor(tm, 8));
                float mn = fmaxf(mst[m][j], tm);
                float sc = __expf(mst[m][j] - mn);
                mst[m][j] = mn;
                float ts = 0.f;
#pragma unroll
                for (int n = 0; n < 4; ++n) {
                    float p = __expf(s[m][n][j] - mn);
                    s[m][n][j] = p;
                    ts += p;
                }
                ts += __shfl_xor(ts, 1);
                ts += __shfl_xor(ts, 2);
                ts += __shfl_xor(ts, 4);
                ts += __shfl_xor(ts, 8);
                lst[m][j] = lst[m][j] * sc + ts;
#pragma unroll
                for (int n = 0; n < 4; ++n) o[m][n][j] *= sc;
            }
        }
#pragma unroll
        for (int m = 0; m < 2; ++m)
#pragma unroll
            for (int n = 0; n < 4; ++n)
#pragma unroll
                for (int j = 0; j < 4; ++j)
                    Ps[wv][m * 16 + g * 4 + j][n * 16 + r15] = (f16)s[m][n][j];
#pragma unroll
        for (int ks = 0; ks < 2; ++ks) {
            half8 pa[2], bv[4];
#pragma unroll
            for (int m = 0; m < 2; ++m)
                pa[m] = *(const half8*)(&Ps[wv][m * 16 + r15][ks * 32 + g * 8]);
#pragma unroll
            for (int n = 0; n < 4; ++n)
                bv[n] = *(const half8*)(&Vs[n * 16 + r15][ks * 32 + g * 8]);
#pragma unroll
            for (int m = 0; m < 2; ++m)
#pragma unroll
                for (int n = 0; n < 4; ++n)
                    o[m][n] = __builtin_amdgcn_mfma_f32_16x16x32_f16(pa[m], bv[n], o[m][n], 0, 0, 0);
        }
    }
    const int HC = H * 64;
#pragma unroll
    for (int m = 0; m < 2; ++m)
#pragma unroll
        for (int j = 0; j < 4; ++j) {
            int q = q0 + wv * 32 + m * 16 + g * 4 + j;
            if (q < S) {
                float inv = 1.f / lst[m][j];
                size_t ro = ((size_t)b * S + q) * HC + h * 64;
#pragma unroll
                for (int n = 0; n < 4; ++n)
                    O[ro + n * 16 + r15] = (f16)(o[m][n][j] * inv);
            }
        }
}

// ---------------- small glue kernels ----------------
__global__ __launch_bounds__(256) void patch_in_gather(
    const float* __restrict__ x, f16* __restrict__ out) {
    int g = blockIdx.x * 256 + threadIdx.x;
    if (g >= BB * S0 * 128) return;
    int k = g & 127;
    int n = (g >> 7) & (S0 - 1);
    int b = g >> 18;
    out[g] = (f16)x[(size_t)b * CIO * TT + (size_t)(k >> 1) * TT + 2 * n + (k & 1)];
}

__global__ __launch_bounds__(256) void time_embed(
    const float* __restrict__ t, const float* __restrict__ tw,
    float* __restrict__ te) {
    int g = blockIdx.x * 256 + threadIdx.x;
    if (g >= BB * MAPD) return;
    int b = g / MAPD, j = g % MAPD;
    float w = tw[(j < 512) ? j : j - 512];
    float ang = 6.283185307179586f * t[b] * w;
    te[g] = (j < 512) ? cosf(ang) : sinf(ang);
}

__global__ __launch_bounds__(256) void token_merge_gather(
    const float* __restrict__ A, f16* __restrict__ out) {
    int g = blockIdx.x * 256 + threadIdx.x;
    if (g >= BB * 1024 * 1024) return;
    int k = g & 1023;
    int n = (g >> 10) & 1023;
    int b = g >> 20;
    out[g] = (f16)A[((size_t)b * S0 + 2 * n + (k & 1)) * W0 + (k >> 1)];
}

__global__ __launch_bounds__(256) void concat_mid(
    const float* __restrict__ pre, const float* __restrict__ Dsrc,
    float* __restrict__ Cm) {
    int g = blockIdx.x * 256 + threadIdx.x;
    if (g >= BB * SM * W1) return;
    int c = g & 1023;
    int row = g >> 10;
    int b = row / SM, r = row % SM;
    Cm[g] = (r == 0) ? pre[b * W1 + c]
                     : Dsrc[((size_t)b * 1024 + r - 1) * W1 + c];
}

__global__ __launch_bounds__(256) void gather_drop(
    const f16* __restrict__ Dsrc, f16* __restrict__ out) {
    int g = blockIdx.x * 256 + threadIdx.x;
    if (g >= BB * 1024 * W1) return;
    int c = g & 1023;
    int n = (g >> 10) & 1023;
    int b = g >> 20;
    out[g] = Dsrc[((size_t)b * SM + 1 + n) * W1 + c];
}

__global__ __launch_bounds__(256) void split_scatter_lerp(
    const float* __restrict__ y, const float* __restrict__ skip,
    const float* __restrict__ fac, float* __restrict__ xo) {
    int g = blockIdx.x * 256 + threadIdx.x;
    if (g >= BB * S0 * W0) return;
    int c = g & 511;
    int tk = (g >> 9) & (S0 - 1);
    int b = g >> 20;
    float yv = y[((size_t)b * 1024 + (tk >> 1)) * W1 + (c * 2 + (tk & 1))];
    float sk = skip[g];
    xo[g] = sk + fac[0] * (yv - sk);
}

__global__ __launch_bounds__(256) void patch_out_scatter(
    const float* __restrict__ y, float* __restrict__ out) {
    int g = blockIdx.x * 256 + threadIdx.x;
    if (g >= BB * CIO * TT) return;
    int tk = g & (TT - 1);
    int c = (g >> 12) & 63;
    int b = g >> 18;
    out[g] = y[((size_t)b * S0 + (tk >> 1)) * 128 + (c * 2 + (tk & 1))];
}

// ---------------- host orchestration ----------------
extern "C" void kernel_launch(void* const* d_in, const int* in_sizes, int n_in,
                              void* d_out, int out_size, void* d_ws, size_t ws_size,
                              hipStream_t stream) {
    const float* x          = (const float*)d_in[0];
    const float* t          = (const float*)d_in[1];
    const float* time_w     = (const float*)d_in[2];
    const float* time_in_w  = (const float*)d_in[3];
    const float* map_in_s   = (const float*)d_in[4];
    const float* map_norm_s = (const float*)d_in[5];
    const float* map_up_w   = (const float*)d_in[6];
    const float* map_down_w = (const float*)d_in[7];
    const float* map_out_s  = (const float*)d_in[8];
    const float* patch_in_w = (const float*)d_in[9];
    const float* dn_anorm_w = (const float*)d_in[10];
    const float* dn_qkv_w   = (const float*)d_in[11];
    const float* dn_o_w     = (const float*)d_in[12];
    const float* dn_fnorm_w = (const float*)d_in[13];
    const float* dn_ff1_w   = (const float*)d_in[14];
    const float* dn_ff2_w   = (const float*)d_in[15];
    const float* merge_w    = (const float*)d_in[16];
    const float* mid_map_w  = (const float*)d_in[17];
    const float* mid_pin_w  = (const float*)d_in[18];
    const float* mid_pout_w = (const float*)d_in[19];
    const float* mid_ln1_g  = (const float*)d_in[20];
    const float* mid_ln1_b  = (const float*)d_in[21];
    const float* mid_qkv_w  = (const float*)d_in[22];
    const float* mid_o_w    = (const float*)d_in[23];
    const float* mid_ln2_g  = (const float*)d_in[24];
    const float* mid_ln2_b  = (const float*)d_in[25];
    const float* mid_ff1_w  = (const float*)d_in[26];
    const float* mid_ff2_w  = (const float*)d_in[27];
    const float* mid_fn_g   = (const float*)d_in[28];
    const float* mid_fn_b   = (const float*)d_in[29];
    const float* split_w    = (const float*)d_in[30];
    const float* split_fac  = (const float*)d_in[31];
    const float* up_anorm_w = (const float*)d_in[32];
    const float* up_qkv_w   = (const float*)d_in[33];
    const float* up_o_w     = (const float*)d_in[34];
    const float* up_fnorm_w = (const float*)d_in[35];
    const float* up_ff1_w   = (const float*)d_in[36];
    const float* up_ff2_w   = (const float*)d_in[37];
    const float* out_norm_s = (const float*)d_in[38];
    const float* patch_out_w= (const float*)d_in[39];

    float* Wp = (float*)d_ws;
    size_t off = 0;
    auto alloc = [&](size_t n) { float* p = Wp + off; off += n; return p; };
    float* A   = alloc((size_t)4096 * 512);          // local residual (f32)
    float* Bsk = alloc((size_t)4096 * 512);          // skip
    float* Cm  = alloc((size_t)2050 * 1024);         // mid residual
    float* Df  = alloc((size_t)2050 * 1024);         // f32 temp
    float* E32 = alloc((size_t)2050 * 3072);         // QKV f32 out
    f16*  Fq   = (f16*)alloc((size_t)1049600);
    f16*  Fk   = (f16*)alloc((size_t)1049600);
    f16*  Fv   = (f16*)alloc((size_t)1049600);
    f16*  Fvt  = (f16*)alloc((size_t)1114112);
    f16*  H1   = (f16*)alloc((size_t)8396800);
    f16*  H2   = (f16*)alloc((size_t)4198400);
    f16*  Wh   = (f16*)alloc((size_t)4194304);
    float* Pb  = alloc((size_t)KSPL * 2 * 2048);     // gemv2 partials
    float* Sma = alloc((size_t)32768);
    (void)ws_size; (void)in_sizes; (void)n_in; (void)out_size;

    float* te   = Sma;
    float* temb = Sma + 2048;
    float* mapx = Sma + 4096;
    float* maph = Sma + 6144;
    float* mapu = Sma + 8192;
    float* mapg = Sma + 12288;
    float* cond = Sma + 14336;
    float* sA   = Sma + 16384;
    float* sF   = Sma + 17408;
    float* pre  = Sma + 18432;

    auto WC = [&](const float* W, int K, int N) {
        wcast<<<dim3(N / 64, K / 64), 256, 0, stream>>>(W, Wh, K, N);
    };
    auto GF = [&](const f16* Aa, const float* res, float* C, int M, int N, int K) {
        gemm_h<false><<<dim3(N / 128, (M + 127) / 128), 256, 0, stream>>>(Aa, Wh, res, C, M, N, K);
    };
    auto GH = [&](const f16* Aa, f16* C, int M, int N, int K) {
        gemm_h<true><<<dim3(N / 128, (M + 127) / 128), 256, 0, stream>>>(Aa, Wh, nullptr, C, M, N, K);
    };
    // M=2 GEMV: C[2][N] = A[2][K] @ W[K][N] (+res)
    auto gemv2 = [&](const float* Aa, const float* W, const float* res,
                     float* C, int N, int K) {
        gemv2_part<<<dim3((N + 255) / 256, KSPL), 256, 0, stream>>>(Aa, W, Pb, N, K);
        gemv2_red<<<(2 * N + 255) / 256, 256, 0, stream>>>(Pb, res, C, N);
    };

    // ---- patch in ----
    patch_in_gather<<<(BB * S0 * 128 + 255) / 256, 256, 0, stream>>>(x, H2);
    WC(patch_in_w, 128, 512);
    GF(H2, nullptr, A, 4096, 512, 128);

    // ---- time embedding + mapping (tiny, f32) ----
    time_embed<<<(BB * MAPD + 255) / 256, 256, 0, stream>>>(t, time_w, te);
    gemv2(te, time_in_w, nullptr, temb, 1024, 1024);
    rmsnorm_k<float><<<2, 256, 0, stream>>>(temb, map_in_s, mapx, 1024, 2, 0.f);
    for (int l = 0; l < 2; ++l) {
        rmsnorm_k<float><<<2, 256, 0, stream>>>(mapx, map_norm_s + (size_t)l * 1024, maph, 1024, 2, 0.f);
        gemv2(maph, map_up_w + (size_t)l * 1024 * 2048, nullptr, mapu, 2048, 1024);
        glu_k<<<(2 * 1024 + 255) / 256, 256, 0, stream>>>(mapu, mapg, 2 * 1024, 1024, 0);
        gemv2(mapg, map_down_w + (size_t)l * 1024 * 1024, mapx, mapx, 1024, 1024);
    }
    rmsnorm_k<float><<<2, 256, 0, stream>>>(mapx, map_out_s, cond, 1024, 2, 0.f);

    // ---- local level (shared for down/up) ----
    auto run_local = [&](const float* anorm, const float* qkvw, const float* ow,
                         const float* fnorm, const float* ff1, const float* ff2) {
        for (int l = 0; l < 2; ++l) {
            gemv2(cond, anorm + (size_t)l * 1024 * 512, nullptr, sA, 512, 1024);
            rmsnorm_k<f16><<<4096, 256, 0, stream>>>(A, sA, H2, 512, 2048, 1.f);
            WC(qkvw + (size_t)l * 512 * 1536, 512, 1536);
            GF(H2, nullptr, E32, 4096, 1536, 512);
            qkv_split_rope<<<(BB * S0 * HDN * 32 + 255) / 256, 256, 0, stream>>>(E32, Fq, Fk, Fv, S0, HDN);
            vtrans<<<dim3(S0 / 64, BB * HDN), 256, 0, stream>>>(Fv, Fvt, S0, S0);
            fattn<<<dim3(S0 / 128, BB * HDN), 256, 0, stream>>>(Fq, Fk, Fvt, H2, S0, S0, HDN, WIN);
            WC(ow + (size_t)l * 512 * 512, 512, 512);
            GF(H2, A, A, 4096, 512, 512);
            gemv2(cond, fnorm + (size_t)l * 1024 * 512, nullptr, sF, 512, 1024);
            rmsnorm_k<f16><<<4096, 256, 0, stream>>>(A, sF, H2, 512, 2048, 1.f);
            WC(ff1 + (size_t)l * 512 * 2048, 512, 2048);
            GH(H2, H1, 4096, 2048, 512);
            glu_h8<<<(4096 * 128 + 255) / 256, 256, 0, stream>>>(H1, H2, (size_t)4096 * 128, 128, 0);
            WC(ff2 + (size_t)l * 1024 * 512, 1024, 512);
            GF(H2, A, A, 4096, 512, 1024);
        }
    };
    run_local(dn_anorm_w, dn_qkv_w, dn_o_w, dn_fnorm_w, dn_ff1_w, dn_ff2_w);

    // ---- skip save, merge, mid prep ----
    hipMemcpyAsync(Bsk, A, (size_t)4096 * 512 * 4, hipMemcpyDeviceToDevice, stream);
    token_merge_gather<<<(BB * 1024 * 1024 + 255) / 256, 256, 0, stream>>>(A, H2);
    WC(merge_w, 1024, 1024);
    GH(H2, H1, 2048, 1024, 1024);
    WC(mid_pin_w, 1024, 1024);
    GF(H1, nullptr, Df, 2048, 1024, 1024);
    gemv2(cond, mid_map_w, nullptr, pre, 1024, 1024);
    concat_mid<<<(BB * SM * W1 + 255) / 256, 256, 0, stream>>>(pre, Df, Cm);

    // ---- mid level ----
    for (int l = 0; l < 4; ++l) {
        layernorm_k<<<2050, 256, 0, stream>>>(Cm, mid_ln1_g + (size_t)l * 1024,
                                              mid_ln1_b + (size_t)l * 1024, H2, 1024);
        WC(mid_qkv_w + (size_t)l * 1024 * 3072, 1024, 3072);
        GF(H2, nullptr, E32, 2050, 3072, 1024);
        qkv_split_rope<<<(BB * SM * HMID * 32 + 255) / 256, 256, 0, stream>>>(E32, Fq, Fk, Fv, SM, HMID);
        vtrans<<<dim3(SMP / 64, BB * HMID), 256, 0, stream>>>(Fv, Fvt, SM, SMP);
        fattn<<<dim3(9, BB * HMID), 256, 0, stream>>>(Fq, Fk, Fvt, H2, SM, SMP, HMID, 0);
        WC(mid_o_w + (size_t)l * 1024 * 1024, 1024, 1024);
        GF(H2, Cm, Cm, 2050, 1024, 1024);
        layernorm_k<<<2050, 256, 0, stream>>>(Cm, mid_ln2_g + (size_t)l * 1024,
                                              mid_ln2_b + (size_t)l * 1024, H2, 1024);
        WC(mid_ff1_w + (size_t)l * 1024 * 8192, 1024, 8192);
        GH(H2, H1, 2050, 8192, 1024);
        glu_h8<<<(int)(((size_t)2050 * 512 + 255) / 256), 256, 0, stream>>>(H1, H2, (size_t)2050 * 512, 512, 1);
        WC(mid_ff2_w + (size_t)l * 4096 * 1024, 4096, 1024);
        GF(H2, Cm, Cm, 2050, 1024, 4096);
    }
    layernorm_k<<<2050, 256, 0, stream>>>(Cm, mid_fn_g, mid_fn_b, H2, 1024);

    // ---- pout + token split + lerp skip ----
    WC(mid_pout_w, 1024, 1024);
    GH(H2, H1, 2050, 1024, 1024);
    gather_drop<<<(BB * 1024 * W1 + 255) / 256, 256, 0, stream>>>(H1, H2);
    WC(split_w, 1024, 1024);
    GF(H2, nullptr, Df, 2048, 1024, 1024);
    split_scatter_lerp<<<(BB * S0 * W0 + 255) / 256, 256, 0, stream>>>(Df, Bsk, split_fac, A);

    // ---- up level ----
    run_local(up_anorm_w, up_qkv_w, up_o_w, up_fnorm_w, up_ff1_w, up_ff2_w);

    // ---- out ----
    rmsnorm_k<f16><<<4096, 256, 0, stream>>>(A, out_norm_s, H2, 512, 4096, 0.f);
    WC(patch_out_w, 512, 128);
    GF(H2, nullptr, Df, 4096, 128, 512);
    patch_out_scatter<<<(BB * CIO * TT + 255) / 256, 256, 0, stream>>>(Df, (float*)d_out);
}

// Round 5
// 2187.033 us; speedup vs baseline: 8.5652x; 1.2114x over previous
//
#include <hip/hip_runtime.h>
#include <math.h>

// ---------------- constants ----------------
#define BB   2
#define CIO  64
#define TT   4096
#define S0   2048      // local level seq len
#define W0   512
#define HDN  8
#define SM   1025      // mid seq len (with prepended token)
#define SMP  1088      // padded mid seq (17*64)
#define W1   1024
#define HMID 16
#define WIN  128
#define NW   16        // S0 / WIN
#define MAPD 1024
#define KSPL 16        // split-K factor for M=2 GEMV
#define PKCAP 8396800L // partial buffer capacity (floats)

typedef _Float16 f16;
typedef _Float16 half8 __attribute__((ext_vector_type(8)));
typedef _Float16 half4v __attribute__((ext_vector_type(4)));
typedef _Float16 half2v __attribute__((ext_vector_type(2)));
typedef float floatx4 __attribute__((ext_vector_type(4)));

// ---------------- device helpers ----------------
__device__ __forceinline__ float gelu_tanh(float x) {
    float x3 = x * x * x;
    return 0.5f * x * (1.f + tanhf(0.7978845608028654f * (x + 0.044715f * x3)));
}

// ---------------- weight transpose-cast: W[K][N] f32 -> Wt[N][K] f16 ------
__global__ __launch_bounds__(256) void wcast(
    const float* __restrict__ W, f16* __restrict__ Wt, int K, int N) {
    __shared__ float T[64][65];
    const int n0 = blockIdx.x * 64, k0 = blockIdx.y * 64;
    const int tid = threadIdx.x;
    for (int e = tid; e < 4096; e += 256) {
        int r = e >> 6, c = e & 63;
        T[r][c] = W[(size_t)(k0 + r) * N + n0 + c];
    }
    __syncthreads();
    for (int e = tid; e < 2048; e += 256) {
        int r = e >> 5, c2 = (e & 31) * 2;
        half2v p;
        p[0] = (f16)T[c2][r];
        p[1] = (f16)T[c2 + 1][r];
        *(half2v*)(Wt + (size_t)(n0 + r) * K + k0 + c2) = p;
    }
}

// ---------------- MFMA GEMM: C = (res?) + A[MxK]f16 @ Bt[NxK]f16^T --------
// OUTM: 0 = f32 out (+res), 1 = f16 out, 2 = split-K f32 partial (grid.z)
// 2-phase double-buffered LDS pipeline + bijective XCD swizzle.
template<int OUTM>
__global__ __launch_bounds__(256) void gemm_h(
    const f16* __restrict__ A, const f16* __restrict__ Bt,
    const float* __restrict__ res, void* __restrict__ Cv,
    int M, int N, int K) {
    __shared__ __align__(16) f16 As[2][4096];
    __shared__ __align__(16) f16 Bs[2][4096];
    const int tid = threadIdx.x;
    const int wv = tid >> 6, ln = tid & 63;
    // bijective XCD swizzle (m204)
    int nwg = gridDim.x * gridDim.y;
    int orig = blockIdx.y * gridDim.x + blockIdx.x;
    int wg = orig;
    if (nwg >= 16) {
        int q = nwg >> 3, r = nwg & 7;
        int xcd = orig & 7, lot = orig >> 3;
        wg = (xcd < r ? xcd * (q + 1) : r * (q + 1) + (xcd - r) * q) + lot;
    }
    const int bm = (wg / gridDim.x) * 128, bn = (wg % gridDim.x) * 128;
    int Kc = K, kbase = 0;
    if (OUTM == 2) { Kc = K / gridDim.z; kbase = blockIdx.z * Kc; }
    const int nt = Kc >> 5;

    auto stage = [&](int buf, int kt) {
        int k0 = kbase + (kt << 5);
#pragma unroll
        for (int i = 0; i < 2; ++i) {
            int off = i * 4096 + wv * 1024 + ln * 16;  // byte offset in 8KB tile
            int row = off >> 6, kb = (off & 63) >> 1;
            int gr = bm + row; gr = gr < M ? gr : M - 1;
            f16* gp = const_cast<f16*>(A) + (size_t)gr * K + k0 + kb;
            __builtin_amdgcn_global_load_lds(
                (__attribute__((address_space(1))) void*)gp,
                (__attribute__((address_space(3))) void*)(&As[buf][i * 2048 + wv * 512]),
                16, 0, 0);
            f16* gq = const_cast<f16*>(Bt) + (size_t)(bn + row) * K + k0 + kb;
            __builtin_amdgcn_global_load_lds(
                (__attribute__((address_space(1))) void*)gq,
                (__attribute__((address_space(3))) void*)(&Bs[buf][i * 2048 + wv * 512]),
                16, 0, 0);
        }
    };

    floatx4 acc[4][4];
#pragma unroll
    for (int m = 0; m < 4; ++m)
#pragma unroll
        for (int n = 0; n < 4; ++n) acc[m][n] = (floatx4)0.f;
    const int r = ln & 15, kc = (ln >> 4) * 8;
    const int wr = (wv >> 1) * 64, wc = (wv & 1) * 64;

    stage(0, 0);
    for (int t = 0; t < nt; ++t) {
        __syncthreads();                 // drains stage(t) loads
        if (t + 1 < nt) stage((t + 1) & 1, t + 1);   // prefetch next tile
        const int buf = t & 1;
        half8 af[4], bf[4];
#pragma unroll
        for (int m = 0; m < 4; ++m)
            af[m] = *(const half8*)(&As[buf][(wr + m * 16 + r) * 32 + kc]);
#pragma unroll
        for (int n = 0; n < 4; ++n)
            bf[n] = *(const half8*)(&Bs[buf][(wc + n * 16 + r) * 32 + kc]);
#pragma unroll
        for (int m = 0; m < 4; ++m)
#pragma unroll
            for (int n = 0; n < 4; ++n)
                acc[m][n] = __builtin_amdgcn_mfma_f32_16x16x32_f16(af[m], bf[n], acc[m][n], 0, 0, 0);
    }

    float* Cf = (float*)Cv;
    f16*   Ch = (f16*)Cv;
    if (OUTM == 2) Cf += (size_t)blockIdx.z * M * N;
#pragma unroll
    for (int m = 0; m < 4; ++m) {
        int rbase = bm + wr + m * 16 + ((ln >> 4) << 2);
#pragma unroll
        for (int j = 0; j < 4; ++j) {
            int row = rbase + j;
            if (row < M) {
                size_t ro = (size_t)row * N;
#pragma unroll
                for (int n = 0; n < 4; ++n) {
                    int col = bn + wc + n * 16 + (ln & 15);
                    float v = acc[m][n][j];
                    if (OUTM == 1) Ch[ro + col] = (f16)v;
                    else if (OUTM == 0) Cf[ro + col] = v + (res ? res[ro + col] : 0.f);
                    else Cf[ro + col] = v;
                }
            }
        }
    }
}

// ---------------- split-K reduce: C = (res?) + sum_z P[z] ------------------
template<bool HOUT>
__global__ __launch_bounds__(256) void kred(
    const float* __restrict__ P, const float* __restrict__ res,
    void* __restrict__ Cv, size_t mn, int ks) {
    size_t i = ((size_t)blockIdx.x * 256 + threadIdx.x) * 4;
    if (i >= mn) return;
    floatx4 s = res ? *(const floatx4*)(res + i) : (floatx4)0.f;
    for (int z = 0; z < ks; ++z) {
        floatx4 p = *(const floatx4*)(P + (size_t)z * mn + i);
        s += p;
    }
    if (HOUT) {
        half4v h;
#pragma unroll
        for (int j = 0; j < 4; ++j) h[j] = (f16)s[j];
        *(half4v*)((f16*)Cv + i) = h;
    } else {
        *(floatx4*)((float*)Cv + i) = s;
    }
}

// ---------------- split-K GEMV for M=2: C[2][N] = A[2][K] @ W[K][N] -------
__global__ __launch_bounds__(256) void gemv2_part(
    const float* __restrict__ A, const float* __restrict__ W,
    float* __restrict__ P, int N, int K) {
    int n = blockIdx.x * 256 + threadIdx.x;
    if (n >= N) return;
    int Kc = K / KSPL;
    int k0 = blockIdx.y * Kc;
    float acc0 = 0.f, acc1 = 0.f;
    const float* Wp = W + (size_t)k0 * N + n;
    const float* a0 = A + k0;
    const float* a1 = A + K + k0;
#pragma unroll 4
    for (int k = 0; k < Kc; ++k) {
        float w = Wp[(size_t)k * N];
        acc0 = fmaf(a0[k], w, acc0);
        acc1 = fmaf(a1[k], w, acc1);
    }
    P[((size_t)blockIdx.y * 2 + 0) * N + n] = acc0;
    P[((size_t)blockIdx.y * 2 + 1) * N + n] = acc1;
}

__global__ __launch_bounds__(256) void gemv2_red(
    const float* __restrict__ P, const float* __restrict__ res,
    float* __restrict__ C, int N) {
    int g = blockIdx.x * 256 + threadIdx.x;
    if (g >= 2 * N) return;
    int m = g / N, n = g - m * N;
    float s = res ? res[g] : 0.f;
#pragma unroll
    for (int ky = 0; ky < KSPL; ++ky)
        s += P[((size_t)ky * 2 + m) * N + n];
    C[g] = s;
}

// ---------------- norms ----------------
__device__ __forceinline__ void stf(float* p, float v) { *p = v; }
__device__ __forceinline__ void stf(f16* p, float v)   { *p = (f16)v; }

template<typename TO>
__global__ __launch_bounds__(256) void rmsnorm_k(
    const float* __restrict__ X, const float* __restrict__ scale,
    TO* __restrict__ Y, int C, int rows_per_group, float sadd) {
    int row = blockIdx.x, tid = threadIdx.x;
    const float* x = X + (size_t)row * C;
    float v[8];
    int cnt = C >> 8;
    float ss = 0.f;
    for (int i = 0; i < cnt; ++i) { v[i] = x[tid + (i << 8)]; ss += v[i] * v[i]; }
    __shared__ float red[256];
    red[tid] = ss; __syncthreads();
    for (int s2 = 128; s2; s2 >>= 1) { if (tid < s2) red[tid] += red[tid + s2]; __syncthreads(); }
    float inv = rsqrtf(red[0] / (float)C + 1e-6f);
    const float* sc = scale + (size_t)(row / rows_per_group) * C;
    TO* y = Y + (size_t)row * C;
    for (int i = 0; i < cnt; ++i) {
        int c = tid + (i << 8);
        stf(&y[c], v[i] * (sadd + sc[c]) * inv);
    }
}

__global__ __launch_bounds__(256) void layernorm_k(
    const float* __restrict__ X, const float* __restrict__ g,
    const float* __restrict__ bta, f16* __restrict__ Y, int C) {
    int row = blockIdx.x, tid = threadIdx.x;
    const float* x = X + (size_t)row * C;
    float v[8];
    int cnt = C >> 8;
    float s = 0.f;
    for (int i = 0; i < cnt; ++i) { v[i] = x[tid + (i << 8)]; s += v[i]; }
    __shared__ float red[256];
    red[tid] = s; __syncthreads();
    for (int s2 = 128; s2; s2 >>= 1) { if (tid < s2) red[tid] += red[tid + s2]; __syncthreads(); }
    float m = red[0] / (float)C;
    __syncthreads();
    float s2s = 0.f;
    for (int i = 0; i < cnt; ++i) { float d = v[i] - m; s2s += d * d; }
    red[tid] = s2s; __syncthreads();
    for (int s2 = 128; s2; s2 >>= 1) { if (tid < s2) red[tid] += red[tid + s2]; __syncthreads(); }
    float inv = rsqrtf(red[0] / (float)C + 1e-5f);
    f16* y = Y + (size_t)row * C;
    for (int i = 0; i < cnt; ++i) {
        int c = tid + (i << 8);
        y[c] = (f16)((v[i] - m) * inv * g[c] + bta[c]);
    }
}

// ---------------- GLU ----------------
__global__ __launch_bounds__(256) void glu_k(
    const float* __restrict__ U, float* __restrict__ Yo,
    size_t total, int F, int mode) {
    size_t gidx = (size_t)blockIdx.x * 256 + threadIdx.x;
    if (gidx >= total) return;
    size_t r = gidx / (size_t)F;
    int c = (int)(gidx - r * F);
    const float* u = U + r * (size_t)(2 * F);
    float a = u[c], gg = u[F + c];
    float act = (mode == 0) ? gelu_tanh(gg) : gg / (1.f + expf(-gg));
    Yo[gidx] = a * act;
}

__global__ __launch_bounds__(256) void glu_h8(
    const f16* __restrict__ U, f16* __restrict__ Yo,
    size_t total8, int F8, int mode) {
    size_t gi = (size_t)blockIdx.x * 256 + threadIdx.x;
    if (gi >= total8) return;
    size_t r = gi / (size_t)F8;
    int c = (int)(gi - r * (size_t)F8);
    const f16* u = U + r * (size_t)F8 * 16;
    half8 av = *(const half8*)(u + c * 8);
    half8 gv = *(const half8*)(u + F8 * 8 + c * 8);
    half8 y;
#pragma unroll
    for (int j = 0; j < 8; ++j) {
        float a = (float)av[j], gg = (float)gv[j];
        float act = (mode == 0) ? gelu_tanh(gg) : gg / (1.f + __expf(-gg));
        y[j] = (f16)(a * act);
    }
    *(half8*)(Yo + gi * 8) = y;
}

// ---------------- QKV split + RoPE (+ q scale 1/8), f16 out ---------------
__global__ __launch_bounds__(256) void qkv_split_rope(
    const float* __restrict__ QKV, f16* __restrict__ Qo,
    f16* __restrict__ Ko, f16* __restrict__ Vo, int S, int H) {
    int g = blockIdx.x * 256 + threadIdx.x;
    int total = BB * S * H * 32;
    if (g >= total) return;
    int i = g & 31;
    int tix = g >> 5;
    int h = tix % H; tix /= H;
    int s = tix % S; int b = tix / S;
    int C = H * 64;
    const float* base = QKV + (size_t)(b * S + s) * 3 * C + h * 64;
    float q1 = base[i], q2 = base[32 + i];
    float k1 = base[C + i], k2 = base[C + 32 + i];
    float v1 = base[2 * C + i], v2 = base[2 * C + 32 + i];
    float inv = expf(-(float)i * 0.28782313662425575f);
    float ang = (float)s * inv;
    float sn, cs;
    sincosf(ang, &sn, &cs);
    size_t o = ((size_t)(b * H + h) * S + s) * 64 + i;
    Qo[o]      = (f16)((q1 * cs - q2 * sn) * 0.125f);
    Qo[o + 32] = (f16)((q2 * cs + q1 * sn) * 0.125f);
    Ko[o]      = (f16)(k1 * cs - k2 * sn);
    Ko[o + 32] = (f16)(k2 * cs + k1 * sn);
    Vo[o]      = (f16)v1;
    Vo[o + 32] = (f16)v2;
}

// ---------------- V transpose: V[bh][S][64] -> Vt[bh][64][Spad] -----------
__global__ __launch_bounds__(256) void vtrans(
    const f16* __restrict__ V, f16* __restrict__ Vt, int S, int Spad) {
    __shared__ f16 T[64][72];
    const int tid = threadIdx.x;
    const int k0 = blockIdx.x * 64;
    const f16* Vb = V + (size_t)blockIdx.y * S * 64;
    f16* Vtb = Vt + (size_t)blockIdx.y * 64 * Spad;
    for (int c = tid; c < 512; c += 256) {
        int kk = c >> 3, d8 = (c & 7) * 8;
        int kg = k0 + kk; kg = kg < S ? kg : S - 1;
        half8 v = *(const half8*)(Vb + (size_t)kg * 64 + d8);
        if (k0 + kk >= S) {
#pragma unroll
            for (int j = 0; j < 8; ++j) v[j] = (f16)0.f;
        }
        *(half8*)(&T[kk][d8]) = v;
    }
    __syncthreads();
    for (int c = tid; c < 512; c += 256) {
        int d = c >> 3, k8 = (c & 7) * 8;
        half8 o;
#pragma unroll
        for (int j = 0; j < 8; ++j) o[j] = T[k8 + j][d];
        *(half8*)(Vtb + (size_t)d * Spad + k0 + k8) = o;
    }
}

// ---------------- fused flash attention -----------------------------------
__global__ __launch_bounds__(256) void fattn(
    const f16* __restrict__ Q, const f16* __restrict__ K,
    const f16* __restrict__ Vt, f16* __restrict__ O,
    int S, int Spad, int H, int win) {
    __shared__ __align__(16) f16 Ks[64][72];
    __shared__ __align__(16) f16 Vs[64][72];
    __shared__ __align__(16) f16 Ps[4][32][72];
    const int tid = threadIdx.x;
    const int wv = tid >> 6, ln = tid & 63;
    const int r15 = ln & 15, g = ln >> 4;
    const int bh = blockIdx.y;
    const int b = bh / H, h = bh % H;
    const int q0 = (int)blockIdx.x * 128;
    const f16* Qb = Q + (size_t)bh * S * 64;
    const f16* Kb = K + (size_t)bh * S * 64;
    const f16* Vtb = Vt + (size_t)bh * 64 * Spad;

    half8 aq[2][2];
#pragma unroll
    for (int m = 0; m < 2; ++m) {
        int q = q0 + wv * 32 + m * 16 + r15;
        q = q < S ? q : S - 1;
#pragma unroll
        for (int ks = 0; ks < 2; ++ks)
            aq[m][ks] = *(const half8*)(Qb + (size_t)q * 64 + ks * 32 + g * 8);
    }
    floatx4 o[2][4];
#pragma unroll
    for (int m = 0; m < 2; ++m)
#pragma unroll
        for (int n = 0; n < 4; ++n) o[m][n] = (floatx4)0.f;
    float mst[2][4], lst[2][4];
#pragma unroll
    for (int m = 0; m < 2; ++m)
#pragma unroll
        for (int j = 0; j < 4; ++j) { mst[m][j] = -3.0e38f; lst[m][j] = 0.f; }

    int klo = 0, khi = S;
    if (win) {
        int n = (int)blockIdx.x;
        klo = (n - 1) * win; if (klo < 0) klo = 0;
        khi = (n + 2) * win; if (khi > S) khi = S;
    }
    for (int kb = klo; kb < khi; kb += 64) {
        __syncthreads();
#pragma unroll
        for (int i = 0; i < 2; ++i) {
            int c = tid + i * 256;
            int rr = c >> 3, c8 = (c & 7) * 8;
            int kg = kb + rr; kg = kg < S ? kg : S - 1;
            *(half8*)(&Ks[rr][c8]) = *(const half8*)(Kb + (size_t)kg * 64 + c8);
            *(half8*)(&Vs[rr][c8]) = *(const half8*)(Vtb + (size_t)rr * Spad + kb + c8);
        }
        __syncthreads();
        floatx4 s[2][4];
#pragma unroll
        for (int m = 0; m < 2; ++m)
#pragma unroll
            for (int n = 0; n < 4; ++n) s[m][n] = (floatx4)0.f;
#pragma unroll
        for (int ks = 0; ks < 2; ++ks) {
            half8 bk[4];
#pragma unroll
            for (int n = 0; n < 4; ++n)
                bk[n] = *(const half8*)(&Ks[n * 16 + r15][ks * 32 + g * 8]);
#pragma unroll
            for (int m = 0; m < 2; ++m)
#pragma unroll
                for (int n = 0; n < 4; ++n)
                    s[m][n] = __builtin_amdgcn_mfma_f32_16x16x32_f16(aq[m][ks], bk[n], s[m][n], 0, 0, 0);
        }
        if (kb + 64 > S) {
#pragma unroll
            for (int n = 0; n < 4; ++n)
                if (kb + n * 16 + r15 >= S) {
#pragma unroll
                    for (int m = 0; m < 2; ++m) s[m][n] = (floatx4)(-3.0e38f);
                }
        }
#pragma unroll
        for (int m = 0; m < 2; ++m) {
#pragma unroll
            for (int j = 0; j < 4; ++j) {
                float tm = fmaxf(fmaxf(s[m][0][j], s[m][1][j]), fmaxf(s[m][2][j], s[m][3][j]));
                tm = fmaxf(tm, __shfl_xor(tm, 1));
                tm = fmaxf(tm, __shfl_xor(tm, 2));
                tm = fmaxf(tm, __shfl_xor(tm, 4));
                tm = fmaxf(tm, __shfl_xor(tm, 8));
                float mn = fmaxf(mst[m][j], tm);
                float sc = __expf(mst[m][j] - mn);
                mst[m][j] = mn;
                float ts = 0.f;
#pragma unroll
                for (int n = 0; n < 4; ++n) {
                    float p = __expf(s[m][n][j] - mn);
                    s[m][n][j] = p;
                    ts += p;
                }
                ts += __shfl_xor(ts, 1);
                ts += __shfl_xor(ts, 2);
                ts += __shfl_xor(ts, 4);
                ts += __shfl_xor(ts, 8);
                lst[m][j] = lst[m][j] * sc + ts;
#pragma unroll
                for (int n = 0; n < 4; ++n) o[m][n][j] *= sc;
            }
        }
#pragma unroll
        for (int m = 0; m < 2; ++m)
#pragma unroll
            for (int n = 0; n < 4; ++n)
#pragma unroll
                for (int j = 0; j < 4; ++j)
                    Ps[wv][m * 16 + g * 4 + j][n * 16 + r15] = (f16)s[m][n][j];
#pragma unroll
        for (int ks = 0; ks < 2; ++ks) {
            half8 pa[2], bv[4];
#pragma unroll
            for (int m = 0; m < 2; ++m)
                pa[m] = *(const half8*)(&Ps[wv][m * 16 + r15][ks * 32 + g * 8]);
#pragma unroll
            for (int n = 0; n < 4; ++n)
                bv[n] = *(const half8*)(&Vs[n * 16 + r15][ks * 32 + g * 8]);
#pragma unroll
            for (int m = 0; m < 2; ++m)
#pragma unroll
                for (int n = 0; n < 4; ++n)
                    o[m][n] = __builtin_amdgcn_mfma_f32_16x16x32_f16(pa[m], bv[n], o[m][n], 0, 0, 0);
        }
    }
    const int HC = H * 64;
#pragma unroll
    for (int m = 0; m < 2; ++m)
#pragma unroll
        for (int j = 0; j < 4; ++j) {
            int q = q0 + wv * 32 + m * 16 + g * 4 + j;
            if (q < S) {
                float inv = 1.f / lst[m][j];
                size_t ro = ((size_t)b * S + q) * HC + h * 64;
#pragma unroll
                for (int n = 0; n < 4; ++n)
                    O[ro + n * 16 + r15] = (f16)(o[m][n][j] * inv);
            }
        }
}

// ---------------- small glue kernels ----------------
__global__ __launch_bounds__(256) void patch_in_gather(
    const float* __restrict__ x, f16* __restrict__ out) {
    int g = blockIdx.x * 256 + threadIdx.x;
    if (g >= BB * S0 * 128) return;
    int k = g & 127;
    int n = (g >> 7) & (S0 - 1);
    int b = g >> 18;
    out[g] = (f16)x[(size_t)b * CIO * TT + (size_t)(k >> 1) * TT + 2 * n + (k & 1)];
}

__global__ __launch_bounds__(256) void time_embed(
    const float* __restrict__ t, const float* __restrict__ tw,
    float* __restrict__ te) {
    int g = blockIdx.x * 256 + threadIdx.x;
    if (g >= BB * MAPD) return;
    int b = g / MAPD, j = g % MAPD;
    float w = tw[(j < 512) ? j : j - 512];
    float ang = 6.283185307179586f * t[b] * w;
    te[g] = (j < 512) ? cosf(ang) : sinf(ang);
}

__global__ __launch_bounds__(256) void token_merge_gather(
    const float* __restrict__ A, f16* __restrict__ out) {
    int g = blockIdx.x * 256 + threadIdx.x;
    if (g >= BB * 1024 * 1024) return;
    int k = g & 1023;
    int n = (g >> 10) & 1023;
    int b = g >> 20;
    out[g] = (f16)A[((size_t)b * S0 + 2 * n + (k & 1)) * W0 + (k >> 1)];
}

__global__ __launch_bounds__(256) void concat_mid(
    const float* __restrict__ pre, const float* __restrict__ Dsrc,
    float* __restrict__ Cm) {
    int g = blockIdx.x * 256 + threadIdx.x;
    if (g >= BB * SM * W1) return;
    int c = g & 1023;
    int row = g >> 10;
    int b = row / SM, r = row % SM;
    Cm[g] = (r == 0) ? pre[b * W1 + c]
                     : Dsrc[((size_t)b * 1024 + r - 1) * W1 + c];
}

__global__ __launch_bounds__(256) void gather_drop(
    const f16* __restrict__ Dsrc, f16* __restrict__ out) {
    int g = blockIdx.x * 256 + threadIdx.x;
    if (g >= BB * 1024 * W1) return;
    int c = g & 1023;
    int n = (g >> 10) & 1023;
    int b = g >> 20;
    out[g] = Dsrc[((size_t)b * SM + 1 + n) * W1 + c];
}

__global__ __launch_bounds__(256) void split_scatter_lerp(
    const float* __restrict__ y, const float* __restrict__ skip,
    const float* __restrict__ fac, float* __restrict__ xo) {
    int g = blockIdx.x * 256 + threadIdx.x;
    if (g >= BB * S0 * W0) return;
    int c = g & 511;
    int tk = (g >> 9) & (S0 - 1);
    int b = g >> 20;
    float yv = y[((size_t)b * 1024 + (tk >> 1)) * W1 + (c * 2 + (tk & 1))];
    float sk = skip[g];
    xo[g] = sk + fac[0] * (yv - sk);
}

__global__ __launch_bounds__(256) void patch_out_scatter(
    const float* __restrict__ y, float* __restrict__ out) {
    int g = blockIdx.x * 256 + threadIdx.x;
    if (g >= BB * CIO * TT) return;
    int tk = g & (TT - 1);
    int c = (g >> 12) & 63;
    int b = g >> 18;
    out[g] = y[((size_t)b * S0 + (tk >> 1)) * 128 + (c * 2 + (tk & 1))];
}

// ---------------- host orchestration ----------------
extern "C" void kernel_launch(void* const* d_in, const int* in_sizes, int n_in,
                              void* d_out, int out_size, void* d_ws, size_t ws_size,
                              hipStream_t stream) {
    const float* x          = (const float*)d_in[0];
    const float* t          = (const float*)d_in[1];
    const float* time_w     = (const float*)d_in[2];
    const float* time_in_w  = (const float*)d_in[3];
    const float* map_in_s   = (const float*)d_in[4];
    const float* map_norm_s = (const float*)d_in[5];
    const float* map_up_w   = (const float*)d_in[6];
    const float* map_down_w = (const float*)d_in[7];
    const float* map_out_s  = (const float*)d_in[8];
    const float* patch_in_w = (const float*)d_in[9];
    const float* dn_anorm_w = (const float*)d_in[10];
    const float* dn_qkv_w   = (const float*)d_in[11];
    const float* dn_o_w     = (const float*)d_in[12];
    const float* dn_fnorm_w = (const float*)d_in[13];
    const float* dn_ff1_w   = (const float*)d_in[14];
    const float* dn_ff2_w   = (const float*)d_in[15];
    const float* merge_w    = (const float*)d_in[16];
    const float* mid_map_w  = (const float*)d_in[17];
    const float* mid_pin_w  = (const float*)d_in[18];
    const float* mid_pout_w = (const float*)d_in[19];
    const float* mid_ln1_g  = (const float*)d_in[20];
    const float* mid_ln1_b  = (const float*)d_in[21];
    const float* mid_qkv_w  = (const float*)d_in[22];
    const float* mid_o_w    = (const float*)d_in[23];
    const float* mid_ln2_g  = (const float*)d_in[24];
    const float* mid_ln2_b  = (const float*)d_in[25];
    const float* mid_ff1_w  = (const float*)d_in[26];
    const float* mid_ff2_w  = (const float*)d_in[27];
    const float* mid_fn_g   = (const float*)d_in[28];
    const float* mid_fn_b   = (const float*)d_in[29];
    const float* split_w    = (const float*)d_in[30];
    const float* split_fac  = (const float*)d_in[31];
    const float* up_anorm_w = (const float*)d_in[32];
    const float* up_qkv_w   = (const float*)d_in[33];
    const float* up_o_w     = (const float*)d_in[34];
    const float* up_fnorm_w = (const float*)d_in[35];
    const float* up_ff1_w   = (const float*)d_in[36];
    const float* up_ff2_w   = (const float*)d_in[37];
    const float* out_norm_s = (const float*)d_in[38];
    const float* patch_out_w= (const float*)d_in[39];

    float* Wp = (float*)d_ws;
    size_t off = 0;
    auto alloc = [&](size_t n) { float* p = Wp + off; off += n; return p; };
    float* A   = alloc((size_t)4096 * 512);          // local residual (f32)
    float* Bsk = alloc((size_t)4096 * 512);          // skip
    float* Cm  = alloc((size_t)2050 * 1024);         // mid residual
    float* Df  = alloc((size_t)2050 * 1024);         // f32 temp
    float* E32 = alloc((size_t)2050 * 3072);         // QKV f32 out
    f16*  Fq   = (f16*)alloc((size_t)1049600);
    f16*  Fk   = (f16*)alloc((size_t)1049600);
    f16*  Fv   = (f16*)alloc((size_t)1049600);
    f16*  Fvt  = (f16*)alloc((size_t)1114112);
    f16*  H1   = (f16*)alloc((size_t)8396800);
    f16*  H2   = (f16*)alloc((size_t)4198400);
    f16*  Wh   = (f16*)alloc((size_t)4194304);
    float* Pk  = alloc((size_t)PKCAP);               // split-K partials
    float* Pb  = alloc((size_t)KSPL * 2 * 2048);     // gemv2 partials
    float* Sma = alloc((size_t)32768);
    (void)ws_size; (void)in_sizes; (void)n_in; (void)out_size;

    float* te   = Sma;
    float* temb = Sma + 2048;
    float* mapx = Sma + 4096;
    float* maph = Sma + 6144;
    float* mapu = Sma + 8192;
    float* mapg = Sma + 12288;
    float* cond = Sma + 14336;
    float* sA   = Sma + 16384;
    float* sF   = Sma + 17408;
    float* pre  = Sma + 18432;

    auto WC = [&](const float* W, int K, int N) {
        wcast<<<dim3(N / 64, K / 64), 256, 0, stream>>>(W, Wh, K, N);
    };
    auto pick_ks = [](int M, int N, int K) {
        long gx = N / 128, gy = (M + 127) / 128;
        int ks = 1;
        while (gx * gy * ks < 512 && ks < 8) {
            int nk = ks * 2;
            if ((K / nk) % 32 != 0 || (long)M * N * nk > PKCAP) break;
            ks = nk;
        }
        return ks;
    };
    // f32 output (+res)
    auto GF = [&](const f16* Aa, const float* res, float* C, int M, int N, int K) {
        int ks = pick_ks(M, N, K);
        dim3 g(N / 128, (M + 127) / 128, ks);
        if (ks == 1) {
            gemm_h<0><<<g, 256, 0, stream>>>(Aa, Wh, res, C, M, N, K);
        } else {
            gemm_h<2><<<g, 256, 0, stream>>>(Aa, Wh, nullptr, Pk, M, N, K);
            size_t mn = (size_t)M * N;
            kred<false><<<(int)((mn / 4 + 255) / 256), 256, 0, stream>>>(Pk, res, C, mn, ks);
        }
    };
    // f16 output
    auto GH = [&](const f16* Aa, f16* C, int M, int N, int K) {
        int ks = pick_ks(M, N, K);
        dim3 g(N / 128, (M + 127) / 128, ks);
        if (ks == 1) {
            gemm_h<1><<<g, 256, 0, stream>>>(Aa, Wh, nullptr, C, M, N, K);
        } else {
            gemm_h<2><<<g, 256, 0, stream>>>(Aa, Wh, nullptr, Pk, M, N, K);
            size_t mn = (size_t)M * N;
            kred<true><<<(int)((mn / 4 + 255) / 256), 256, 0, stream>>>(Pk, nullptr, C, mn, ks);
        }
    };
    auto gemv2 = [&](const float* Aa, const float* W, const float* res,
                     float* C, int N, int K) {
        gemv2_part<<<dim3((N + 255) / 256, KSPL), 256, 0, stream>>>(Aa, W, Pb, N, K);
        gemv2_red<<<(2 * N + 255) / 256, 256, 0, stream>>>(Pb, res, C, N);
    };

    // ---- patch in ----
    patch_in_gather<<<(BB * S0 * 128 + 255) / 256, 256, 0, stream>>>(x, H2);
    WC(patch_in_w, 128, 512);
    GF(H2, nullptr, A, 4096, 512, 128);

    // ---- time embedding + mapping (tiny, f32) ----
    time_embed<<<(BB * MAPD + 255) / 256, 256, 0, stream>>>(t, time_w, te);
    gemv2(te, time_in_w, nullptr, temb, 1024, 1024);
    rmsnorm_k<float><<<2, 256, 0, stream>>>(temb, map_in_s, mapx, 1024, 2, 0.f);
    for (int l = 0; l < 2; ++l) {
        rmsnorm_k<float><<<2, 256, 0, stream>>>(mapx, map_norm_s + (size_t)l * 1024, maph, 1024, 2, 0.f);
        gemv2(maph, map_up_w + (size_t)l * 1024 * 2048, nullptr, mapu, 2048, 1024);
        glu_k<<<(2 * 1024 + 255) / 256, 256, 0, stream>>>(mapu, mapg, 2 * 1024, 1024, 0);
        gemv2(mapg, map_down_w + (size_t)l * 1024 * 1024, mapx, mapx, 1024, 1024);
    }
    rmsnorm_k<float><<<2, 256, 0, stream>>>(mapx, map_out_s, cond, 1024, 2, 0.f);

    // ---- local level (shared for down/up) ----
    auto run_local = [&](const float* anorm, const float* qkvw, const float* ow,
                         const float* fnorm, const float* ff1, const float* ff2) {
        for (int l = 0; l < 2; ++l) {
            gemv2(cond, anorm + (size_t)l * 1024 * 512, nullptr, sA, 512, 1024);
            rmsnorm_k<f16><<<4096, 256, 0, stream>>>(A, sA, H2, 512, 2048, 1.f);
            WC(qkvw + (size_t)l * 512 * 1536, 512, 1536);
            GF(H2, nullptr, E32, 4096, 1536, 512);
            qkv_split_rope<<<(BB * S0 * HDN * 32 + 255) / 256, 256, 0, stream>>>(E32, Fq, Fk, Fv, S0, HDN);
            vtrans<<<dim3(S0 / 64, BB * HDN), 256, 0, stream>>>(Fv, Fvt, S0, S0);
            fattn<<<dim3(S0 / 128, BB * HDN), 256, 0, stream>>>(Fq, Fk, Fvt, H2, S0, S0, HDN, WIN);
            WC(ow + (size_t)l * 512 * 512, 512, 512);
            GF(H2, A, A, 4096, 512, 512);
            gemv2(cond, fnorm + (size_t)l * 1024 * 512, nullptr, sF, 512, 1024);
            rmsnorm_k<f16><<<4096, 256, 0, stream>>>(A, sF, H2, 512, 2048, 1.f);
            WC(ff1 + (size_t)l * 512 * 2048, 512, 2048);
            GH(H2, H1, 4096, 2048, 512);
            glu_h8<<<(4096 * 128 + 255) / 256, 256, 0, stream>>>(H1, H2, (size_t)4096 * 128, 128, 0);
            WC(ff2 + (size_t)l * 1024 * 512, 1024, 512);
            GF(H2, A, A, 4096, 512, 1024);
        }
    };
    run_local(dn_anorm_w, dn_qkv_w, dn_o_w, dn_fnorm_w, dn_ff1_w, dn_ff2_w);

    // ---- skip save, merge, mid prep ----
    hipMemcpyAsync(Bsk, A, (size_t)4096 * 512 * 4, hipMemcpyDeviceToDevice, stream);
    token_merge_gather<<<(BB * 1024 * 1024 + 255) / 256, 256, 0, stream>>>(A, H2);
    WC(merge_w, 1024, 1024);
    GH(H2, H1, 2048, 1024, 1024);
    WC(mid_pin_w, 1024, 1024);
    GF(H1, nullptr, Df, 2048, 1024, 1024);
    gemv2(cond, mid_map_w, nullptr, pre, 1024, 1024);
    concat_mid<<<(BB * SM * W1 + 255) / 256, 256, 0, stream>>>(pre, Df, Cm);

    // ---- mid level ----
    for (int l = 0; l < 4; ++l) {
        layernorm_k<<<2050, 256, 0, stream>>>(Cm, mid_ln1_g + (size_t)l * 1024,
                                              mid_ln1_b + (size_t)l * 1024, H2, 1024);
        WC(mid_qkv_w + (size_t)l * 1024 * 3072, 1024, 3072);
        GF(H2, nullptr, E32, 2050, 3072, 1024);
        qkv_split_rope<<<(BB * SM * HMID * 32 + 255) / 256, 256, 0, stream>>>(E32, Fq, Fk, Fv, SM, HMID);
        vtrans<<<dim3(SMP / 64, BB * HMID), 256, 0, stream>>>(Fv, Fvt, SM, SMP);
        fattn<<<dim3(9, BB * HMID), 256, 0, stream>>>(Fq, Fk, Fvt, H2, SM, SMP, HMID, 0);
        WC(mid_o_w + (size_t)l * 1024 * 1024, 1024, 1024);
        GF(H2, Cm, Cm, 2050, 1024, 1024);
        layernorm_k<<<2050, 256, 0, stream>>>(Cm, mid_ln2_g + (size_t)l * 1024,
                                              mid_ln2_b + (size_t)l * 1024, H2, 1024);
        WC(mid_ff1_w + (size_t)l * 1024 * 8192, 1024, 8192);
        GH(H2, H1, 2050, 8192, 1024);
        glu_h8<<<(int)(((size_t)2050 * 512 + 255) / 256), 256, 0, stream>>>(H1, H2, (size_t)2050 * 512, 512, 1);
        WC(mid_ff2_w + (size_t)l * 4096 * 1024, 4096, 1024);
        GF(H2, Cm, Cm, 2050, 1024, 4096);
    }
    layernorm_k<<<2050, 256, 0, stream>>>(Cm, mid_fn_g, mid_fn_b, H2, 1024);

    // ---- pout + token split + lerp skip ----
    WC(mid_pout_w, 1024, 1024);
    GH(H2, H1, 2050, 1024, 1024);
    gather_drop<<<(BB * 1024 * W1 + 255) / 256, 256, 0, stream>>>(H1, H2);
    WC(split_w, 1024, 1024);
    GF(H2, nullptr, Df, 2048, 1024, 1024);
    split_scatter_lerp<<<(BB * S0 * W0 + 255) / 256, 256, 0, stream>>>(Df, Bsk, split_fac, A);

    // ---- up level ----
    run_local(up_anorm_w, up_qkv_w, up_o_w, up_fnorm_w, up_ff1_w, up_ff2_w);

    // ---- out ----
    rmsnorm_k<f16><<<4096, 256, 0, stream>>>(A, out_norm_s, H2, 512, 4096, 0.f);
    WC(patch_out_w, 512, 128);
    GF(H2, nullptr, Df, 4096, 128, 512);
    patch_out_scatter<<<(BB * CIO * TT + 255) / 256, 256, 0, stream>>>(Df, (float*)d_out);
}

// Round 6
// 2146.271 us; speedup vs baseline: 8.7279x; 1.0190x over previous
//
#include <hip/hip_runtime.h>
#include <math.h>

// ---------------- constants ----------------
#define BB   2
#define CIO  64
#define TT   4096
#define S0   2048      // local level seq len
#define W0   512
#define HDN  8
#define SM   1025      // mid seq len (with prepended token)
#define SMP  1088      // padded mid seq (17*64)
#define W1   1024
#define HMID 16
#define WIN  128
#define NW   16        // S0 / WIN
#define MAPD 1024
#define KSPL 16        // split-K factor for M=2 GEMV
#define PKCAP 8396800L // partial buffer capacity (floats)

typedef _Float16 f16;
typedef _Float16 half8 __attribute__((ext_vector_type(8)));
typedef _Float16 half4v __attribute__((ext_vector_type(4)));
typedef _Float16 half2v __attribute__((ext_vector_type(2)));
typedef float floatx4 __attribute__((ext_vector_type(4)));

// ---------------- device helpers ----------------
__device__ __forceinline__ float gelu_tanh(float x) {
    float x3 = x * x * x;
    return 0.5f * x * (1.f + tanhf(0.7978845608028654f * (x + 0.044715f * x3)));
}

// ---------------- weight transpose-cast: W[K][N] f32 -> Wt[N][K] f16 ------
__global__ __launch_bounds__(256) void wcast(
    const float* __restrict__ W, f16* __restrict__ Wt, int K, int N) {
    __shared__ float T[64][65];
    const int n0 = blockIdx.x * 64, k0 = blockIdx.y * 64;
    const int tid = threadIdx.x;
    for (int e = tid; e < 4096; e += 256) {
        int r = e >> 6, c = e & 63;
        T[r][c] = W[(size_t)(k0 + r) * N + n0 + c];
    }
    __syncthreads();
    for (int e = tid; e < 2048; e += 256) {
        int r = e >> 5, c2 = (e & 31) * 2;
        half2v p;
        p[0] = (f16)T[c2][r];
        p[1] = (f16)T[c2 + 1][r];
        *(half2v*)(Wt + (size_t)(n0 + r) * K + k0 + c2) = p;
    }
}

// ---------------- MFMA GEMM: C = (res?) + A[MxK]f16 @ Bt[NxK]f16^T --------
// OUTM: 0 = f32 out (+res), 1 = f16 out, 2 = split-K f32 partial (grid.z)
template<int OUTM>
__global__ __launch_bounds__(256) void gemm_h(
    const f16* __restrict__ A, const f16* __restrict__ Bt,
    const float* __restrict__ res, void* __restrict__ Cv,
    int M, int N, int K) {
    __shared__ __align__(16) f16 As[2][4096];
    __shared__ __align__(16) f16 Bs[2][4096];
    const int tid = threadIdx.x;
    const int wv = tid >> 6, ln = tid & 63;
    int nwg = gridDim.x * gridDim.y;
    int orig = blockIdx.y * gridDim.x + blockIdx.x;
    int wg = orig;
    if (nwg >= 16) {
        int q = nwg >> 3, r = nwg & 7;
        int xcd = orig & 7, lot = orig >> 3;
        wg = (xcd < r ? xcd * (q + 1) : r * (q + 1) + (xcd - r) * q) + lot;
    }
    const int bm = (wg / gridDim.x) * 128, bn = (wg % gridDim.x) * 128;
    int Kc = K, kbase = 0;
    if (OUTM == 2) { Kc = K / gridDim.z; kbase = blockIdx.z * Kc; }
    const int nt = Kc >> 5;

    auto stage = [&](int buf, int kt) {
        int k0 = kbase + (kt << 5);
#pragma unroll
        for (int i = 0; i < 2; ++i) {
            int off = i * 4096 + wv * 1024 + ln * 16;
            int row = off >> 6, kb = (off & 63) >> 1;
            int gr = bm + row; gr = gr < M ? gr : M - 1;
            f16* gp = const_cast<f16*>(A) + (size_t)gr * K + k0 + kb;
            __builtin_amdgcn_global_load_lds(
                (__attribute__((address_space(1))) void*)gp,
                (__attribute__((address_space(3))) void*)(&As[buf][i * 2048 + wv * 512]),
                16, 0, 0);
            f16* gq = const_cast<f16*>(Bt) + (size_t)(bn + row) * K + k0 + kb;
            __builtin_amdgcn_global_load_lds(
                (__attribute__((address_space(1))) void*)gq,
                (__attribute__((address_space(3))) void*)(&Bs[buf][i * 2048 + wv * 512]),
                16, 0, 0);
        }
    };

    floatx4 acc[4][4];
#pragma unroll
    for (int m = 0; m < 4; ++m)
#pragma unroll
        for (int n = 0; n < 4; ++n) acc[m][n] = (floatx4)0.f;
    const int r = ln & 15, kc = (ln >> 4) * 8;
    const int wr = (wv >> 1) * 64, wc = (wv & 1) * 64;

    stage(0, 0);
    for (int t = 0; t < nt; ++t) {
        __syncthreads();
        if (t + 1 < nt) stage((t + 1) & 1, t + 1);
        const int buf = t & 1;
        half8 af[4], bf[4];
#pragma unroll
        for (int m = 0; m < 4; ++m)
            af[m] = *(const half8*)(&As[buf][(wr + m * 16 + r) * 32 + kc]);
#pragma unroll
        for (int n = 0; n < 4; ++n)
            bf[n] = *(const half8*)(&Bs[buf][(wc + n * 16 + r) * 32 + kc]);
#pragma unroll
        for (int m = 0; m < 4; ++m)
#pragma unroll
            for (int n = 0; n < 4; ++n)
                acc[m][n] = __builtin_amdgcn_mfma_f32_16x16x32_f16(af[m], bf[n], acc[m][n], 0, 0, 0);
    }

    float* Cf = (float*)Cv;
    f16*   Ch = (f16*)Cv;
    if (OUTM == 2) Cf += (size_t)blockIdx.z * M * N;
#pragma unroll
    for (int m = 0; m < 4; ++m) {
        int rbase = bm + wr + m * 16 + ((ln >> 4) << 2);
#pragma unroll
        for (int j = 0; j < 4; ++j) {
            int row = rbase + j;
            if (row < M) {
                size_t ro = (size_t)row * N;
#pragma unroll
                for (int n = 0; n < 4; ++n) {
                    int col = bn + wc + n * 16 + (ln & 15);
                    float v = acc[m][n][j];
                    if (OUTM == 1) Ch[ro + col] = (f16)v;
                    else if (OUTM == 0) Cf[ro + col] = v + (res ? res[ro + col] : 0.f);
                    else Cf[ro + col] = v;
                }
            }
        }
    }
}

// ---------------- split-K reduce ------------------------------------------
template<bool HOUT>
__global__ __launch_bounds__(256) void kred(
    const float* __restrict__ P, const float* __restrict__ res,
    void* __restrict__ Cv, size_t mn, int ks) {
    size_t i = ((size_t)blockIdx.x * 256 + threadIdx.x) * 4;
    if (i >= mn) return;
    floatx4 s = res ? *(const floatx4*)(res + i) : (floatx4)0.f;
    for (int z = 0; z < ks; ++z) {
        floatx4 p = *(const floatx4*)(P + (size_t)z * mn + i);
        s += p;
    }
    if (HOUT) {
        half4v h;
#pragma unroll
        for (int j = 0; j < 4; ++j) h[j] = (f16)s[j];
        *(half4v*)((f16*)Cv + i) = h;
    } else {
        *(floatx4*)((float*)Cv + i) = s;
    }
}

// ---------------- split-K GEMV for M=2 ------------------------------------
__global__ __launch_bounds__(256) void gemv2_part(
    const float* __restrict__ A, const float* __restrict__ W,
    float* __restrict__ P, int N, int K) {
    int n = blockIdx.x * 256 + threadIdx.x;
    if (n >= N) return;
    int Kc = K / KSPL;
    int k0 = blockIdx.y * Kc;
    float acc0 = 0.f, acc1 = 0.f;
    const float* Wp = W + (size_t)k0 * N + n;
    const float* a0 = A + k0;
    const float* a1 = A + K + k0;
#pragma unroll 4
    for (int k = 0; k < Kc; ++k) {
        float w = Wp[(size_t)k * N];
        acc0 = fmaf(a0[k], w, acc0);
        acc1 = fmaf(a1[k], w, acc1);
    }
    P[((size_t)blockIdx.y * 2 + 0) * N + n] = acc0;
    P[((size_t)blockIdx.y * 2 + 1) * N + n] = acc1;
}

__global__ __launch_bounds__(256) void gemv2_red(
    const float* __restrict__ P, const float* __restrict__ res,
    float* __restrict__ C, int N) {
    int g = blockIdx.x * 256 + threadIdx.x;
    if (g >= 2 * N) return;
    int m = g / N, n = g - m * N;
    float s = res ? res[g] : 0.f;
#pragma unroll
    for (int ky = 0; ky < KSPL; ++ky)
        s += P[((size_t)ky * 2 + m) * N + n];
    C[g] = s;
}

// ---------------- norms ----------------
__device__ __forceinline__ void stf(float* p, float v) { *p = v; }
__device__ __forceinline__ void stf(f16* p, float v)   { *p = (f16)v; }

template<typename TO>
__global__ __launch_bounds__(256) void rmsnorm_k(
    const float* __restrict__ X, const float* __restrict__ scale,
    TO* __restrict__ Y, int C, int rows_per_group, float sadd) {
    int row = blockIdx.x, tid = threadIdx.x;
    const float* x = X + (size_t)row * C;
    float v[8];
    int cnt = C >> 8;
    float ss = 0.f;
    for (int i = 0; i < cnt; ++i) { v[i] = x[tid + (i << 8)]; ss += v[i] * v[i]; }
    __shared__ float red[256];
    red[tid] = ss; __syncthreads();
    for (int s2 = 128; s2; s2 >>= 1) { if (tid < s2) red[tid] += red[tid + s2]; __syncthreads(); }
    float inv = rsqrtf(red[0] / (float)C + 1e-6f);
    const float* sc = scale + (size_t)(row / rows_per_group) * C;
    TO* y = Y + (size_t)row * C;
    for (int i = 0; i < cnt; ++i) {
        int c = tid + (i << 8);
        stf(&y[c], v[i] * (sadd + sc[c]) * inv);
    }
}

__global__ __launch_bounds__(256) void layernorm_k(
    const float* __restrict__ X, const float* __restrict__ g,
    const float* __restrict__ bta, f16* __restrict__ Y, int C) {
    int row = blockIdx.x, tid = threadIdx.x;
    const float* x = X + (size_t)row * C;
    float v[8];
    int cnt = C >> 8;
    float s = 0.f;
    for (int i = 0; i < cnt; ++i) { v[i] = x[tid + (i << 8)]; s += v[i]; }
    __shared__ float red[256];
    red[tid] = s; __syncthreads();
    for (int s2 = 128; s2; s2 >>= 1) { if (tid < s2) red[tid] += red[tid + s2]; __syncthreads(); }
    float m = red[0] / (float)C;
    __syncthreads();
    float s2s = 0.f;
    for (int i = 0; i < cnt; ++i) { float d = v[i] - m; s2s += d * d; }
    red[tid] = s2s; __syncthreads();
    for (int s2 = 128; s2; s2 >>= 1) { if (tid < s2) red[tid] += red[tid + s2]; __syncthreads(); }
    float inv = rsqrtf(red[0] / (float)C + 1e-5f);
    f16* y = Y + (size_t)row * C;
    for (int i = 0; i < cnt; ++i) {
        int c = tid + (i << 8);
        y[c] = (f16)((v[i] - m) * inv * g[c] + bta[c]);
    }
}

// ---------------- GLU ----------------
__global__ __launch_bounds__(256) void glu_k(
    const float* __restrict__ U, float* __restrict__ Yo,
    size_t total, int F, int mode) {
    size_t gidx = (size_t)blockIdx.x * 256 + threadIdx.x;
    if (gidx >= total) return;
    size_t r = gidx / (size_t)F;
    int c = (int)(gidx - r * F);
    const float* u = U + r * (size_t)(2 * F);
    float a = u[c], gg = u[F + c];
    float act = (mode == 0) ? gelu_tanh(gg) : gg / (1.f + expf(-gg));
    Yo[gidx] = a * act;
}

__global__ __launch_bounds__(256) void glu_h8(
    const f16* __restrict__ U, f16* __restrict__ Yo,
    size_t total8, int F8, int mode) {
    size_t gi = (size_t)blockIdx.x * 256 + threadIdx.x;
    if (gi >= total8) return;
    size_t r = gi / (size_t)F8;
    int c = (int)(gi - r * (size_t)F8);
    const f16* u = U + r * (size_t)F8 * 16;
    half8 av = *(const half8*)(u + c * 8);
    half8 gv = *(const half8*)(u + F8 * 8 + c * 8);
    half8 y;
#pragma unroll
    for (int j = 0; j < 8; ++j) {
        float a = (float)av[j], gg = (float)gv[j];
        float act = (mode == 0) ? gelu_tanh(gg) : gg / (1.f + __expf(-gg));
        y[j] = (f16)(a * act);
    }
    *(half8*)(Yo + gi * 8) = y;
}

// ---------------- QKV split + RoPE (+ q scale 1/8), f16 out ---------------
__global__ __launch_bounds__(256) void qkv_split_rope(
    const float* __restrict__ QKV, f16* __restrict__ Qo,
    f16* __restrict__ Ko, f16* __restrict__ Vo, int S, int H) {
    int g = blockIdx.x * 256 + threadIdx.x;
    int total = BB * S * H * 32;
    if (g >= total) return;
    int i = g & 31;
    int tix = g >> 5;
    int h = tix % H; tix /= H;
    int s = tix % S; int b = tix / S;
    int C = H * 64;
    const float* base = QKV + (size_t)(b * S + s) * 3 * C + h * 64;
    float q1 = base[i], q2 = base[32 + i];
    float k1 = base[C + i], k2 = base[C + 32 + i];
    float v1 = base[2 * C + i], v2 = base[2 * C + 32 + i];
    float inv = expf(-(float)i * 0.28782313662425575f);
    float ang = (float)s * inv;
    float sn, cs;
    sincosf(ang, &sn, &cs);
    size_t o = ((size_t)(b * H + h) * S + s) * 64 + i;
    Qo[o]      = (f16)((q1 * cs - q2 * sn) * 0.125f);
    Qo[o + 32] = (f16)((q2 * cs + q1 * sn) * 0.125f);
    Ko[o]      = (f16)(k1 * cs - k2 * sn);
    Ko[o + 32] = (f16)(k2 * cs + k1 * sn);
    Vo[o]      = (f16)v1;
    Vo[o + 32] = (f16)v2;
}

// ---------------- V transpose: V[bh][S][64] -> Vt[bh][64][Spad] -----------
__global__ __launch_bounds__(256) void vtrans(
    const f16* __restrict__ V, f16* __restrict__ Vt, int S, int Spad) {
    __shared__ f16 T[64][72];
    const int tid = threadIdx.x;
    const int k0 = blockIdx.x * 64;
    const f16* Vb = V + (size_t)blockIdx.y * S * 64;
    f16* Vtb = Vt + (size_t)blockIdx.y * 64 * Spad;
    for (int c = tid; c < 512; c += 256) {
        int kk = c >> 3, d8 = (c & 7) * 8;
        int kg = k0 + kk; kg = kg < S ? kg : S - 1;
        half8 v = *(const half8*)(Vb + (size_t)kg * 64 + d8);
        if (k0 + kk >= S) {
#pragma unroll
            for (int j = 0; j < 8; ++j) v[j] = (f16)0.f;
        }
        *(half8*)(&T[kk][d8]) = v;
    }
    __syncthreads();
    for (int c = tid; c < 512; c += 256) {
        int d = c >> 3, k8 = (c & 7) * 8;
        half8 o;
#pragma unroll
        for (int j = 0; j < 8; ++j) o[j] = T[k8 + j][d];
        *(half8*)(Vtb + (size_t)d * Spad + k0 + k8) = o;
    }
}

// ---------------- split-KV flash attention --------------------------------
// Q,K: [BH][S][64] f16 (Q pre-scaled). Vt: [BH][64][Spad] f16.
// Writes unnormalized partials: Op[z][bh][QR][64] f32, Mst/Lst[z][bh][QR].
// win=0: full attention; win>0: local window. nz = gridDim.z KV splits.
__global__ __launch_bounds__(256) void fattn(
    const f16* __restrict__ Q, const f16* __restrict__ K,
    const f16* __restrict__ Vt, float* __restrict__ Op,
    float* __restrict__ Mst, float* __restrict__ Lst,
    int S, int Spad, int H, int win, int QR) {
    __shared__ __align__(16) f16 Ks[64][72];
    __shared__ __align__(16) f16 Vs[64][72];
    __shared__ __align__(16) f16 Ps[4][32][72];
    const int tid = threadIdx.x;
    const int wv = tid >> 6, ln = tid & 63;
    const int r15 = ln & 15, g = ln >> 4;
    const int bh = blockIdx.y;
    const int NBH = gridDim.y;
    const int z = blockIdx.z, nz = gridDim.z;
    const int q0 = (int)blockIdx.x * 128;
    const f16* Qb = Q + (size_t)bh * S * 64;
    const f16* Kb = K + (size_t)bh * S * 64;
    const f16* Vtb = Vt + (size_t)bh * 64 * Spad;

    half8 aq[2][2];
#pragma unroll
    for (int m = 0; m < 2; ++m) {
        int q = q0 + wv * 32 + m * 16 + r15;
        q = q < S ? q : S - 1;
#pragma unroll
        for (int ks = 0; ks < 2; ++ks)
            aq[m][ks] = *(const half8*)(Qb + (size_t)q * 64 + ks * 32 + g * 8);
    }
    floatx4 o[2][4];
#pragma unroll
    for (int m = 0; m < 2; ++m)
#pragma unroll
        for (int n = 0; n < 4; ++n) o[m][n] = (floatx4)0.f;
    float mst[2][4], lst[2][4];
#pragma unroll
    for (int m = 0; m < 2; ++m)
#pragma unroll
        for (int j = 0; j < 4; ++j) { mst[m][j] = -3.0e38f; lst[m][j] = 0.f; }

    int klo = 0, khi = S;
    if (win) {
        int n = (int)blockIdx.x;
        klo = (n - 1) * win; if (klo < 0) klo = 0;
        khi = (n + 2) * win; if (khi > S) khi = S;
    }
    // carve this block's KV chunk (64-aligned)
    int ntile = (khi - klo + 63) >> 6;
    int chunk = (ntile + nz - 1) / nz;
    int myLo = klo + z * chunk * 64;
    int myHi = klo + (z + 1) * chunk * 64; if (myHi > khi) myHi = khi;

    for (int kb = myLo; kb < myHi; kb += 64) {
        __syncthreads();
#pragma unroll
        for (int i = 0; i < 2; ++i) {
            int c = tid + i * 256;
            int rr = c >> 3, c8 = (c & 7) * 8;
            int kg = kb + rr; kg = kg < S ? kg : S - 1;
            *(half8*)(&Ks[rr][c8]) = *(const half8*)(Kb + (size_t)kg * 64 + c8);
            *(half8*)(&Vs[rr][c8]) = *(const half8*)(Vtb + (size_t)rr * Spad + kb + c8);
        }
        __syncthreads();
        floatx4 s[2][4];
#pragma unroll
        for (int m = 0; m < 2; ++m)
#pragma unroll
            for (int n = 0; n < 4; ++n) s[m][n] = (floatx4)0.f;
#pragma unroll
        for (int ks = 0; ks < 2; ++ks) {
            half8 bk[4];
#pragma unroll
            for (int n = 0; n < 4; ++n)
                bk[n] = *(const half8*)(&Ks[n * 16 + r15][ks * 32 + g * 8]);
#pragma unroll
            for (int m = 0; m < 2; ++m)
#pragma unroll
                for (int n = 0; n < 4; ++n)
                    s[m][n] = __builtin_amdgcn_mfma_f32_16x16x32_f16(aq[m][ks], bk[n], s[m][n], 0, 0, 0);
        }
        if (kb + 64 > S) {
#pragma unroll
            for (int n = 0; n < 4; ++n)
                if (kb + n * 16 + r15 >= S) {
#pragma unroll
                    for (int m = 0; m < 2; ++m) s[m][n] = (floatx4)(-3.0e38f);
                }
        }
#pragma unroll
        for (int m = 0; m < 2; ++m) {
#pragma unroll
            for (int j = 0; j < 4; ++j) {
                float tm = fmaxf(fmaxf(s[m][0][j], s[m][1][j]), fmaxf(s[m][2][j], s[m][3][j]));
                tm = fmaxf(tm, __shfl_xor(tm, 1));
                tm = fmaxf(tm, __shfl_xor(tm, 2));
                tm = fmaxf(tm, __shfl_xor(tm, 4));
                tm = fmaxf(tm, __shfl_xor(tm, 8));
                float mn = fmaxf(mst[m][j], tm);
                float sc = __expf(mst[m][j] - mn);
                mst[m][j] = mn;
                float ts = 0.f;
#pragma unroll
                for (int n = 0; n < 4; ++n) {
                    float p = __expf(s[m][n][j] - mn);
                    s[m][n][j] = p;
                    ts += p;
                }
                ts += __shfl_xor(ts, 1);
                ts += __shfl_xor(ts, 2);
                ts += __shfl_xor(ts, 4);
                ts += __shfl_xor(ts, 8);
                lst[m][j] = lst[m][j] * sc + ts;
#pragma unroll
                for (int n = 0; n < 4; ++n) o[m][n][j] *= sc;
            }
        }
#pragma unroll
        for (int m = 0; m < 2; ++m)
#pragma unroll
            for (int n = 0; n < 4; ++n)
#pragma unroll
                for (int j = 0; j < 4; ++j)
                    Ps[wv][m * 16 + g * 4 + j][n * 16 + r15] = (f16)s[m][n][j];
#pragma unroll
        for (int ks = 0; ks < 2; ++ks) {
            half8 pa[2], bv[4];
#pragma unroll
            for (int m = 0; m < 2; ++m)
                pa[m] = *(const half8*)(&Ps[wv][m * 16 + r15][ks * 32 + g * 8]);
#pragma unroll
            for (int n = 0; n < 4; ++n)
                bv[n] = *(const half8*)(&Vs[n * 16 + r15][ks * 32 + g * 8]);
#pragma unroll
            for (int m = 0; m < 2; ++m)
#pragma unroll
                for (int n = 0; n < 4; ++n)
                    o[m][n] = __builtin_amdgcn_mfma_f32_16x16x32_f16(pa[m], bv[n], o[m][n], 0, 0, 0);
        }
    }
    // write partials (unnormalized o, row stats m/l)
    size_t zb = ((size_t)z * NBH + bh) * QR;
#pragma unroll
    for (int m = 0; m < 2; ++m)
#pragma unroll
        for (int j = 0; j < 4; ++j) {
            int qr = q0 + wv * 32 + m * 16 + g * 4 + j;
            size_t ro = (zb + qr) * 64;
#pragma unroll
            for (int n = 0; n < 4; ++n)
                Op[ro + n * 16 + r15] = o[m][n][j];
            if (r15 == 0) {
                Mst[zb + qr] = mst[m][j];
                Lst[zb + qr] = lst[m][j];
            }
        }
}

// ---------------- flash combine: O = sum_z w_z*Op_z / sum_z w_z*l_z -------
__global__ __launch_bounds__(256) void fcomb(
    const float* __restrict__ Op, const float* __restrict__ Mst,
    const float* __restrict__ Lst, f16* __restrict__ O,
    int S, int H, int QR, int nz, int rows) {
    int g = blockIdx.x * 256 + threadIdx.x;
    int idx = g >> 4;
    int d4 = (g & 15) * 4;
    if (idx >= rows) return;
    int bh = idx / QR, q = idx - bh * QR;
    if (q >= S) return;
    float mstar = -3.0e38f;
    for (int z = 0; z < nz; ++z)
        mstar = fmaxf(mstar, Mst[(size_t)z * rows + idx]);
    float den = 0.f;
    floatx4 num = (floatx4)0.f;
    for (int z = 0; z < nz; ++z) {
        float w = __expf(Mst[(size_t)z * rows + idx] - mstar);
        den += w * Lst[(size_t)z * rows + idx];
        floatx4 ov = *(const floatx4*)(Op + ((size_t)z * rows + idx) * 64 + d4);
        num += w * ov;
    }
    float inv = 1.f / den;
    int b = bh / H, h = bh % H;
    f16* op = O + ((size_t)b * S + q) * (H * 64) + h * 64 + d4;
    half4v hv;
#pragma unroll
    for (int j = 0; j < 4; ++j) hv[j] = (f16)(num[j] * inv);
    *(half4v*)op = hv;
}

// ---------------- small glue kernels ----------------
__global__ __launch_bounds__(256) void patch_in_gather(
    const float* __restrict__ x, f16* __restrict__ out) {
    int g = blockIdx.x * 256 + threadIdx.x;
    if (g >= BB * S0 * 128) return;
    int k = g & 127;
    int n = (g >> 7) & (S0 - 1);
    int b = g >> 18;
    out[g] = (f16)x[(size_t)b * CIO * TT + (size_t)(k >> 1) * TT + 2 * n + (k & 1)];
}

__global__ __launch_bounds__(256) void time_embed(
    const float* __restrict__ t, const float* __restrict__ tw,
    float* __restrict__ te) {
    int g = blockIdx.x * 256 + threadIdx.x;
    if (g >= BB * MAPD) return;
    int b = g / MAPD, j = g % MAPD;
    float w = tw[(j < 512) ? j : j - 512];
    float ang = 6.283185307179586f * t[b] * w;
    te[g] = (j < 512) ? cosf(ang) : sinf(ang);
}

__global__ __launch_bounds__(256) void token_merge_gather(
    const float* __restrict__ A, f16* __restrict__ out) {
    int g = blockIdx.x * 256 + threadIdx.x;
    if (g >= BB * 1024 * 1024) return;
    int k = g & 1023;
    int n = (g >> 10) & 1023;
    int b = g >> 20;
    out[g] = (f16)A[((size_t)b * S0 + 2 * n + (k & 1)) * W0 + (k >> 1)];
}

__global__ __launch_bounds__(256) void concat_mid(
    const float* __restrict__ pre, const float* __restrict__ Dsrc,
    float* __restrict__ Cm) {
    int g = blockIdx.x * 256 + threadIdx.x;
    if (g >= BB * SM * W1) return;
    int c = g & 1023;
    int row = g >> 10;
    int b = row / SM, r = row % SM;
    Cm[g] = (r == 0) ? pre[b * W1 + c]
                     : Dsrc[((size_t)b * 1024 + r - 1) * W1 + c];
}

__global__ __launch_bounds__(256) void gather_drop(
    const f16* __restrict__ Dsrc, f16* __restrict__ out) {
    int g = blockIdx.x * 256 + threadIdx.x;
    if (g >= BB * 1024 * W1) return;
    int c = g & 1023;
    int n = (g >> 10) & 1023;
    int b = g >> 20;
    out[g] = Dsrc[((size_t)b * SM + 1 + n) * W1 + c];
}

__global__ __launch_bounds__(256) void split_scatter_lerp(
    const float* __restrict__ y, const float* __restrict__ skip,
    const float* __restrict__ fac, float* __restrict__ xo) {
    int g = blockIdx.x * 256 + threadIdx.x;
    if (g >= BB * S0 * W0) return;
    int c = g & 511;
    int tk = (g >> 9) & (S0 - 1);
    int b = g >> 20;
    float yv = y[((size_t)b * 1024 + (tk >> 1)) * W1 + (c * 2 + (tk & 1))];
    float sk = skip[g];
    xo[g] = sk + fac[0] * (yv - sk);
}

__global__ __launch_bounds__(256) void patch_out_scatter(
    const float* __restrict__ y, float* __restrict__ out) {
    int g = blockIdx.x * 256 + threadIdx.x;
    if (g >= BB * CIO * TT) return;
    int tk = g & (TT - 1);
    int c = (g >> 12) & 63;
    int b = g >> 18;
    out[g] = y[((size_t)b * S0 + (tk >> 1)) * 128 + (c * 2 + (tk & 1))];
}

// ---------------- host orchestration ----------------
extern "C" void kernel_launch(void* const* d_in, const int* in_sizes, int n_in,
                              void* d_out, int out_size, void* d_ws, size_t ws_size,
                              hipStream_t stream) {
    const float* x          = (const float*)d_in[0];
    const float* t          = (const float*)d_in[1];
    const float* time_w     = (const float*)d_in[2];
    const float* time_in_w  = (const float*)d_in[3];
    const float* map_in_s   = (const float*)d_in[4];
    const float* map_norm_s = (const float*)d_in[5];
    const float* map_up_w   = (const float*)d_in[6];
    const float* map_down_w = (const float*)d_in[7];
    const float* map_out_s  = (const float*)d_in[8];
    const float* patch_in_w = (const float*)d_in[9];
    const float* dn_anorm_w = (const float*)d_in[10];
    const float* dn_qkv_w   = (const float*)d_in[11];
    const float* dn_o_w     = (const float*)d_in[12];
    const float* dn_fnorm_w = (const float*)d_in[13];
    const float* dn_ff1_w   = (const float*)d_in[14];
    const float* dn_ff2_w   = (const float*)d_in[15];
    const float* merge_w    = (const float*)d_in[16];
    const float* mid_map_w  = (const float*)d_in[17];
    const float* mid_pin_w  = (const float*)d_in[18];
    const float* mid_pout_w = (const float*)d_in[19];
    const float* mid_ln1_g  = (const float*)d_in[20];
    const float* mid_ln1_b  = (const float*)d_in[21];
    const float* mid_qkv_w  = (const float*)d_in[22];
    const float* mid_o_w    = (const float*)d_in[23];
    const float* mid_ln2_g  = (const float*)d_in[24];
    const float* mid_ln2_b  = (const float*)d_in[25];
    const float* mid_ff1_w  = (const float*)d_in[26];
    const float* mid_ff2_w  = (const float*)d_in[27];
    const float* mid_fn_g   = (const float*)d_in[28];
    const float* mid_fn_b   = (const float*)d_in[29];
    const float* split_w    = (const float*)d_in[30];
    const float* split_fac  = (const float*)d_in[31];
    const float* up_anorm_w = (const float*)d_in[32];
    const float* up_qkv_w   = (const float*)d_in[33];
    const float* up_o_w     = (const float*)d_in[34];
    const float* up_fnorm_w = (const float*)d_in[35];
    const float* up_ff1_w   = (const float*)d_in[36];
    const float* up_ff2_w   = (const float*)d_in[37];
    const float* out_norm_s = (const float*)d_in[38];
    const float* patch_out_w= (const float*)d_in[39];

    float* Wp = (float*)d_ws;
    size_t off = 0;
    auto alloc = [&](size_t n) { float* p = Wp + off; off += n; return p; };
    float* A   = alloc((size_t)4096 * 512);
    float* Bsk = alloc((size_t)4096 * 512);
    float* Cm  = alloc((size_t)2050 * 1024);
    float* Df  = alloc((size_t)2050 * 1024);
    float* E32 = alloc((size_t)2050 * 3072);
    f16*  Fq   = (f16*)alloc((size_t)1049600);
    f16*  Fk   = (f16*)alloc((size_t)1049600);
    f16*  Fv   = (f16*)alloc((size_t)1049600);
    f16*  Fvt  = (f16*)alloc((size_t)1114112);
    f16*  H1   = (f16*)alloc((size_t)8396800);
    f16*  H2   = (f16*)alloc((size_t)4198400);
    f16*  Wh   = (f16*)alloc((size_t)4194304);
    float* Pk  = alloc((size_t)PKCAP);               // split-K / attn partials
    float* ML  = alloc((size_t)262144);              // attn m/l stats
    float* Pb  = alloc((size_t)KSPL * 2 * 2048);
    float* Sma = alloc((size_t)32768);
    (void)ws_size; (void)in_sizes; (void)n_in; (void)out_size;

    float* te   = Sma;
    float* temb = Sma + 2048;
    float* mapx = Sma + 4096;
    float* maph = Sma + 6144;
    float* mapu = Sma + 8192;
    float* mapg = Sma + 12288;
    float* cond = Sma + 14336;
    float* sA   = Sma + 16384;
    float* sF   = Sma + 17408;
    float* pre  = Sma + 18432;

    auto WC = [&](const float* W, int K, int N) {
        wcast<<<dim3(N / 64, K / 64), 256, 0, stream>>>(W, Wh, K, N);
    };
    auto pick_ks = [](int M, int N, int K) {
        long gx = N / 128, gy = (M + 127) / 128;
        int ks = 1;
        while (gx * gy * ks < 512 && ks < 8) {
            int nk = ks * 2;
            if ((K / nk) % 32 != 0 || (long)M * N * nk > PKCAP) break;
            ks = nk;
        }
        return ks;
    };
    auto GF = [&](const f16* Aa, const float* res, float* C, int M, int N, int K) {
        int ks = pick_ks(M, N, K);
        dim3 g(N / 128, (M + 127) / 128, ks);
        if (ks == 1) {
            gemm_h<0><<<g, 256, 0, stream>>>(Aa, Wh, res, C, M, N, K);
        } else {
            gemm_h<2><<<g, 256, 0, stream>>>(Aa, Wh, nullptr, Pk, M, N, K);
            size_t mn = (size_t)M * N;
            kred<false><<<(int)((mn / 4 + 255) / 256), 256, 0, stream>>>(Pk, res, C, mn, ks);
        }
    };
    auto GH = [&](const f16* Aa, f16* C, int M, int N, int K) {
        int ks = pick_ks(M, N, K);
        dim3 g(N / 128, (M + 127) / 128, ks);
        if (ks == 1) {
            gemm_h<1><<<g, 256, 0, stream>>>(Aa, Wh, nullptr, C, M, N, K);
        } else {
            gemm_h<2><<<g, 256, 0, stream>>>(Aa, Wh, nullptr, Pk, M, N, K);
            size_t mn = (size_t)M * N;
            kred<true><<<(int)((mn / 4 + 255) / 256), 256, 0, stream>>>(Pk, nullptr, C, mn, ks);
        }
    };
    auto gemv2 = [&](const float* Aa, const float* W, const float* res,
                     float* C, int N, int K) {
        gemv2_part<<<dim3((N + 255) / 256, KSPL), 256, 0, stream>>>(Aa, W, Pb, N, K);
        gemv2_red<<<(2 * N + 255) / 256, 256, 0, stream>>>(Pb, res, C, N);
    };
    // split-KV flash attn + combine
    auto FATT = [&](const f16* Qp, const f16* Kp, const f16* Vtp, f16* Out,
                    int S, int Spad, int H, int win, int nq, int nbh, int nz) {
        int QR = nq * 128;
        int rows = nbh * QR;
        fattn<<<dim3(nq, nbh, nz), 256, 0, stream>>>(
            Qp, Kp, Vtp, Pk, ML, ML + (size_t)nz * rows, S, Spad, H, win, QR);
        fcomb<<<(rows * 16 + 255) / 256, 256, 0, stream>>>(
            Pk, ML, ML + (size_t)nz * rows, Out, S, H, QR, nz, rows);
    };

    // ---- patch in ----
    patch_in_gather<<<(BB * S0 * 128 + 255) / 256, 256, 0, stream>>>(x, H2);
    WC(patch_in_w, 128, 512);
    GF(H2, nullptr, A, 4096, 512, 128);

    // ---- time embedding + mapping (tiny, f32) ----
    time_embed<<<(BB * MAPD + 255) / 256, 256, 0, stream>>>(t, time_w, te);
    gemv2(te, time_in_w, nullptr, temb, 1024, 1024);
    rmsnorm_k<float><<<2, 256, 0, stream>>>(temb, map_in_s, mapx, 1024, 2, 0.f);
    for (int l = 0; l < 2; ++l) {
        rmsnorm_k<float><<<2, 256, 0, stream>>>(mapx, map_norm_s + (size_t)l * 1024, maph, 1024, 2, 0.f);
        gemv2(maph, map_up_w + (size_t)l * 1024 * 2048, nullptr, mapu, 2048, 1024);
        glu_k<<<(2 * 1024 + 255) / 256, 256, 0, stream>>>(mapu, mapg, 2 * 1024, 1024, 0);
        gemv2(mapg, map_down_w + (size_t)l * 1024 * 1024, mapx, mapx, 1024, 1024);
    }
    rmsnorm_k<float><<<2, 256, 0, stream>>>(mapx, map_out_s, cond, 1024, 2, 0.f);

    // ---- local level (shared for down/up) ----
    auto run_local = [&](const float* anorm, const float* qkvw, const float* ow,
                         const float* fnorm, const float* ff1, const float* ff2) {
        for (int l = 0; l < 2; ++l) {
            gemv2(cond, anorm + (size_t)l * 1024 * 512, nullptr, sA, 512, 1024);
            rmsnorm_k<f16><<<4096, 256, 0, stream>>>(A, sA, H2, 512, 2048, 1.f);
            WC(qkvw + (size_t)l * 512 * 1536, 512, 1536);
            GF(H2, nullptr, E32, 4096, 1536, 512);
            qkv_split_rope<<<(BB * S0 * HDN * 32 + 255) / 256, 256, 0, stream>>>(E32, Fq, Fk, Fv, S0, HDN);
            vtrans<<<dim3(S0 / 64, BB * HDN), 256, 0, stream>>>(Fv, Fvt, S0, S0);
            FATT(Fq, Fk, Fvt, H2, S0, S0, HDN, WIN, S0 / 128, BB * HDN, 2);
            WC(ow + (size_t)l * 512 * 512, 512, 512);
            GF(H2, A, A, 4096, 512, 512);
            gemv2(cond, fnorm + (size_t)l * 1024 * 512, nullptr, sF, 512, 1024);
            rmsnorm_k<f16><<<4096, 256, 0, stream>>>(A, sF, H2, 512, 2048, 1.f);
            WC(ff1 + (size_t)l * 512 * 2048, 512, 2048);
            GH(H2, H1, 4096, 2048, 512);
            glu_h8<<<(4096 * 128 + 255) / 256, 256, 0, stream>>>(H1, H2, (size_t)4096 * 128, 128, 0);
            WC(ff2 + (size_t)l * 1024 * 512, 1024, 512);
            GF(H2, A, A, 4096, 512, 1024);
        }
    };
    run_local(dn_anorm_w, dn_qkv_w, dn_o_w, dn_fnorm_w, dn_ff1_w, dn_ff2_w);

    // ---- skip save, merge, mid prep ----
    hipMemcpyAsync(Bsk, A, (size_t)4096 * 512 * 4, hipMemcpyDeviceToDevice, stream);
    token_merge_gather<<<(BB * 1024 * 1024 + 255) / 256, 256, 0, stream>>>(A, H2);
    WC(merge_w, 1024, 1024);
    GH(H2, H1, 2048, 1024, 1024);
    WC(mid_pin_w, 1024, 1024);
    GF(H1, nullptr, Df, 2048, 1024, 1024);
    gemv2(cond, mid_map_w, nullptr, pre, 1024, 1024);
    concat_mid<<<(BB * SM * W1 + 255) / 256, 256, 0, stream>>>(pre, Df, Cm);

    // ---- mid level ----
    for (int l = 0; l < 4; ++l) {
        layernorm_k<<<2050, 256, 0, stream>>>(Cm, mid_ln1_g + (size_t)l * 1024,
                                              mid_ln1_b + (size_t)l * 1024, H2, 1024);
        WC(mid_qkv_w + (size_t)l * 1024 * 3072, 1024, 3072);
        GF(H2, nullptr, E32, 2050, 3072, 1024);
        qkv_split_rope<<<(BB * SM * HMID * 32 + 255) / 256, 256, 0, stream>>>(E32, Fq, Fk, Fv, SM, HMID);
        vtrans<<<dim3(SMP / 64, BB * HMID), 256, 0, stream>>>(Fv, Fvt, SM, SMP);
        FATT(Fq, Fk, Fvt, H2, SM, SMP, HMID, 0, 9, BB * HMID, 3);
        WC(mid_o_w + (size_t)l * 1024 * 1024, 1024, 1024);
        GF(H2, Cm, Cm, 2050, 1024, 1024);
        layernorm_k<<<2050, 256, 0, stream>>>(Cm, mid_ln2_g + (size_t)l * 1024,
                                              mid_ln2_b + (size_t)l * 1024, H2, 1024);
        WC(mid_ff1_w + (size_t)l * 1024 * 8192, 1024, 8192);
        GH(H2, H1, 2050, 8192, 1024);
        glu_h8<<<(int)(((size_t)2050 * 512 + 255) / 256), 256, 0, stream>>>(H1, H2, (size_t)2050 * 512, 512, 1);
        WC(mid_ff2_w + (size_t)l * 4096 * 1024, 4096, 1024);
        GF(H2, Cm, Cm, 2050, 1024, 4096);
    }
    layernorm_k<<<2050, 256, 0, stream>>>(Cm, mid_fn_g, mid_fn_b, H2, 1024);

    // ---- pout + token split + lerp skip ----
    WC(mid_pout_w, 1024, 1024);
    GH(H2, H1, 2050, 1024, 1024);
    gather_drop<<<(BB * 1024 * W1 + 255) / 256, 256, 0, stream>>>(H1, H2);
    WC(split_w, 1024, 1024);
    GF(H2, nullptr, Df, 2048, 1024, 1024);
    split_scatter_lerp<<<(BB * S0 * W0 + 255) / 256, 256, 0, stream>>>(Df, Bsk, split_fac, A);

    // ---- up level ----
    run_local(up_anorm_w, up_qkv_w, up_o_w, up_fnorm_w, up_ff1_w, up_ff2_w);

    // ---- out ----
    rmsnorm_k<f16><<<4096, 256, 0, stream>>>(A, out_norm_s, H2, 512, 4096, 0.f);
    WC(patch_out_w, 512, 128);
    GF(H2, nullptr, Df, 4096, 128, 512);
    patch_out_scatter<<<(BB * CIO * TT + 255) / 256, 256, 0, stream>>>(Df, (float*)d_out);
}

// Round 7
// 2109.598 us; speedup vs baseline: 8.8796x; 1.0174x over previous
//
#include <hip/hip_runtime.h>
#include <math.h>

// ---------------- constants ----------------
#define BB   2
#define CIO  64
#define TT   4096
#define S0   2048      // local level seq len
#define W0   512
#define HDN  8
#define SM   1025      // mid seq len (with prepended token)
#define SMP  1088      // padded mid seq (17*64)
#define W1   1024
#define HMID 16
#define WIN  128
#define NW   16        // S0 / WIN
#define MAPD 1024
#define KSPL 16        // split-K factor for M=2 GEMV
#define PKCAP 8396800L // partial buffer capacity (floats)

typedef _Float16 f16;
typedef _Float16 half8 __attribute__((ext_vector_type(8)));
typedef _Float16 half4v __attribute__((ext_vector_type(4)));
typedef _Float16 half2v __attribute__((ext_vector_type(2)));
typedef float floatx4 __attribute__((ext_vector_type(4)));

// ---------------- device helpers ----------------
__device__ __forceinline__ float gelu_tanh(float x) {
    float x3 = x * x * x;
    return 0.5f * x * (1.f + tanhf(0.7978845608028654f * (x + 0.044715f * x3)));
}

// ---------------- weight transpose-cast: W[K][N] f32 -> Wt[N][K] f16 ------
__global__ __launch_bounds__(256) void wcast(
    const float* __restrict__ W, f16* __restrict__ Wt, int K, int N) {
    __shared__ float T[64][65];
    const int n0 = blockIdx.x * 64, k0 = blockIdx.y * 64;
    const int tid = threadIdx.x;
    for (int e = tid; e < 4096; e += 256) {
        int r = e >> 6, c = e & 63;
        T[r][c] = W[(size_t)(k0 + r) * N + n0 + c];
    }
    __syncthreads();
    for (int e = tid; e < 2048; e += 256) {
        int r = e >> 5, c2 = (e & 31) * 2;
        half2v p;
        p[0] = (f16)T[c2][r];
        p[1] = (f16)T[c2 + 1][r];
        *(half2v*)(Wt + (size_t)(n0 + r) * K + k0 + c2) = p;
    }
}

// ---------------- MFMA GEMM: C = (res?) + A[MxK]f16 @ Bt[NxK]f16^T --------
// OUTM: 0 = f32 out (+res), 1 = f16 out, 2 = split-K f32 partial (grid.z)
// 3-buffer, 2-deep prefetch with counted vmcnt (T4) + bijective XCD swizzle.
template<int OUTM>
__global__ __launch_bounds__(256) void gemm_h(
    const f16* __restrict__ A, const f16* __restrict__ Bt,
    const float* __restrict__ res, void* __restrict__ Cv,
    int M, int N, int K) {
    __shared__ __align__(16) f16 As[3][4096];
    __shared__ __align__(16) f16 Bs[3][4096];
    const int tid = threadIdx.x;
    const int wv = tid >> 6, ln = tid & 63;
    int nwg = gridDim.x * gridDim.y;
    int orig = blockIdx.y * gridDim.x + blockIdx.x;
    int wg = orig;
    if (nwg >= 16) {
        int q = nwg >> 3, r = nwg & 7;
        int xcd = orig & 7, lot = orig >> 3;
        wg = (xcd < r ? xcd * (q + 1) : r * (q + 1) + (xcd - r) * q) + lot;
    }
    const int bm = (wg / gridDim.x) * 128, bn = (wg % gridDim.x) * 128;
    int Kc = K, kbase = 0;
    if (OUTM == 2) { Kc = K / gridDim.z; kbase = blockIdx.z * Kc; }
    const int nt = Kc >> 5;

    auto stage = [&](int buf, int kt) {
        int k0 = kbase + (kt << 5);
#pragma unroll
        for (int i = 0; i < 2; ++i) {
            int off = i * 4096 + wv * 1024 + ln * 16;
            int row = off >> 6, kb = (off & 63) >> 1;
            int gr = bm + row; gr = gr < M ? gr : M - 1;
            f16* gp = const_cast<f16*>(A) + (size_t)gr * K + k0 + kb;
            __builtin_amdgcn_global_load_lds(
                (__attribute__((address_space(1))) void*)gp,
                (__attribute__((address_space(3))) void*)(&As[buf][i * 2048 + wv * 512]),
                16, 0, 0);
            f16* gq = const_cast<f16*>(Bt) + (size_t)(bn + row) * K + k0 + kb;
            __builtin_amdgcn_global_load_lds(
                (__attribute__((address_space(1))) void*)gq,
                (__attribute__((address_space(3))) void*)(&Bs[buf][i * 2048 + wv * 512]),
                16, 0, 0);
        }
    };

    floatx4 acc[4][4];
#pragma unroll
    for (int m = 0; m < 4; ++m)
#pragma unroll
        for (int n = 0; n < 4; ++n) acc[m][n] = (floatx4)0.f;
    const int r = ln & 15, kc = (ln >> 4) * 8;
    const int wr = (wv >> 1) * 64, wc = (wv & 1) * 64;

    stage(0, 0);
    if (nt > 1) stage(1, 1);
    int buf = 0;
    for (int t = 0; t < nt; ++t) {
        // wait for own stage(t) loads only; leave stage(t+1)'s 4 in flight
        if (t + 1 < nt) { asm volatile("s_waitcnt vmcnt(4)" ::: "memory"); }
        else            { asm volatile("s_waitcnt vmcnt(0)" ::: "memory"); }
        __builtin_amdgcn_s_barrier();
        if (t + 2 < nt) {
            int nb = buf + 2; if (nb >= 3) nb -= 3;
            stage(nb, t + 2);
        }
        half8 af[4], bf[4];
#pragma unroll
        for (int m = 0; m < 4; ++m)
            af[m] = *(const half8*)(&As[buf][(wr + m * 16 + r) * 32 + kc]);
#pragma unroll
        for (int n = 0; n < 4; ++n)
            bf[n] = *(const half8*)(&Bs[buf][(wc + n * 16 + r) * 32 + kc]);
#pragma unroll
        for (int m = 0; m < 4; ++m)
#pragma unroll
            for (int n = 0; n < 4; ++n)
                acc[m][n] = __builtin_amdgcn_mfma_f32_16x16x32_f16(af[m], bf[n], acc[m][n], 0, 0, 0);
        if (++buf >= 3) buf = 0;
    }

    float* Cf = (float*)Cv;
    f16*   Ch = (f16*)Cv;
    if (OUTM == 2) Cf += (size_t)blockIdx.z * M * N;
#pragma unroll
    for (int m = 0; m < 4; ++m) {
        int rbase = bm + wr + m * 16 + ((ln >> 4) << 2);
#pragma unroll
        for (int j = 0; j < 4; ++j) {
            int row = rbase + j;
            if (row < M) {
                size_t ro = (size_t)row * N;
#pragma unroll
                for (int n = 0; n < 4; ++n) {
                    int col = bn + wc + n * 16 + (ln & 15);
                    float v = acc[m][n][j];
                    if (OUTM == 1) Ch[ro + col] = (f16)v;
                    else if (OUTM == 0) Cf[ro + col] = v + (res ? res[ro + col] : 0.f);
                    else Cf[ro + col] = v;
                }
            }
        }
    }
}

// ---------------- split-K reduce ------------------------------------------
template<bool HOUT>
__global__ __launch_bounds__(256) void kred(
    const float* __restrict__ P, const float* __restrict__ res,
    void* __restrict__ Cv, size_t mn, int ks) {
    size_t i = ((size_t)blockIdx.x * 256 + threadIdx.x) * 4;
    if (i >= mn) return;
    floatx4 s = res ? *(const floatx4*)(res + i) : (floatx4)0.f;
    for (int z = 0; z < ks; ++z) {
        floatx4 p = *(const floatx4*)(P + (size_t)z * mn + i);
        s += p;
    }
    if (HOUT) {
        half4v h;
#pragma unroll
        for (int j = 0; j < 4; ++j) h[j] = (f16)s[j];
        *(half4v*)((f16*)Cv + i) = h;
    } else {
        *(floatx4*)((float*)Cv + i) = s;
    }
}

// ---------------- split-K GEMV for M=2 ------------------------------------
__global__ __launch_bounds__(256) void gemv2_part(
    const float* __restrict__ A, const float* __restrict__ W,
    float* __restrict__ P, int N, int K) {
    int n = blockIdx.x * 256 + threadIdx.x;
    if (n >= N) return;
    int Kc = K / KSPL;
    int k0 = blockIdx.y * Kc;
    float acc0 = 0.f, acc1 = 0.f;
    const float* Wp = W + (size_t)k0 * N + n;
    const float* a0 = A + k0;
    const float* a1 = A + K + k0;
#pragma unroll 4
    for (int k = 0; k < Kc; ++k) {
        float w = Wp[(size_t)k * N];
        acc0 = fmaf(a0[k], w, acc0);
        acc1 = fmaf(a1[k], w, acc1);
    }
    P[((size_t)blockIdx.y * 2 + 0) * N + n] = acc0;
    P[((size_t)blockIdx.y * 2 + 1) * N + n] = acc1;
}

__global__ __launch_bounds__(256) void gemv2_red(
    const float* __restrict__ P, const float* __restrict__ res,
    float* __restrict__ C, int N) {
    int g = blockIdx.x * 256 + threadIdx.x;
    if (g >= 2 * N) return;
    int m = g / N, n = g - m * N;
    float s = res ? res[g] : 0.f;
#pragma unroll
    for (int ky = 0; ky < KSPL; ++ky)
        s += P[((size_t)ky * 2 + m) * N + n];
    C[g] = s;
}

// ---------------- norms ----------------
__device__ __forceinline__ void stf(float* p, float v) { *p = v; }
__device__ __forceinline__ void stf(f16* p, float v)   { *p = (f16)v; }

template<typename TO>
__global__ __launch_bounds__(256) void rmsnorm_k(
    const float* __restrict__ X, const float* __restrict__ scale,
    TO* __restrict__ Y, int C, int rows_per_group, float sadd) {
    int row = blockIdx.x, tid = threadIdx.x;
    const float* x = X + (size_t)row * C;
    float v[8];
    int cnt = C >> 8;
    float ss = 0.f;
    for (int i = 0; i < cnt; ++i) { v[i] = x[tid + (i << 8)]; ss += v[i] * v[i]; }
    __shared__ float red[256];
    red[tid] = ss; __syncthreads();
    for (int s2 = 128; s2; s2 >>= 1) { if (tid < s2) red[tid] += red[tid + s2]; __syncthreads(); }
    float inv = rsqrtf(red[0] / (float)C + 1e-6f);
    const float* sc = scale + (size_t)(row / rows_per_group) * C;
    TO* y = Y + (size_t)row * C;
    for (int i = 0; i < cnt; ++i) {
        int c = tid + (i << 8);
        stf(&y[c], v[i] * (sadd + sc[c]) * inv);
    }
}

__global__ __launch_bounds__(256) void layernorm_k(
    const float* __restrict__ X, const float* __restrict__ g,
    const float* __restrict__ bta, f16* __restrict__ Y, int C) {
    int row = blockIdx.x, tid = threadIdx.x;
    const float* x = X + (size_t)row * C;
    float v[8];
    int cnt = C >> 8;
    float s = 0.f;
    for (int i = 0; i < cnt; ++i) { v[i] = x[tid + (i << 8)]; s += v[i]; }
    __shared__ float red[256];
    red[tid] = s; __syncthreads();
    for (int s2 = 128; s2; s2 >>= 1) { if (tid < s2) red[tid] += red[tid + s2]; __syncthreads(); }
    float m = red[0] / (float)C;
    __syncthreads();
    float s2s = 0.f;
    for (int i = 0; i < cnt; ++i) { float d = v[i] - m; s2s += d * d; }
    red[tid] = s2s; __syncthreads();
    for (int s2 = 128; s2; s2 >>= 1) { if (tid < s2) red[tid] += red[tid + s2]; __syncthreads(); }
    float inv = rsqrtf(red[0] / (float)C + 1e-5f);
    f16* y = Y + (size_t)row * C;
    for (int i = 0; i < cnt; ++i) {
        int c = tid + (i << 8);
        y[c] = (f16)((v[i] - m) * inv * g[c] + bta[c]);
    }
}

// ---------------- GLU ----------------
__global__ __launch_bounds__(256) void glu_k(
    const float* __restrict__ U, float* __restrict__ Yo,
    size_t total, int F, int mode) {
    size_t gidx = (size_t)blockIdx.x * 256 + threadIdx.x;
    if (gidx >= total) return;
    size_t r = gidx / (size_t)F;
    int c = (int)(gidx - r * F);
    const float* u = U + r * (size_t)(2 * F);
    float a = u[c], gg = u[F + c];
    float act = (mode == 0) ? gelu_tanh(gg) : gg / (1.f + expf(-gg));
    Yo[gidx] = a * act;
}

__global__ __launch_bounds__(256) void glu_h8(
    const f16* __restrict__ U, f16* __restrict__ Yo,
    size_t total8, int F8, int mode) {
    size_t gi = (size_t)blockIdx.x * 256 + threadIdx.x;
    if (gi >= total8) return;
    size_t r = gi / (size_t)F8;
    int c = (int)(gi - r * (size_t)F8);
    const f16* u = U + r * (size_t)F8 * 16;
    half8 av = *(const half8*)(u + c * 8);
    half8 gv = *(const half8*)(u + F8 * 8 + c * 8);
    half8 y;
#pragma unroll
    for (int j = 0; j < 8; ++j) {
        float a = (float)av[j], gg = (float)gv[j];
        float act = (mode == 0) ? gelu_tanh(gg) : gg / (1.f + __expf(-gg));
        y[j] = (f16)(a * act);
    }
    *(half8*)(Yo + gi * 8) = y;
}

// ---------------- QKV split + RoPE (+ q scale 1/8), f16 in/out ------------
__global__ __launch_bounds__(256) void qkv_split_rope(
    const f16* __restrict__ QKV, f16* __restrict__ Qo,
    f16* __restrict__ Ko, f16* __restrict__ Vo, int S, int H) {
    int g = blockIdx.x * 256 + threadIdx.x;
    int total = BB * S * H * 32;
    if (g >= total) return;
    int i = g & 31;
    int tix = g >> 5;
    int h = tix % H; tix /= H;
    int s = tix % S; int b = tix / S;
    int C = H * 64;
    const f16* base = QKV + (size_t)(b * S + s) * 3 * C + h * 64;
    float q1 = (float)base[i], q2 = (float)base[32 + i];
    float k1 = (float)base[C + i], k2 = (float)base[C + 32 + i];
    f16 v1 = base[2 * C + i], v2 = base[2 * C + 32 + i];
    float inv = expf(-(float)i * 0.28782313662425575f);
    float ang = (float)s * inv;
    float sn, cs;
    sincosf(ang, &sn, &cs);
    size_t o = ((size_t)(b * H + h) * S + s) * 64 + i;
    Qo[o]      = (f16)((q1 * cs - q2 * sn) * 0.125f);
    Qo[o + 32] = (f16)((q2 * cs + q1 * sn) * 0.125f);
    Ko[o]      = (f16)(k1 * cs - k2 * sn);
    Ko[o + 32] = (f16)(k2 * cs + k1 * sn);
    Vo[o]      = v1;
    Vo[o + 32] = v2;
}

// ---------------- V transpose: V[bh][S][64] -> Vt[bh][64][Spad] -----------
__global__ __launch_bounds__(256) void vtrans(
    const f16* __restrict__ V, f16* __restrict__ Vt, int S, int Spad) {
    __shared__ f16 T[64][72];
    const int tid = threadIdx.x;
    const int k0 = blockIdx.x * 64;
    const f16* Vb = V + (size_t)blockIdx.y * S * 64;
    f16* Vtb = Vt + (size_t)blockIdx.y * 64 * Spad;
    for (int c = tid; c < 512; c += 256) {
        int kk = c >> 3, d8 = (c & 7) * 8;
        int kg = k0 + kk; kg = kg < S ? kg : S - 1;
        half8 v = *(const half8*)(Vb + (size_t)kg * 64 + d8);
        if (k0 + kk >= S) {
#pragma unroll
            for (int j = 0; j < 8; ++j) v[j] = (f16)0.f;
        }
        *(half8*)(&T[kk][d8]) = v;
    }
    __syncthreads();
    for (int c = tid; c < 512; c += 256) {
        int d = c >> 3, k8 = (c & 7) * 8;
        half8 o;
#pragma unroll
        for (int j = 0; j < 8; ++j) o[j] = T[k8 + j][d];
        *(half8*)(Vtb + (size_t)d * Spad + k0 + k8) = o;
    }
}

// ---------------- split-KV flash attention --------------------------------
__global__ __launch_bounds__(256) void fattn(
    const f16* __restrict__ Q, const f16* __restrict__ K,
    const f16* __restrict__ Vt, float* __restrict__ Op,
    float* __restrict__ Mst, float* __restrict__ Lst,
    int S, int Spad, int H, int win, int QR) {
    __shared__ __align__(16) f16 Ks[64][72];
    __shared__ __align__(16) f16 Vs[64][72];
    __shared__ __align__(16) f16 Ps[4][32][72];
    const int tid = threadIdx.x;
    const int wv = tid >> 6, ln = tid & 63;
    const int r15 = ln & 15, g = ln >> 4;
    const int bh = blockIdx.y;
    const int NBH = gridDim.y;
    const int z = blockIdx.z, nz = gridDim.z;
    const int q0 = (int)blockIdx.x * 128;
    const f16* Qb = Q + (size_t)bh * S * 64;
    const f16* Kb = K + (size_t)bh * S * 64;
    const f16* Vtb = Vt + (size_t)bh * 64 * Spad;

    half8 aq[2][2];
#pragma unroll
    for (int m = 0; m < 2; ++m) {
        int q = q0 + wv * 32 + m * 16 + r15;
        q = q < S ? q : S - 1;
#pragma unroll
        for (int ks = 0; ks < 2; ++ks)
            aq[m][ks] = *(const half8*)(Qb + (size_t)q * 64 + ks * 32 + g * 8);
    }
    floatx4 o[2][4];
#pragma unroll
    for (int m = 0; m < 2; ++m)
#pragma unroll
        for (int n = 0; n < 4; ++n) o[m][n] = (floatx4)0.f;
    float mst[2][4], lst[2][4];
#pragma unroll
    for (int m = 0; m < 2; ++m)
#pragma unroll
        for (int j = 0; j < 4; ++j) { mst[m][j] = -3.0e38f; lst[m][j] = 0.f; }

    int klo = 0, khi = S;
    if (win) {
        int n = (int)blockIdx.x;
        klo = (n - 1) * win; if (klo < 0) klo = 0;
        khi = (n + 2) * win; if (khi > S) khi = S;
    }
    int ntile = (khi - klo + 63) >> 6;
    int chunk = (ntile + nz - 1) / nz;
    int myLo = klo + z * chunk * 64;
    int myHi = klo + (z + 1) * chunk * 64; if (myHi > khi) myHi = khi;

    for (int kb = myLo; kb < myHi; kb += 64) {
        __syncthreads();
#pragma unroll
        for (int i = 0; i < 2; ++i) {
            int c = tid + i * 256;
            int rr = c >> 3, c8 = (c & 7) * 8;
            int kg = kb + rr; kg = kg < S ? kg : S - 1;
            *(half8*)(&Ks[rr][c8]) = *(const half8*)(Kb + (size_t)kg * 64 + c8);
            *(half8*)(&Vs[rr][c8]) = *(const half8*)(Vtb + (size_t)rr * Spad + kb + c8);
        }
        __syncthreads();
        floatx4 s[2][4];
#pragma unroll
        for (int m = 0; m < 2; ++m)
#pragma unroll
            for (int n = 0; n < 4; ++n) s[m][n] = (floatx4)0.f;
#pragma unroll
        for (int ks = 0; ks < 2; ++ks) {
            half8 bk[4];
#pragma unroll
            for (int n = 0; n < 4; ++n)
                bk[n] = *(const half8*)(&Ks[n * 16 + r15][ks * 32 + g * 8]);
#pragma unroll
            for (int m = 0; m < 2; ++m)
#pragma unroll
                for (int n = 0; n < 4; ++n)
                    s[m][n] = __builtin_amdgcn_mfma_f32_16x16x32_f16(aq[m][ks], bk[n], s[m][n], 0, 0, 0);
        }
        if (kb + 64 > S) {
#pragma unroll
            for (int n = 0; n < 4; ++n)
                if (kb + n * 16 + r15 >= S) {
#pragma unroll
                    for (int m = 0; m < 2; ++m) s[m][n] = (floatx4)(-3.0e38f);
                }
        }
#pragma unroll
        for (int m = 0; m < 2; ++m) {
#pragma unroll
            for (int j = 0; j < 4; ++j) {
                float tm = fmaxf(fmaxf(s[m][0][j], s[m][1][j]), fmaxf(s[m][2][j], s[m][3][j]));
                tm = fmaxf(tm, __shfl_xor(tm, 1));
                tm = fmaxf(tm, __shfl_xor(tm, 2));
                tm = fmaxf(tm, __shfl_xor(tm, 4));
                tm = fmaxf(tm, __shfl_xor(tm, 8));
                float mn = fmaxf(mst[m][j], tm);
                float sc = __expf(mst[m][j] - mn);
                mst[m][j] = mn;
                float ts = 0.f;
#pragma unroll
                for (int n = 0; n < 4; ++n) {
                    float p = __expf(s[m][n][j] - mn);
                    s[m][n][j] = p;
                    ts += p;
                }
                ts += __shfl_xor(ts, 1);
                ts += __shfl_xor(ts, 2);
                ts += __shfl_xor(ts, 4);
                ts += __shfl_xor(ts, 8);
                lst[m][j] = lst[m][j] * sc + ts;
#pragma unroll
                for (int n = 0; n < 4; ++n) o[m][n][j] *= sc;
            }
        }
#pragma unroll
        for (int m = 0; m < 2; ++m)
#pragma unroll
            for (int n = 0; n < 4; ++n)
#pragma unroll
                for (int j = 0; j < 4; ++j)
                    Ps[wv][m * 16 + g * 4 + j][n * 16 + r15] = (f16)s[m][n][j];
#pragma unroll
        for (int ks = 0; ks < 2; ++ks) {
            half8 pa[2], bv[4];
#pragma unroll
            for (int m = 0; m < 2; ++m)
                pa[m] = *(const half8*)(&Ps[wv][m * 16 + r15][ks * 32 + g * 8]);
#pragma unroll
            for (int n = 0; n < 4; ++n)
                bv[n] = *(const half8*)(&Vs[n * 16 + r15][ks * 32 + g * 8]);
#pragma unroll
            for (int m = 0; m < 2; ++m)
#pragma unroll
                for (int n = 0; n < 4; ++n)
                    o[m][n] = __builtin_amdgcn_mfma_f32_16x16x32_f16(pa[m], bv[n], o[m][n], 0, 0, 0);
        }
    }
    size_t zb = ((size_t)z * NBH + bh) * QR;
#pragma unroll
    for (int m = 0; m < 2; ++m)
#pragma unroll
        for (int j = 0; j < 4; ++j) {
            int qr = q0 + wv * 32 + m * 16 + g * 4 + j;
            size_t ro = (zb + qr) * 64;
#pragma unroll
            for (int n = 0; n < 4; ++n)
                Op[ro + n * 16 + r15] = o[m][n][j];
            if (r15 == 0) {
                Mst[zb + qr] = mst[m][j];
                Lst[zb + qr] = lst[m][j];
            }
        }
}

// ---------------- flash combine -------------------------------------------
__global__ __launch_bounds__(256) void fcomb(
    const float* __restrict__ Op, const float* __restrict__ Mst,
    const float* __restrict__ Lst, f16* __restrict__ O,
    int S, int H, int QR, int nz, int rows) {
    int g = blockIdx.x * 256 + threadIdx.x;
    int idx = g >> 4;
    int d4 = (g & 15) * 4;
    if (idx >= rows) return;
    int bh = idx / QR, q = idx - bh * QR;
    if (q >= S) return;
    float mstar = -3.0e38f;
    for (int z = 0; z < nz; ++z)
        mstar = fmaxf(mstar, Mst[(size_t)z * rows + idx]);
    float den = 0.f;
    floatx4 num = (floatx4)0.f;
    for (int z = 0; z < nz; ++z) {
        float w = __expf(Mst[(size_t)z * rows + idx] - mstar);
        den += w * Lst[(size_t)z * rows + idx];
        floatx4 ov = *(const floatx4*)(Op + ((size_t)z * rows + idx) * 64 + d4);
        num += w * ov;
    }
    float inv = 1.f / den;
    int b = bh / H, h = bh % H;
    f16* op = O + ((size_t)b * S + q) * (H * 64) + h * 64 + d4;
    half4v hv;
#pragma unroll
    for (int j = 0; j < 4; ++j) hv[j] = (f16)(num[j] * inv);
    *(half4v*)op = hv;
}

// ---------------- small glue kernels ----------------
__global__ __launch_bounds__(256) void patch_in_gather(
    const float* __restrict__ x, f16* __restrict__ out) {
    int g = blockIdx.x * 256 + threadIdx.x;
    if (g >= BB * S0 * 128) return;
    int k = g & 127;
    int n = (g >> 7) & (S0 - 1);
    int b = g >> 18;
    out[g] = (f16)x[(size_t)b * CIO * TT + (size_t)(k >> 1) * TT + 2 * n + (k & 1)];
}

__global__ __launch_bounds__(256) void time_embed(
    const float* __restrict__ t, const float* __restrict__ tw,
    float* __restrict__ te) {
    int g = blockIdx.x * 256 + threadIdx.x;
    if (g >= BB * MAPD) return;
    int b = g / MAPD, j = g % MAPD;
    float w = tw[(j < 512) ? j : j - 512];
    float ang = 6.283185307179586f * t[b] * w;
    te[g] = (j < 512) ? cosf(ang) : sinf(ang);
}

__global__ __launch_bounds__(256) void token_merge_gather(
    const float* __restrict__ A, f16* __restrict__ out) {
    int g = blockIdx.x * 256 + threadIdx.x;
    if (g >= BB * 1024 * 1024) return;
    int k = g & 1023;
    int n = (g >> 10) & 1023;
    int b = g >> 20;
    out[g] = (f16)A[((size_t)b * S0 + 2 * n + (k & 1)) * W0 + (k >> 1)];
}

__global__ __launch_bounds__(256) void concat_mid(
    const float* __restrict__ pre, const float* __restrict__ Dsrc,
    float* __restrict__ Cm) {
    int g = blockIdx.x * 256 + threadIdx.x;
    if (g >= BB * SM * W1) return;
    int c = g & 1023;
    int row = g >> 10;
    int b = row / SM, r = row % SM;
    Cm[g] = (r == 0) ? pre[b * W1 + c]
                     : Dsrc[((size_t)b * 1024 + r - 1) * W1 + c];
}

__global__ __launch_bounds__(256) void gather_drop(
    const f16* __restrict__ Dsrc, f16* __restrict__ out) {
    int g = blockIdx.x * 256 + threadIdx.x;
    if (g >= BB * 1024 * W1) return;
    int c = g & 1023;
    int n = (g >> 10) & 1023;
    int b = g >> 20;
    out[g] = Dsrc[((size_t)b * SM + 1 + n) * W1 + c];
}

__global__ __launch_bounds__(256) void split_scatter_lerp(
    const float* __restrict__ y, const float* __restrict__ skip,
    const float* __restrict__ fac, float* __restrict__ xo) {
    int g = blockIdx.x * 256 + threadIdx.x;
    if (g >= BB * S0 * W0) return;
    int c = g & 511;
    int tk = (g >> 9) & (S0 - 1);
    int b = g >> 20;
    float yv = y[((size_t)b * 1024 + (tk >> 1)) * W1 + (c * 2 + (tk & 1))];
    float sk = skip[g];
    xo[g] = sk + fac[0] * (yv - sk);
}

__global__ __launch_bounds__(256) void patch_out_scatter(
    const float* __restrict__ y, float* __restrict__ out) {
    int g = blockIdx.x * 256 + threadIdx.x;
    if (g >= BB * CIO * TT) return;
    int tk = g & (TT - 1);
    int c = (g >> 12) & 63;
    int b = g >> 18;
    out[g] = y[((size_t)b * S0 + (tk >> 1)) * 128 + (c * 2 + (tk & 1))];
}

// ---------------- host orchestration ----------------
extern "C" void kernel_launch(void* const* d_in, const int* in_sizes, int n_in,
                              void* d_out, int out_size, void* d_ws, size_t ws_size,
                              hipStream_t stream) {
    const float* x          = (const float*)d_in[0];
    const float* t          = (const float*)d_in[1];
    const float* time_w     = (const float*)d_in[2];
    const float* time_in_w  = (const float*)d_in[3];
    const float* map_in_s   = (const float*)d_in[4];
    const float* map_norm_s = (const float*)d_in[5];
    const float* map_up_w   = (const float*)d_in[6];
    const float* map_down_w = (const float*)d_in[7];
    const float* map_out_s  = (const float*)d_in[8];
    const float* patch_in_w = (const float*)d_in[9];
    const float* dn_anorm_w = (const float*)d_in[10];
    const float* dn_qkv_w   = (const float*)d_in[11];
    const float* dn_o_w     = (const float*)d_in[12];
    const float* dn_fnorm_w = (const float*)d_in[13];
    const float* dn_ff1_w   = (const float*)d_in[14];
    const float* dn_ff2_w   = (const float*)d_in[15];
    const float* merge_w    = (const float*)d_in[16];
    const float* mid_map_w  = (const float*)d_in[17];
    const float* mid_pin_w  = (const float*)d_in[18];
    const float* mid_pout_w = (const float*)d_in[19];
    const float* mid_ln1_g  = (const float*)d_in[20];
    const float* mid_ln1_b  = (const float*)d_in[21];
    const float* mid_qkv_w  = (const float*)d_in[22];
    const float* mid_o_w    = (const float*)d_in[23];
    const float* mid_ln2_g  = (const float*)d_in[24];
    const float* mid_ln2_b  = (const float*)d_in[25];
    const float* mid_ff1_w  = (const float*)d_in[26];
    const float* mid_ff2_w  = (const float*)d_in[27];
    const float* mid_fn_g   = (const float*)d_in[28];
    const float* mid_fn_b   = (const float*)d_in[29];
    const float* split_w    = (const float*)d_in[30];
    const float* split_fac  = (const float*)d_in[31];
    const float* up_anorm_w = (const float*)d_in[32];
    const float* up_qkv_w   = (const float*)d_in[33];
    const float* up_o_w     = (const float*)d_in[34];
    const float* up_fnorm_w = (const float*)d_in[35];
    const float* up_ff1_w   = (const float*)d_in[36];
    const float* up_ff2_w   = (const float*)d_in[37];
    const float* out_norm_s = (const float*)d_in[38];
    const float* patch_out_w= (const float*)d_in[39];

    float* Wp = (float*)d_ws;
    size_t off = 0;
    auto alloc = [&](size_t n) { float* p = Wp + off; off += n; return p; };
    float* A   = alloc((size_t)4096 * 512);
    float* Bsk = alloc((size_t)4096 * 512);
    float* Cm  = alloc((size_t)2050 * 1024);
    float* Df  = alloc((size_t)2050 * 1024);
    f16*  Fq   = (f16*)alloc((size_t)1049600);
    f16*  Fk   = (f16*)alloc((size_t)1049600);
    f16*  Fv   = (f16*)alloc((size_t)1049600);
    f16*  Fvt  = (f16*)alloc((size_t)1114112);
    f16*  H1   = (f16*)alloc((size_t)8396800);       // 16.79M halves
    f16*  H2   = (f16*)alloc((size_t)4198400);
    f16*  Wh   = (f16*)alloc((size_t)4194304);
    float* Pk  = alloc((size_t)PKCAP);               // split-K / attn partials
    float* ML  = alloc((size_t)262144);
    float* Pb  = alloc((size_t)KSPL * 2 * 2048);
    float* Sma = alloc((size_t)32768);
    (void)ws_size; (void)in_sizes; (void)n_in; (void)out_size;

    float* te   = Sma;
    float* temb = Sma + 2048;
    float* mapx = Sma + 4096;
    float* maph = Sma + 6144;
    float* mapu = Sma + 8192;
    float* mapg = Sma + 12288;
    float* cond = Sma + 14336;
    float* sA   = Sma + 16384;
    float* sF   = Sma + 17408;
    float* pre  = Sma + 18432;

    auto WC = [&](const float* W, int K, int N) {
        wcast<<<dim3(N / 64, K / 64), 256, 0, stream>>>(W, Wh, K, N);
    };
    auto pick_ks = [](int M, int N, int K) {
        long gx = N / 128, gy = (M + 127) / 128;
        int ks = 1;
        while (gx * gy * ks < 512 && ks < 8) {
            int nk = ks * 2;
            if ((K / nk) % 32 != 0 || (long)M * N * nk > PKCAP) break;
            ks = nk;
        }
        return ks;
    };
    auto GF = [&](const f16* Aa, const float* res, float* C, int M, int N, int K) {
        int ks = pick_ks(M, N, K);
        dim3 g(N / 128, (M + 127) / 128, ks);
        if (ks == 1) {
            gemm_h<0><<<g, 256, 0, stream>>>(Aa, Wh, res, C, M, N, K);
        } else {
            gemm_h<2><<<g, 256, 0, stream>>>(Aa, Wh, nullptr, Pk, M, N, K);
            size_t mn = (size_t)M * N;
            kred<false><<<(int)((mn / 4 + 255) / 256), 256, 0, stream>>>(Pk, res, C, mn, ks);
        }
    };
    auto GH = [&](const f16* Aa, f16* C, int M, int N, int K) {
        int ks = pick_ks(M, N, K);
        dim3 g(N / 128, (M + 127) / 128, ks);
        if (ks == 1) {
            gemm_h<1><<<g, 256, 0, stream>>>(Aa, Wh, nullptr, C, M, N, K);
        } else {
            gemm_h<2><<<g, 256, 0, stream>>>(Aa, Wh, nullptr, Pk, M, N, K);
            size_t mn = (size_t)M * N;
            kred<true><<<(int)((mn / 4 + 255) / 256), 256, 0, stream>>>(Pk, nullptr, C, mn, ks);
        }
    };
    auto gemv2 = [&](const float* Aa, const float* W, const float* res,
                     float* C, int N, int K) {
        gemv2_part<<<dim3((N + 255) / 256, KSPL), 256, 0, stream>>>(Aa, W, Pb, N, K);
        gemv2_red<<<(2 * N + 255) / 256, 256, 0, stream>>>(Pb, res, C, N);
    };
    auto FATT = [&](const f16* Qp, const f16* Kp, const f16* Vtp, f16* Out,
                    int S, int Spad, int H, int win, int nq, int nbh, int nz) {
        int QR = nq * 128;
        int rows = nbh * QR;
        fattn<<<dim3(nq, nbh, nz), 256, 0, stream>>>(
            Qp, Kp, Vtp, Pk, ML, ML + (size_t)nz * rows, S, Spad, H, win, QR);
        fcomb<<<(rows * 16 + 255) / 256, 256, 0, stream>>>(
            Pk, ML, ML + (size_t)nz * rows, Out, S, H, QR, nz, rows);
    };

    // ---- patch in ----
    patch_in_gather<<<(BB * S0 * 128 + 255) / 256, 256, 0, stream>>>(x, H2);
    WC(patch_in_w, 128, 512);
    GF(H2, nullptr, A, 4096, 512, 128);

    // ---- time embedding + mapping (tiny, f32) ----
    time_embed<<<(BB * MAPD + 255) / 256, 256, 0, stream>>>(t, time_w, te);
    gemv2(te, time_in_w, nullptr, temb, 1024, 1024);
    rmsnorm_k<float><<<2, 256, 0, stream>>>(temb, map_in_s, mapx, 1024, 2, 0.f);
    for (int l = 0; l < 2; ++l) {
        rmsnorm_k<float><<<2, 256, 0, stream>>>(mapx, map_norm_s + (size_t)l * 1024, maph, 1024, 2, 0.f);
        gemv2(maph, map_up_w + (size_t)l * 1024 * 2048, nullptr, mapu, 2048, 1024);
        glu_k<<<(2 * 1024 + 255) / 256, 256, 0, stream>>>(mapu, mapg, 2 * 1024, 1024, 0);
        gemv2(mapg, map_down_w + (size_t)l * 1024 * 1024, mapx, mapx, 1024, 1024);
    }
    rmsnorm_k<float><<<2, 256, 0, stream>>>(mapx, map_out_s, cond, 1024, 2, 0.f);

    // ---- local level (shared for down/up) ----
    auto run_local = [&](const float* anorm, const float* qkvw, const float* ow,
                         const float* fnorm, const float* ff1, const float* ff2) {
        for (int l = 0; l < 2; ++l) {
            gemv2(cond, anorm + (size_t)l * 1024 * 512, nullptr, sA, 512, 1024);
            rmsnorm_k<f16><<<4096, 256, 0, stream>>>(A, sA, H2, 512, 2048, 1.f);
            WC(qkvw + (size_t)l * 512 * 1536, 512, 1536);
            GH(H2, H1, 4096, 1536, 512);
            qkv_split_rope<<<(BB * S0 * HDN * 32 + 255) / 256, 256, 0, stream>>>(H1, Fq, Fk, Fv, S0, HDN);
            vtrans<<<dim3(S0 / 64, BB * HDN), 256, 0, stream>>>(Fv, Fvt, S0, S0);
            FATT(Fq, Fk, Fvt, H2, S0, S0, HDN, WIN, S0 / 128, BB * HDN, 2);
            WC(ow + (size_t)l * 512 * 512, 512, 512);
            GF(H2, A, A, 4096, 512, 512);
            gemv2(cond, fnorm + (size_t)l * 1024 * 512, nullptr, sF, 512, 1024);
            rmsnorm_k<f16><<<4096, 256, 0, stream>>>(A, sF, H2, 512, 2048, 1.f);
            WC(ff1 + (size_t)l * 512 * 2048, 512, 2048);
            GH(H2, H1, 4096, 2048, 512);
            glu_h8<<<(4096 * 128 + 255) / 256, 256, 0, stream>>>(H1, H2, (size_t)4096 * 128, 128, 0);
            WC(ff2 + (size_t)l * 1024 * 512, 1024, 512);
            GF(H2, A, A, 4096, 512, 1024);
        }
    };
    run_local(dn_anorm_w, dn_qkv_w, dn_o_w, dn_fnorm_w, dn_ff1_w, dn_ff2_w);

    // ---- skip save, merge, mid prep ----
    hipMemcpyAsync(Bsk, A, (size_t)4096 * 512 * 4, hipMemcpyDeviceToDevice, stream);
    token_merge_gather<<<(BB * 1024 * 1024 + 255) / 256, 256, 0, stream>>>(A, H2);
    WC(merge_w, 1024, 1024);
    GH(H2, H1, 2048, 1024, 1024);
    WC(mid_pin_w, 1024, 1024);
    GF(H1, nullptr, Df, 2048, 1024, 1024);
    gemv2(cond, mid_map_w, nullptr, pre, 1024, 1024);
    concat_mid<<<(BB * SM * W1 + 255) / 256, 256, 0, stream>>>(pre, Df, Cm);

    // ---- mid level ----
    for (int l = 0; l < 4; ++l) {
        layernorm_k<<<2050, 256, 0, stream>>>(Cm, mid_ln1_g + (size_t)l * 1024,
                                              mid_ln1_b + (size_t)l * 1024, H2, 1024);
        WC(mid_qkv_w + (size_t)l * 1024 * 3072, 1024, 3072);
        GH(H2, H1, 2050, 3072, 1024);
        qkv_split_rope<<<(BB * SM * HMID * 32 + 255) / 256, 256, 0, stream>>>(H1, Fq, Fk, Fv, SM, HMID);
        vtrans<<<dim3(SMP / 64, BB * HMID), 256, 0, stream>>>(Fv, Fvt, SM, SMP);
        FATT(Fq, Fk, Fvt, H2, SM, SMP, HMID, 0, 9, BB * HMID, 3);
        WC(mid_o_w + (size_t)l * 1024 * 1024, 1024, 1024);
        GF(H2, Cm, Cm, 2050, 1024, 1024);
        layernorm_k<<<2050, 256, 0, stream>>>(Cm, mid_ln2_g + (size_t)l * 1024,
                                              mid_ln2_b + (size_t)l * 1024, H2, 1024);
        WC(mid_ff1_w + (size_t)l * 1024 * 8192, 1024, 8192);
        GH(H2, H1, 2050, 8192, 1024);
        glu_h8<<<(int)(((size_t)2050 * 512 + 255) / 256), 256, 0, stream>>>(H1, H2, (size_t)2050 * 512, 512, 1);
        WC(mid_ff2_w + (size_t)l * 4096 * 1024, 4096, 1024);
        GF(H2, Cm, Cm, 2050, 1024, 4096);
    }
    layernorm_k<<<2050, 256, 0, stream>>>(Cm, mid_fn_g, mid_fn_b, H2, 1024);

    // ---- pout + token split + lerp skip ----
    WC(mid_pout_w, 1024, 1024);
    GH(H2, H1, 2050, 1024, 1024);
    gather_drop<<<(BB * 1024 * W1 + 255) / 256, 256, 0, stream>>>(H1, H2);
    WC(split_w, 1024, 1024);
    GF(H2, nullptr, Df, 2048, 1024, 1024);
    split_scatter_lerp<<<(BB * S0 * W0 + 255) / 256, 256, 0, stream>>>(Df, Bsk, split_fac, A);

    // ---- up level ----
    run_local(up_anorm_w, up_qkv_w, up_o_w, up_fnorm_w, up_ff1_w, up_ff2_w);

    // ---- out ----
    rmsnorm_k<f16><<<4096, 256, 0, stream>>>(A, out_norm_s, H2, 512, 4096, 0.f);
    WC(patch_out_w, 512, 128);
    GF(H2, nullptr, Df, 4096, 128, 512);
    patch_out_scatter<<<(BB * CIO * TT + 255) / 256, 256, 0, stream>>>(Df, (float*)d_out);
}

// Round 8
// 2100.906 us; speedup vs baseline: 8.9164x; 1.0041x over previous
//
#include <hip/hip_runtime.h>
#include <math.h>

// ---------------- constants ----------------
#define BB   2
#define CIO  64
#define TT   4096
#define S0   2048      // local level seq len
#define W0   512
#define HDN  8
#define SM   1025      // mid seq len (with prepended token)
#define SMP  1088      // padded mid seq (17*64)
#define W1   1024
#define HMID 16
#define WIN  128
#define NW   16        // S0 / WIN
#define MAPD 1024
#define KSPL 16        // split-K factor for M=2 GEMV
#define PKCAP 8396800L // partial buffer capacity (floats)

typedef _Float16 f16;
typedef _Float16 half8 __attribute__((ext_vector_type(8)));
typedef _Float16 half4v __attribute__((ext_vector_type(4)));
typedef _Float16 half2v __attribute__((ext_vector_type(2)));
typedef float floatx4 __attribute__((ext_vector_type(4)));

// ---------------- device helpers ----------------
__device__ __forceinline__ float gelu_tanh(float x) {
    float x3 = x * x * x;
    return 0.5f * x * (1.f + tanhf(0.7978845608028654f * (x + 0.044715f * x3)));
}

// ---------------- weight transpose-cast: W[K][N] f32 -> Wt[N][K] f16 ------
__global__ __launch_bounds__(256) void wcast(
    const float* __restrict__ W, f16* __restrict__ Wt, int K, int N) {
    __shared__ float T[64][65];
    const int n0 = blockIdx.x * 64, k0 = blockIdx.y * 64;
    const int tid = threadIdx.x;
    for (int e = tid; e < 4096; e += 256) {
        int r = e >> 6, c = e & 63;
        T[r][c] = W[(size_t)(k0 + r) * N + n0 + c];
    }
    __syncthreads();
    for (int e = tid; e < 2048; e += 256) {
        int r = e >> 5, c2 = (e & 31) * 2;
        half2v p;
        p[0] = (f16)T[c2][r];
        p[1] = (f16)T[c2 + 1][r];
        *(half2v*)(Wt + (size_t)(n0 + r) * K + k0 + c2) = p;
    }
}

// ---------------- MFMA GEMM: C = (res?) + A[MxK]f16 @ Bt[NxK]f16^T --------
// OUTM: 0 = f32 out (+res), 1 = f16 out, 2 = split-K f32 partial (grid.z)
template<int OUTM>
__global__ __launch_bounds__(256) void gemm_h(
    const f16* __restrict__ A, const f16* __restrict__ Bt,
    const float* __restrict__ res, void* __restrict__ Cv,
    int M, int N, int K) {
    __shared__ __align__(16) f16 As[3][4096];
    __shared__ __align__(16) f16 Bs[3][4096];
    const int tid = threadIdx.x;
    const int wv = tid >> 6, ln = tid & 63;
    int nwg = gridDim.x * gridDim.y;
    int orig = blockIdx.y * gridDim.x + blockIdx.x;
    int wg = orig;
    if (nwg >= 16) {
        int q = nwg >> 3, r = nwg & 7;
        int xcd = orig & 7, lot = orig >> 3;
        wg = (xcd < r ? xcd * (q + 1) : r * (q + 1) + (xcd - r) * q) + lot;
    }
    const int bm = (wg / gridDim.x) * 128, bn = (wg % gridDim.x) * 128;
    int Kc = K, kbase = 0;
    if (OUTM == 2) { Kc = K / gridDim.z; kbase = blockIdx.z * Kc; }
    const int nt = Kc >> 5;

    auto stage = [&](int buf, int kt) {
        int k0 = kbase + (kt << 5);
#pragma unroll
        for (int i = 0; i < 2; ++i) {
            int off = i * 4096 + wv * 1024 + ln * 16;
            int row = off >> 6, kb = (off & 63) >> 1;
            int gr = bm + row; gr = gr < M ? gr : M - 1;
            f16* gp = const_cast<f16*>(A) + (size_t)gr * K + k0 + kb;
            __builtin_amdgcn_global_load_lds(
                (__attribute__((address_space(1))) void*)gp,
                (__attribute__((address_space(3))) void*)(&As[buf][i * 2048 + wv * 512]),
                16, 0, 0);
            f16* gq = const_cast<f16*>(Bt) + (size_t)(bn + row) * K + k0 + kb;
            __builtin_amdgcn_global_load_lds(
                (__attribute__((address_space(1))) void*)gq,
                (__attribute__((address_space(3))) void*)(&Bs[buf][i * 2048 + wv * 512]),
                16, 0, 0);
        }
    };

    floatx4 acc[4][4];
#pragma unroll
    for (int m = 0; m < 4; ++m)
#pragma unroll
        for (int n = 0; n < 4; ++n) acc[m][n] = (floatx4)0.f;
    const int r = ln & 15, kc = (ln >> 4) * 8;
    const int wr = (wv >> 1) * 64, wc = (wv & 1) * 64;

    stage(0, 0);
    if (nt > 1) stage(1, 1);
    int buf = 0;
    for (int t = 0; t < nt; ++t) {
        if (t + 1 < nt) { asm volatile("s_waitcnt vmcnt(4)" ::: "memory"); }
        else            { asm volatile("s_waitcnt vmcnt(0)" ::: "memory"); }
        __builtin_amdgcn_s_barrier();
        if (t + 2 < nt) {
            int nb = buf + 2; if (nb >= 3) nb -= 3;
            stage(nb, t + 2);
        }
        half8 af[4], bf[4];
#pragma unroll
        for (int m = 0; m < 4; ++m)
            af[m] = *(const half8*)(&As[buf][(wr + m * 16 + r) * 32 + kc]);
#pragma unroll
        for (int n = 0; n < 4; ++n)
            bf[n] = *(const half8*)(&Bs[buf][(wc + n * 16 + r) * 32 + kc]);
#pragma unroll
        for (int m = 0; m < 4; ++m)
#pragma unroll
            for (int n = 0; n < 4; ++n)
                acc[m][n] = __builtin_amdgcn_mfma_f32_16x16x32_f16(af[m], bf[n], acc[m][n], 0, 0, 0);
        if (++buf >= 3) buf = 0;
    }

    float* Cf = (float*)Cv;
    f16*   Ch = (f16*)Cv;
    if (OUTM == 2) Cf += (size_t)blockIdx.z * M * N;
#pragma unroll
    for (int m = 0; m < 4; ++m) {
        int rbase = bm + wr + m * 16 + ((ln >> 4) << 2);
#pragma unroll
        for (int j = 0; j < 4; ++j) {
            int row = rbase + j;
            if (row < M) {
                size_t ro = (size_t)row * N;
#pragma unroll
                for (int n = 0; n < 4; ++n) {
                    int col = bn + wc + n * 16 + (ln & 15);
                    float v = acc[m][n][j];
                    if (OUTM == 1) Ch[ro + col] = (f16)v;
                    else if (OUTM == 0) Cf[ro + col] = v + (res ? res[ro + col] : 0.f);
                    else Cf[ro + col] = v;
                }
            }
        }
    }
}

// ---------------- QKV GEMM with fused rope+split epilogue -----------------
// A[M][K] f16, Bt[N][K] f16 (N = 3*C). Writes Fq (scaled+rope), Fk (rope),
// Fv directly in [BH][S][64] layout. tab[s][i][2] = (cos, sin), i in [0,32).
__global__ __launch_bounds__(256) void gemm_qkv(
    const f16* __restrict__ A, const f16* __restrict__ Bt,
    const float* __restrict__ tab, f16* __restrict__ Fq,
    f16* __restrict__ Fk, f16* __restrict__ Fv,
    int M, int N, int K, int S, int H) {
    __shared__ __align__(16) f16 As[3][4096];
    __shared__ __align__(16) f16 Bs[3][4096];
    const int tid = threadIdx.x;
    const int wv = tid >> 6, ln = tid & 63;
    int nwg = gridDim.x * gridDim.y;
    int orig = blockIdx.y * gridDim.x + blockIdx.x;
    int wg = orig;
    if (nwg >= 16) {
        int q = nwg >> 3, r = nwg & 7;
        int xcd = orig & 7, lot = orig >> 3;
        wg = (xcd < r ? xcd * (q + 1) : r * (q + 1) + (xcd - r) * q) + lot;
    }
    const int bm = (wg / gridDim.x) * 128, bn = (wg % gridDim.x) * 128;
    const int nt = K >> 5;

    auto stage = [&](int buf, int kt) {
        int k0 = kt << 5;
#pragma unroll
        for (int i = 0; i < 2; ++i) {
            int off = i * 4096 + wv * 1024 + ln * 16;
            int row = off >> 6, kb = (off & 63) >> 1;
            int gr = bm + row; gr = gr < M ? gr : M - 1;
            f16* gp = const_cast<f16*>(A) + (size_t)gr * K + k0 + kb;
            __builtin_amdgcn_global_load_lds(
                (__attribute__((address_space(1))) void*)gp,
                (__attribute__((address_space(3))) void*)(&As[buf][i * 2048 + wv * 512]),
                16, 0, 0);
            f16* gq = const_cast<f16*>(Bt) + (size_t)(bn + row) * K + k0 + kb;
            __builtin_amdgcn_global_load_lds(
                (__attribute__((address_space(1))) void*)gq,
                (__attribute__((address_space(3))) void*)(&Bs[buf][i * 2048 + wv * 512]),
                16, 0, 0);
        }
    };

    floatx4 acc[4][4];
#pragma unroll
    for (int m = 0; m < 4; ++m)
#pragma unroll
        for (int n = 0; n < 4; ++n) acc[m][n] = (floatx4)0.f;
    const int r = ln & 15, kc = (ln >> 4) * 8;
    const int wr = (wv >> 1) * 64, wc = (wv & 1) * 64;

    stage(0, 0);
    if (nt > 1) stage(1, 1);
    int buf = 0;
    for (int t = 0; t < nt; ++t) {
        if (t + 1 < nt) { asm volatile("s_waitcnt vmcnt(4)" ::: "memory"); }
        else            { asm volatile("s_waitcnt vmcnt(0)" ::: "memory"); }
        __builtin_amdgcn_s_barrier();
        if (t + 2 < nt) {
            int nb = buf + 2; if (nb >= 3) nb -= 3;
            stage(nb, t + 2);
        }
        half8 af[4], bf[4];
#pragma unroll
        for (int m = 0; m < 4; ++m)
            af[m] = *(const half8*)(&As[buf][(wr + m * 16 + r) * 32 + kc]);
#pragma unroll
        for (int n = 0; n < 4; ++n)
            bf[n] = *(const half8*)(&Bs[buf][(wc + n * 16 + r) * 32 + kc]);
#pragma unroll
        for (int m = 0; m < 4; ++m)
#pragma unroll
            for (int n = 0; n < 4; ++n)
                acc[m][n] = __builtin_amdgcn_mfma_f32_16x16x32_f16(af[m], bf[n], acc[m][n], 0, 0, 0);
        if (++buf >= 3) buf = 0;
    }

    // epilogue: rope + scatter to Fq/Fk/Fv
    const int C = N / 3;
    const int colbase = bn + wc;           // 64-aligned, within one region
    const int reg = colbase / C;
    const int h = (colbase % C) >> 6;
#pragma unroll
    for (int m = 0; m < 4; ++m) {
        int rbase = bm + wr + m * 16 + ((ln >> 4) << 2);
#pragma unroll
        for (int j = 0; j < 4; ++j) {
            int row = rbase + j;
            if (row >= M) continue;
            int b = row / S, s = row - b * S;
            size_t ob = ((size_t)(b * H + h) * S + s) * 64;
            if (reg == 2) {
#pragma unroll
                for (int n = 0; n < 4; ++n)
                    Fv[ob + n * 16 + (ln & 15)] = (f16)acc[m][n][j];
            } else {
                const float* tb = tab + ((size_t)s << 6);
#pragma unroll
                for (int p = 0; p < 2; ++p) {
                    int i = p * 16 + (ln & 15);
                    float cs = tb[2 * i], sn = tb[2 * i + 1];
                    float x1 = acc[m][p][j], x2 = acc[m][p + 2][j];
                    float o1 = x1 * cs - x2 * sn;
                    float o2 = x2 * cs + x1 * sn;
                    if (reg == 0) {
                        Fq[ob + i]      = (f16)(o1 * 0.125f);
                        Fq[ob + i + 32] = (f16)(o2 * 0.125f);
                    } else {
                        Fk[ob + i]      = (f16)o1;
                        Fk[ob + i + 32] = (f16)o2;
                    }
                }
            }
        }
    }
}

// ---------------- rope table: tab[s][i][2] = (cos, sin) -------------------
__global__ __launch_bounds__(256) void rope_tab(float* __restrict__ tab, int S) {
    int g = blockIdx.x * 256 + threadIdx.x;
    if (g >= S * 32) return;
    int s = g >> 5, i = g & 31;
    float inv = expf(-(float)i * 0.28782313662425575f);
    float sn, cs;
    sincosf((float)s * inv, &sn, &cs);
    tab[2 * g] = cs;
    tab[2 * g + 1] = sn;
}

// ---------------- split-K reduce ------------------------------------------
template<bool HOUT>
__global__ __launch_bounds__(256) void kred(
    const float* __restrict__ P, const float* __restrict__ res,
    void* __restrict__ Cv, size_t mn, int ks) {
    size_t i = ((size_t)blockIdx.x * 256 + threadIdx.x) * 4;
    if (i >= mn) return;
    floatx4 s = res ? *(const floatx4*)(res + i) : (floatx4)0.f;
    for (int z = 0; z < ks; ++z) {
        floatx4 p = *(const floatx4*)(P + (size_t)z * mn + i);
        s += p;
    }
    if (HOUT) {
        half4v h;
#pragma unroll
        for (int j = 0; j < 4; ++j) h[j] = (f16)s[j];
        *(half4v*)((f16*)Cv + i) = h;
    } else {
        *(floatx4*)((float*)Cv + i) = s;
    }
}

// ---------------- split-K GEMV for M=2 ------------------------------------
__global__ __launch_bounds__(256) void gemv2_part(
    const float* __restrict__ A, const float* __restrict__ W,
    float* __restrict__ P, int N, int K) {
    int n = blockIdx.x * 256 + threadIdx.x;
    if (n >= N) return;
    int Kc = K / KSPL;
    int k0 = blockIdx.y * Kc;
    float acc0 = 0.f, acc1 = 0.f;
    const float* Wp = W + (size_t)k0 * N + n;
    const float* a0 = A + k0;
    const float* a1 = A + K + k0;
#pragma unroll 4
    for (int k = 0; k < Kc; ++k) {
        float w = Wp[(size_t)k * N];
        acc0 = fmaf(a0[k], w, acc0);
        acc1 = fmaf(a1[k], w, acc1);
    }
    P[((size_t)blockIdx.y * 2 + 0) * N + n] = acc0;
    P[((size_t)blockIdx.y * 2 + 1) * N + n] = acc1;
}

__global__ __launch_bounds__(256) void gemv2_red(
    const float* __restrict__ P, const float* __restrict__ res,
    float* __restrict__ C, int N) {
    int g = blockIdx.x * 256 + threadIdx.x;
    if (g >= 2 * N) return;
    int m = g / N, n = g - m * N;
    float s = res ? res[g] : 0.f;
#pragma unroll
    for (int ky = 0; ky < KSPL; ++ky)
        s += P[((size_t)ky * 2 + m) * N + n];
    C[g] = s;
}

// ------- layer-batched M=2 GEMV: W[L][K][Nper], out [L][2][Nper] ----------
__global__ __launch_bounds__(256) void gemv2L_part(
    const float* __restrict__ A, const float* __restrict__ W,
    float* __restrict__ P, int Nper, int L, int K) {
    int tot = L * Nper;
    int c = blockIdx.x * 256 + threadIdx.x;
    if (c >= tot) return;
    int l = c / Nper, n = c - l * Nper;
    int Kc = K / KSPL;
    int k0 = blockIdx.y * Kc;
    const float* Wp = W + (size_t)l * K * Nper + (size_t)k0 * Nper + n;
    const float* a0 = A + k0;
    const float* a1 = A + K + k0;
    float acc0 = 0.f, acc1 = 0.f;
#pragma unroll 4
    for (int k = 0; k < Kc; ++k) {
        float w = Wp[(size_t)k * Nper];
        acc0 = fmaf(a0[k], w, acc0);
        acc1 = fmaf(a1[k], w, acc1);
    }
    P[((size_t)blockIdx.y * 2 + 0) * tot + c] = acc0;
    P[((size_t)blockIdx.y * 2 + 1) * tot + c] = acc1;
}

__global__ __launch_bounds__(256) void gemv2L_red(
    const float* __restrict__ P, float* __restrict__ C, int Nper, int L) {
    int tot = L * Nper;
    int g = blockIdx.x * 256 + threadIdx.x;
    if (g >= 2 * tot) return;
    int m = g / tot, cc = g - m * tot;
    float s = 0.f;
#pragma unroll
    for (int ky = 0; ky < KSPL; ++ky)
        s += P[((size_t)ky * 2 + m) * tot + cc];
    int l = cc / Nper, n = cc - l * Nper;
    C[((size_t)l * 2 + m) * Nper + n] = s;
}

// ---------------- norms ----------------
__device__ __forceinline__ void stf(float* p, float v) { *p = v; }
__device__ __forceinline__ void stf(f16* p, float v)   { *p = (f16)v; }

template<typename TO>
__global__ __launch_bounds__(256) void rmsnorm_k(
    const float* __restrict__ X, const float* __restrict__ scale,
    TO* __restrict__ Y, int C, int rows_per_group, float sadd) {
    int row = blockIdx.x, tid = threadIdx.x;
    const float* x = X + (size_t)row * C;
    float v[8];
    int cnt = C >> 8;
    float ss = 0.f;
    for (int i = 0; i < cnt; ++i) { v[i] = x[tid + (i << 8)]; ss += v[i] * v[i]; }
    __shared__ float red[256];
    red[tid] = ss; __syncthreads();
    for (int s2 = 128; s2; s2 >>= 1) { if (tid < s2) red[tid] += red[tid + s2]; __syncthreads(); }
    float inv = rsqrtf(red[0] / (float)C + 1e-6f);
    const float* sc = scale + (size_t)(row / rows_per_group) * C;
    TO* y = Y + (size_t)row * C;
    for (int i = 0; i < cnt; ++i) {
        int c = tid + (i << 8);
        stf(&y[c], v[i] * (sadd + sc[c]) * inv);
    }
}

__global__ __launch_bounds__(256) void layernorm_k(
    const float* __restrict__ X, const float* __restrict__ g,
    const float* __restrict__ bta, f16* __restrict__ Y, int C) {
    int row = blockIdx.x, tid = threadIdx.x;
    const float* x = X + (size_t)row * C;
    float v[8];
    int cnt = C >> 8;
    float s = 0.f;
    for (int i = 0; i < cnt; ++i) { v[i] = x[tid + (i << 8)]; s += v[i]; }
    __shared__ float red[256];
    red[tid] = s; __syncthreads();
    for (int s2 = 128; s2; s2 >>= 1) { if (tid < s2) red[tid] += red[tid + s2]; __syncthreads(); }
    float m = red[0] / (float)C;
    __syncthreads();
    float s2s = 0.f;
    for (int i = 0; i < cnt; ++i) { float d = v[i] - m; s2s += d * d; }
    red[tid] = s2s; __syncthreads();
    for (int s2 = 128; s2; s2 >>= 1) { if (tid < s2) red[tid] += red[tid + s2]; __syncthreads(); }
    float inv = rsqrtf(red[0] / (float)C + 1e-5f);
    f16* y = Y + (size_t)row * C;
    for (int i = 0; i < cnt; ++i) {
        int c = tid + (i << 8);
        y[c] = (f16)((v[i] - m) * inv * g[c] + bta[c]);
    }
}

// ---------------- GLU ----------------
__global__ __launch_bounds__(256) void glu_k(
    const float* __restrict__ U, float* __restrict__ Yo,
    size_t total, int F, int mode) {
    size_t gidx = (size_t)blockIdx.x * 256 + threadIdx.x;
    if (gidx >= total) return;
    size_t r = gidx / (size_t)F;
    int c = (int)(gidx - r * F);
    const float* u = U + r * (size_t)(2 * F);
    float a = u[c], gg = u[F + c];
    float act = (mode == 0) ? gelu_tanh(gg) : gg / (1.f + expf(-gg));
    Yo[gidx] = a * act;
}

__global__ __launch_bounds__(256) void glu_h8(
    const f16* __restrict__ U, f16* __restrict__ Yo,
    size_t total8, int F8, int mode) {
    size_t gi = (size_t)blockIdx.x * 256 + threadIdx.x;
    if (gi >= total8) return;
    size_t r = gi / (size_t)F8;
    int c = (int)(gi - r * (size_t)F8);
    const f16* u = U + r * (size_t)F8 * 16;
    half8 av = *(const half8*)(u + c * 8);
    half8 gv = *(const half8*)(u + F8 * 8 + c * 8);
    half8 y;
#pragma unroll
    for (int j = 0; j < 8; ++j) {
        float a = (float)av[j], gg = (float)gv[j];
        float act = (mode == 0) ? gelu_tanh(gg) : gg / (1.f + __expf(-gg));
        y[j] = (f16)(a * act);
    }
    *(half8*)(Yo + gi * 8) = y;
}

// ---------------- V transpose: V[bh][S][64] -> Vt[bh][64][Spad] -----------
__global__ __launch_bounds__(256) void vtrans(
    const f16* __restrict__ V, f16* __restrict__ Vt, int S, int Spad) {
    __shared__ f16 T[64][72];
    const int tid = threadIdx.x;
    const int k0 = blockIdx.x * 64;
    const f16* Vb = V + (size_t)blockIdx.y * S * 64;
    f16* Vtb = Vt + (size_t)blockIdx.y * 64 * Spad;
    for (int c = tid; c < 512; c += 256) {
        int kk = c >> 3, d8 = (c & 7) * 8;
        int kg = k0 + kk; kg = kg < S ? kg : S - 1;
        half8 v = *(const half8*)(Vb + (size_t)kg * 64 + d8);
        if (k0 + kk >= S) {
#pragma unroll
            for (int j = 0; j < 8; ++j) v[j] = (f16)0.f;
        }
        *(half8*)(&T[kk][d8]) = v;
    }
    __syncthreads();
    for (int c = tid; c < 512; c += 256) {
        int d = c >> 3, k8 = (c & 7) * 8;
        half8 o;
#pragma unroll
        for (int j = 0; j < 8; ++j) o[j] = T[k8 + j][d];
        *(half8*)(Vtb + (size_t)d * Spad + k0 + k8) = o;
    }
}

// ---------------- split-KV flash attention --------------------------------
__global__ __launch_bounds__(256) void fattn(
    const f16* __restrict__ Q, const f16* __restrict__ K,
    const f16* __restrict__ Vt, float* __restrict__ Op,
    float* __restrict__ Mst, float* __restrict__ Lst,
    int S, int Spad, int H, int win, int QR) {
    __shared__ __align__(16) f16 Ks[64][72];
    __shared__ __align__(16) f16 Vs[64][72];
    __shared__ __align__(16) f16 Ps[4][32][72];
    const int tid = threadIdx.x;
    const int wv = tid >> 6, ln = tid & 63;
    const int r15 = ln & 15, g = ln >> 4;
    const int bh = blockIdx.y;
    const int NBH = gridDim.y;
    const int z = blockIdx.z, nz = gridDim.z;
    const int q0 = (int)blockIdx.x * 128;
    const f16* Qb = Q + (size_t)bh * S * 64;
    const f16* Kb = K + (size_t)bh * S * 64;
    const f16* Vtb = Vt + (size_t)bh * 64 * Spad;

    half8 aq[2][2];
#pragma unroll
    for (int m = 0; m < 2; ++m) {
        int q = q0 + wv * 32 + m * 16 + r15;
        q = q < S ? q : S - 1;
#pragma unroll
        for (int ks = 0; ks < 2; ++ks)
            aq[m][ks] = *(const half8*)(Qb + (size_t)q * 64 + ks * 32 + g * 8);
    }
    floatx4 o[2][4];
#pragma unroll
    for (int m = 0; m < 2; ++m)
#pragma unroll
        for (int n = 0; n < 4; ++n) o[m][n] = (floatx4)0.f;
    float mst[2][4], lst[2][4];
#pragma unroll
    for (int m = 0; m < 2; ++m)
#pragma unroll
        for (int j = 0; j < 4; ++j) { mst[m][j] = -3.0e38f; lst[m][j] = 0.f; }

    int klo = 0, khi = S;
    if (win) {
        int n = (int)blockIdx.x;
        klo = (n - 1) * win; if (klo < 0) klo = 0;
        khi = (n + 2) * win; if (khi > S) khi = S;
    }
    int ntile = (khi - klo + 63) >> 6;
    int chunk = (ntile + nz - 1) / nz;
    int myLo = klo + z * chunk * 64;
    int myHi = klo + (z + 1) * chunk * 64; if (myHi > khi) myHi = khi;

    for (int kb = myLo; kb < myHi; kb += 64) {
        __syncthreads();
#pragma unroll
        for (int i = 0; i < 2; ++i) {
            int c = tid + i * 256;
            int rr = c >> 3, c8 = (c & 7) * 8;
            int kg = kb + rr; kg = kg < S ? kg : S - 1;
            *(half8*)(&Ks[rr][c8]) = *(const half8*)(Kb + (size_t)kg * 64 + c8);
            *(half8*)(&Vs[rr][c8]) = *(const half8*)(Vtb + (size_t)rr * Spad + kb + c8);
        }
        __syncthreads();
        floatx4 s[2][4];
#pragma unroll
        for (int m = 0; m < 2; ++m)
#pragma unroll
            for (int n = 0; n < 4; ++n) s[m][n] = (floatx4)0.f;
#pragma unroll
        for (int ks = 0; ks < 2; ++ks) {
            half8 bk[4];
#pragma unroll
            for (int n = 0; n < 4; ++n)
                bk[n] = *(const half8*)(&Ks[n * 16 + r15][ks * 32 + g * 8]);
#pragma unroll
            for (int m = 0; m < 2; ++m)
#pragma unroll
                for (int n = 0; n < 4; ++n)
                    s[m][n] = __builtin_amdgcn_mfma_f32_16x16x32_f16(aq[m][ks], bk[n], s[m][n], 0, 0, 0);
        }
        if (kb + 64 > S) {
#pragma unroll
            for (int n = 0; n < 4; ++n)
                if (kb + n * 16 + r15 >= S) {
#pragma unroll
                    for (int m = 0; m < 2; ++m) s[m][n] = (floatx4)(-3.0e38f);
                }
        }
#pragma unroll
        for (int m = 0; m < 2; ++m) {
#pragma unroll
            for (int j = 0; j < 4; ++j) {
                float tm = fmaxf(fmaxf(s[m][0][j], s[m][1][j]), fmaxf(s[m][2][j], s[m][3][j]));
                tm = fmaxf(tm, __shfl_xor(tm, 1));
                tm = fmaxf(tm, __shfl_xor(tm, 2));
                tm = fmaxf(tm, __shfl_xor(tm, 4));
                tm = fmaxf(tm, __shfl_xor(tm, 8));
                float mn = fmaxf(mst[m][j], tm);
                float sc = __expf(mst[m][j] - mn);
                mst[m][j] = mn;
                float ts = 0.f;
#pragma unroll
                for (int n = 0; n < 4; ++n) {
                    float p = __expf(s[m][n][j] - mn);
                    s[m][n][j] = p;
                    ts += p;
                }
                ts += __shfl_xor(ts, 1);
                ts += __shfl_xor(ts, 2);
                ts += __shfl_xor(ts, 4);
                ts += __shfl_xor(ts, 8);
                lst[m][j] = lst[m][j] * sc + ts;
#pragma unroll
                for (int n = 0; n < 4; ++n) o[m][n][j] *= sc;
            }
        }
#pragma unroll
        for (int m = 0; m < 2; ++m)
#pragma unroll
            for (int n = 0; n < 4; ++n)
#pragma unroll
                for (int j = 0; j < 4; ++j)
                    Ps[wv][m * 16 + g * 4 + j][n * 16 + r15] = (f16)s[m][n][j];
#pragma unroll
        for (int ks = 0; ks < 2; ++ks) {
            half8 pa[2], bv[4];
#pragma unroll
            for (int m = 0; m < 2; ++m)
                pa[m] = *(const half8*)(&Ps[wv][m * 16 + r15][ks * 32 + g * 8]);
#pragma unroll
            for (int n = 0; n < 4; ++n)
                bv[n] = *(const half8*)(&Vs[n * 16 + r15][ks * 32 + g * 8]);
#pragma unroll
            for (int m = 0; m < 2; ++m)
#pragma unroll
                for (int n = 0; n < 4; ++n)
                    o[m][n] = __builtin_amdgcn_mfma_f32_16x16x32_f16(pa[m], bv[n], o[m][n], 0, 0, 0);
        }
    }
    size_t zb = ((size_t)z * NBH + bh) * QR;
#pragma unroll
    for (int m = 0; m < 2; ++m)
#pragma unroll
        for (int j = 0; j < 4; ++j) {
            int qr = q0 + wv * 32 + m * 16 + g * 4 + j;
            size_t ro = (zb + qr) * 64;
#pragma unroll
            for (int n = 0; n < 4; ++n)
                Op[ro + n * 16 + r15] = o[m][n][j];
            if (r15 == 0) {
                Mst[zb + qr] = mst[m][j];
                Lst[zb + qr] = lst[m][j];
            }
        }
}

// ---------------- flash combine -------------------------------------------
__global__ __launch_bounds__(256) void fcomb(
    const float* __restrict__ Op, const float* __restrict__ Mst,
    const float* __restrict__ Lst, f16* __restrict__ O,
    int S, int H, int QR, int nz, int rows) {
    int g = blockIdx.x * 256 + threadIdx.x;
    int idx = g >> 4;
    int d4 = (g & 15) * 4;
    if (idx >= rows) return;
    int bh = idx / QR, q = idx - bh * QR;
    if (q >= S) return;
    float mstar = -3.0e38f;
    for (int z = 0; z < nz; ++z)
        mstar = fmaxf(mstar, Mst[(size_t)z * rows + idx]);
    float den = 0.f;
    floatx4 num = (floatx4)0.f;
    for (int z = 0; z < nz; ++z) {
        float w = __expf(Mst[(size_t)z * rows + idx] - mstar);
        den += w * Lst[(size_t)z * rows + idx];
        floatx4 ov = *(const floatx4*)(Op + ((size_t)z * rows + idx) * 64 + d4);
        num += w * ov;
    }
    float inv = 1.f / den;
    int b = bh / H, h = bh % H;
    f16* op = O + ((size_t)b * S + q) * (H * 64) + h * 64 + d4;
    half4v hv;
#pragma unroll
    for (int j = 0; j < 4; ++j) hv[j] = (f16)(num[j] * inv);
    *(half4v*)op = hv;
}

// ---------------- small glue kernels ----------------
__global__ __launch_bounds__(256) void patch_in_gather(
    const float* __restrict__ x, f16* __restrict__ out) {
    int g = blockIdx.x * 256 + threadIdx.x;
    if (g >= BB * S0 * 128) return;
    int k = g & 127;
    int n = (g >> 7) & (S0 - 1);
    int b = g >> 18;
    out[g] = (f16)x[(size_t)b * CIO * TT + (size_t)(k >> 1) * TT + 2 * n + (k & 1)];
}

__global__ __launch_bounds__(256) void time_embed(
    const float* __restrict__ t, const float* __restrict__ tw,
    float* __restrict__ te) {
    int g = blockIdx.x * 256 + threadIdx.x;
    if (g >= BB * MAPD) return;
    int b = g / MAPD, j = g % MAPD;
    float w = tw[(j < 512) ? j : j - 512];
    float ang = 6.283185307179586f * t[b] * w;
    te[g] = (j < 512) ? cosf(ang) : sinf(ang);
}

__global__ __launch_bounds__(256) void token_merge_gather(
    const float* __restrict__ A, f16* __restrict__ out) {
    int g = blockIdx.x * 256 + threadIdx.x;
    if (g >= BB * 1024 * 1024) return;
    int k = g & 1023;
    int n = (g >> 10) & 1023;
    int b = g >> 20;
    out[g] = (f16)A[((size_t)b * S0 + 2 * n + (k & 1)) * W0 + (k >> 1)];
}

__global__ __launch_bounds__(256) void concat_mid(
    const float* __restrict__ pre, const float* __restrict__ Dsrc,
    float* __restrict__ Cm) {
    int g = blockIdx.x * 256 + threadIdx.x;
    if (g >= BB * SM * W1) return;
    int c = g & 1023;
    int row = g >> 10;
    int b = row / SM, r = row % SM;
    Cm[g] = (r == 0) ? pre[b * W1 + c]
                     : Dsrc[((size_t)b * 1024 + r - 1) * W1 + c];
}

__global__ __launch_bounds__(256) void gather_drop(
    const f16* __restrict__ Dsrc, f16* __restrict__ out) {
    int g = blockIdx.x * 256 + threadIdx.x;
    if (g >= BB * 1024 * W1) return;
    int c = g & 1023;
    int n = (g >> 10) & 1023;
    int b = g >> 20;
    out[g] = Dsrc[((size_t)b * SM + 1 + n) * W1 + c];
}

__global__ __launch_bounds__(256) void split_scatter_lerp(
    const float* __restrict__ y, const float* __restrict__ skip,
    const float* __restrict__ fac, float* __restrict__ xo) {
    int g = blockIdx.x * 256 + threadIdx.x;
    if (g >= BB * S0 * W0) return;
    int c = g & 511;
    int tk = (g >> 9) & (S0 - 1);
    int b = g >> 20;
    float yv = y[((size_t)b * 1024 + (tk >> 1)) * W1 + (c * 2 + (tk & 1))];
    float sk = skip[g];
    xo[g] = sk + fac[0] * (yv - sk);
}

__global__ __launch_bounds__(256) void patch_out_scatter(
    const float* __restrict__ y, float* __restrict__ out) {
    int g = blockIdx.x * 256 + threadIdx.x;
    if (g >= BB * CIO * TT) return;
    int tk = g & (TT - 1);
    int c = (g >> 12) & 63;
    int b = g >> 18;
    out[g] = y[((size_t)b * S0 + (tk >> 1)) * 128 + (c * 2 + (tk & 1))];
}

// ---------------- host orchestration ----------------
extern "C" void kernel_launch(void* const* d_in, const int* in_sizes, int n_in,
                              void* d_out, int out_size, void* d_ws, size_t ws_size,
                              hipStream_t stream) {
    const float* x          = (const float*)d_in[0];
    const float* t          = (const float*)d_in[1];
    const float* time_w     = (const float*)d_in[2];
    const float* time_in_w  = (const float*)d_in[3];
    const float* map_in_s   = (const float*)d_in[4];
    const float* map_norm_s = (const float*)d_in[5];
    const float* map_up_w   = (const float*)d_in[6];
    const float* map_down_w = (const float*)d_in[7];
    const float* map_out_s  = (const float*)d_in[8];
    const float* patch_in_w = (const float*)d_in[9];
    const float* dn_anorm_w = (const float*)d_in[10];
    const float* dn_qkv_w   = (const float*)d_in[11];
    const float* dn_o_w     = (const float*)d_in[12];
    const float* dn_fnorm_w = (const float*)d_in[13];
    const float* dn_ff1_w   = (const float*)d_in[14];
    const float* dn_ff2_w   = (const float*)d_in[15];
    const float* merge_w    = (const float*)d_in[16];
    const float* mid_map_w  = (const float*)d_in[17];
    const float* mid_pin_w  = (const float*)d_in[18];
    const float* mid_pout_w = (const float*)d_in[19];
    const float* mid_ln1_g  = (const float*)d_in[20];
    const float* mid_ln1_b  = (const float*)d_in[21];
    const float* mid_qkv_w  = (const float*)d_in[22];
    const float* mid_o_w    = (const float*)d_in[23];
    const float* mid_ln2_g  = (const float*)d_in[24];
    const float* mid_ln2_b  = (const float*)d_in[25];
    const float* mid_ff1_w  = (const float*)d_in[26];
    const float* mid_ff2_w  = (const float*)d_in[27];
    const float* mid_fn_g   = (const float*)d_in[28];
    const float* mid_fn_b   = (const float*)d_in[29];
    const float* split_w    = (const float*)d_in[30];
    const float* split_fac  = (const float*)d_in[31];
    const float* up_anorm_w = (const float*)d_in[32];
    const float* up_qkv_w   = (const float*)d_in[33];
    const float* up_o_w     = (const float*)d_in[34];
    const float* up_fnorm_w = (const float*)d_in[35];
    const float* up_ff1_w   = (const float*)d_in[36];
    const float* up_ff2_w   = (const float*)d_in[37];
    const float* out_norm_s = (const float*)d_in[38];
    const float* patch_out_w= (const float*)d_in[39];

    float* Wp = (float*)d_ws;
    size_t off = 0;
    auto alloc = [&](size_t n) { float* p = Wp + off; off += n; return p; };
    float* A    = alloc((size_t)4096 * 512);
    float* Bsk  = alloc((size_t)4096 * 512);
    float* Cm   = alloc((size_t)2050 * 1024);
    float* Df   = alloc((size_t)2050 * 1024);
    f16*  Fq    = (f16*)alloc((size_t)1049600);
    f16*  Fk    = (f16*)alloc((size_t)1049600);
    f16*  Fv    = (f16*)alloc((size_t)1049600);
    f16*  Fvt   = (f16*)alloc((size_t)1114112);
    f16*  H1    = (f16*)alloc((size_t)8396800);
    f16*  H2    = (f16*)alloc((size_t)4198400);
    f16*  Wh    = (f16*)alloc((size_t)4194304);
    float* Pk   = alloc((size_t)PKCAP);
    float* ML   = alloc((size_t)262144);
    float* Pb   = alloc((size_t)KSPL * 2 * 2048);
    float* tabL = alloc((size_t)S0 * 64);
    float* tabM = alloc((size_t)SM * 64);
    float* Sma  = alloc((size_t)32768);
    (void)ws_size; (void)in_sizes; (void)n_in; (void)out_size;

    float* te   = Sma;
    float* temb = Sma + 2048;
    float* mapx = Sma + 4096;
    float* maph = Sma + 6144;
    float* mapu = Sma + 8192;
    float* mapg = Sma + 12288;
    float* cond = Sma + 14336;
    float* pre  = Sma + 18432;
    float* sAdn = Sma + 20480;   // [2][2][512]
    float* sFdn = Sma + 22528;
    float* sAup = Sma + 24576;
    float* sFup = Sma + 26624;

    auto WC = [&](const float* W, int K, int N) {
        wcast<<<dim3(N / 64, K / 64), 256, 0, stream>>>(W, Wh, K, N);
    };
    auto pick_ks = [](int M, int N, int K) {
        long gx = N / 128, gy = (M + 127) / 128;
        int ks = 1;
        while (gx * gy * ks < 512 && ks < 8) {
            int nk = ks * 2;
            if ((K / nk) % 32 != 0 || (long)M * N * nk > PKCAP) break;
            ks = nk;
        }
        return ks;
    };
    auto GF = [&](const f16* Aa, const float* res, float* C, int M, int N, int K) {
        int ks = pick_ks(M, N, K);
        dim3 g(N / 128, (M + 127) / 128, ks);
        if (ks == 1) {
            gemm_h<0><<<g, 256, 0, stream>>>(Aa, Wh, res, C, M, N, K);
        } else {
            gemm_h<2><<<g, 256, 0, stream>>>(Aa, Wh, nullptr, Pk, M, N, K);
            size_t mn = (size_t)M * N;
            kred<false><<<(int)((mn / 4 + 255) / 256), 256, 0, stream>>>(Pk, res, C, mn, ks);
        }
    };
    auto GH = [&](const f16* Aa, f16* C, int M, int N, int K) {
        int ks = pick_ks(M, N, K);
        dim3 g(N / 128, (M + 127) / 128, ks);
        if (ks == 1) {
            gemm_h<1><<<g, 256, 0, stream>>>(Aa, Wh, nullptr, C, M, N, K);
        } else {
            gemm_h<2><<<g, 256, 0, stream>>>(Aa, Wh, nullptr, Pk, M, N, K);
            size_t mn = (size_t)M * N;
            kred<true><<<(int)((mn / 4 + 255) / 256), 256, 0, stream>>>(Pk, nullptr, C, mn, ks);
        }
    };
    auto GQKV = [&](const f16* Aa, const float* tab, int M, int N, int K, int S, int H) {
        dim3 g(N / 128, (M + 127) / 128);
        gemm_qkv<<<g, 256, 0, stream>>>(Aa, Wh, tab, Fq, Fk, Fv, M, N, K, S, H);
    };
    auto gemv2 = [&](const float* Aa, const float* W, const float* res,
                     float* C, int N, int K) {
        gemv2_part<<<dim3((N + 255) / 256, KSPL), 256, 0, stream>>>(Aa, W, Pb, N, K);
        gemv2_red<<<(2 * N + 255) / 256, 256, 0, stream>>>(Pb, res, C, N);
    };
    auto gemv2L = [&](const float* Aa, const float* W, float* C, int Nper, int L, int K) {
        int tot = L * Nper;
        gemv2L_part<<<dim3((tot + 255) / 256, KSPL), 256, 0, stream>>>(Aa, W, Pb, Nper, L, K);
        gemv2L_red<<<(2 * tot + 255) / 256, 256, 0, stream>>>(Pb, C, Nper, L);
    };
    auto FATT = [&](const f16* Qp, const f16* Kp, const f16* Vtp, f16* Out,
                    int S, int Spad, int H, int win, int nq, int nbh, int nz) {
        int QR = nq * 128;
        int rows = nbh * QR;
        fattn<<<dim3(nq, nbh, nz), 256, 0, stream>>>(
            Qp, Kp, Vtp, Pk, ML, ML + (size_t)nz * rows, S, Spad, H, win, QR);
        fcomb<<<(rows * 16 + 255) / 256, 256, 0, stream>>>(
            Pk, ML, ML + (size_t)nz * rows, Out, S, H, QR, nz, rows);
    };

    // ---- rope tables (once) ----
    rope_tab<<<(S0 * 32 + 255) / 256, 256, 0, stream>>>(tabL, S0);
    rope_tab<<<(SM * 32 + 255) / 256, 256, 0, stream>>>(tabM, SM);

    // ---- patch in ----
    patch_in_gather<<<(BB * S0 * 128 + 255) / 256, 256, 0, stream>>>(x, H2);
    WC(patch_in_w, 128, 512);
    GF(H2, nullptr, A, 4096, 512, 128);

    // ---- time embedding + mapping (tiny, f32) ----
    time_embed<<<(BB * MAPD + 255) / 256, 256, 0, stream>>>(t, time_w, te);
    gemv2(te, time_in_w, nullptr, temb, 1024, 1024);
    rmsnorm_k<float><<<2, 256, 0, stream>>>(temb, map_in_s, mapx, 1024, 2, 0.f);
    for (int l = 0; l < 2; ++l) {
        rmsnorm_k<float><<<2, 256, 0, stream>>>(mapx, map_norm_s + (size_t)l * 1024, maph, 1024, 2, 0.f);
        gemv2(maph, map_up_w + (size_t)l * 1024 * 2048, nullptr, mapu, 2048, 1024);
        glu_k<<<(2 * 1024 + 255) / 256, 256, 0, stream>>>(mapu, mapg, 2 * 1024, 1024, 0);
        gemv2(mapg, map_down_w + (size_t)l * 1024 * 1024, mapx, mapx, 1024, 1024);
    }
    rmsnorm_k<float><<<2, 256, 0, stream>>>(mapx, map_out_s, cond, 1024, 2, 0.f);

    // ---- all cond projections (batched, once) ----
    gemv2L(cond, dn_anorm_w, sAdn, 512, 2, 1024);
    gemv2L(cond, dn_fnorm_w, sFdn, 512, 2, 1024);
    gemv2L(cond, up_anorm_w, sAup, 512, 2, 1024);
    gemv2L(cond, up_fnorm_w, sFup, 512, 2, 1024);
    gemv2L(cond, mid_map_w,  pre, 1024, 1, 1024);

    // ---- local level (shared for down/up) ----
    auto run_local = [&](const float* qkvw, const float* ow,
                         const float* ff1, const float* ff2,
                         const float* sAall, const float* sFall) {
        for (int l = 0; l < 2; ++l) {
            rmsnorm_k<f16><<<4096, 256, 0, stream>>>(A, sAall + (size_t)l * 1024, H2, 512, 2048, 1.f);
            WC(qkvw + (size_t)l * 512 * 1536, 512, 1536);
            GQKV(H2, tabL, 4096, 1536, 512, S0, HDN);
            vtrans<<<dim3(S0 / 64, BB * HDN), 256, 0, stream>>>(Fv, Fvt, S0, S0);
            FATT(Fq, Fk, Fvt, H2, S0, S0, HDN, WIN, S0 / 128, BB * HDN, 2);
            WC(ow + (size_t)l * 512 * 512, 512, 512);
            GF(H2, A, A, 4096, 512, 512);
            rmsnorm_k<f16><<<4096, 256, 0, stream>>>(A, sFall + (size_t)l * 1024, H2, 512, 2048, 1.f);
            WC(ff1 + (size_t)l * 512 * 2048, 512, 2048);
            GH(H2, H1, 4096, 2048, 512);
            glu_h8<<<(4096 * 128 + 255) / 256, 256, 0, stream>>>(H1, H2, (size_t)4096 * 128, 128, 0);
            WC(ff2 + (size_t)l * 1024 * 512, 1024, 512);
            GF(H2, A, A, 4096, 512, 1024);
        }
    };
    run_local(dn_qkv_w, dn_o_w, dn_ff1_w, dn_ff2_w, sAdn, sFdn);

    // ---- skip save, merge, mid prep ----
    hipMemcpyAsync(Bsk, A, (size_t)4096 * 512 * 4, hipMemcpyDeviceToDevice, stream);
    token_merge_gather<<<(BB * 1024 * 1024 + 255) / 256, 256, 0, stream>>>(A, H2);
    WC(merge_w, 1024, 1024);
    GH(H2, H1, 2048, 1024, 1024);
    WC(mid_pin_w, 1024, 1024);
    GF(H1, nullptr, Df, 2048, 1024, 1024);
    concat_mid<<<(BB * SM * W1 + 255) / 256, 256, 0, stream>>>(pre, Df, Cm);

    // ---- mid level ----
    for (int l = 0; l < 4; ++l) {
        layernorm_k<<<2050, 256, 0, stream>>>(Cm, mid_ln1_g + (size_t)l * 1024,
                                              mid_ln1_b + (size_t)l * 1024, H2, 1024);
        WC(mid_qkv_w + (size_t)l * 1024 * 3072, 1024, 3072);
        GQKV(H2, tabM, 2050, 3072, 1024, SM, HMID);
        vtrans<<<dim3(SMP / 64, BB * HMID), 256, 0, stream>>>(Fv, Fvt, SM, SMP);
        FATT(Fq, Fk, Fvt, H2, SM, SMP, HMID, 0, 9, BB * HMID, 3);
        WC(mid_o_w + (size_t)l * 1024 * 1024, 1024, 1024);
        GF(H2, Cm, Cm, 2050, 1024, 1024);
        layernorm_k<<<2050, 256, 0, stream>>>(Cm, mid_ln2_g + (size_t)l * 1024,
                                              mid_ln2_b + (size_t)l * 1024, H2, 1024);
        WC(mid_ff1_w + (size_t)l * 1024 * 8192, 1024, 8192);
        GH(H2, H1, 2050, 8192, 1024);
        glu_h8<<<(int)(((size_t)2050 * 512 + 255) / 256), 256, 0, stream>>>(H1, H2, (size_t)2050 * 512, 512, 1);
        WC(mid_ff2_w + (size_t)l * 4096 * 1024, 4096, 1024);
        GF(H2, Cm, Cm, 2050, 1024, 4096);
    }
    layernorm_k<<<2050, 256, 0, stream>>>(Cm, mid_fn_g, mid_fn_b, H2, 1024);

    // ---- pout + token split + lerp skip ----
    WC(mid_pout_w, 1024, 1024);
    GH(H2, H1, 2050, 1024, 1024);
    gather_drop<<<(BB * 1024 * W1 + 255) / 256, 256, 0, stream>>>(H1, H2);
    WC(split_w, 1024, 1024);
    GF(H2, nullptr, Df, 2048, 1024, 1024);
    split_scatter_lerp<<<(BB * S0 * W0 + 255) / 256, 256, 0, stream>>>(Df, Bsk, split_fac, A);

    // ---- up level ----
    run_local(up_qkv_w, up_o_w, up_ff1_w, up_ff2_w, sAup, sFup);

    // ---- out ----
    rmsnorm_k<f16><<<4096, 256, 0, stream>>>(A, out_norm_s, H2, 512, 4096, 0.f);
    WC(patch_out_w, 512, 128);
    GF(H2, nullptr, Df, 4096, 128, 512);
    patch_out_scatter<<<(BB * CIO * TT + 255) / 256, 256, 0, stream>>>(Df, (float*)d_out);
}

// Round 9
// 1984.536 us; speedup vs baseline: 9.4392x; 1.0586x over previous
//
#include <hip/hip_runtime.h>
#include <math.h>

// ---------------- constants ----------------
#define BB   2
#define CIO  64
#define TT   4096
#define S0   2048      // local level seq len
#define W0   512
#define HDN  8
#define SM   1025      // mid seq len (with prepended token)
#define SMP  1088      // padded mid seq (17*64)
#define W1   1024
#define HMID 16
#define WIN  128
#define NW   16        // S0 / WIN
#define MAPD 1024
#define KSPL 16        // split-K factor for M=2 GEMV
#define PKCAP 8396800L // partial buffer capacity (floats)

typedef _Float16 f16;
typedef _Float16 half8 __attribute__((ext_vector_type(8)));
typedef _Float16 half4v __attribute__((ext_vector_type(4)));
typedef _Float16 half2v __attribute__((ext_vector_type(2)));
typedef float floatx4 __attribute__((ext_vector_type(4)));

// ---------------- device helpers ----------------
__device__ __forceinline__ float gelu_tanh(float x) {
    float x3 = x * x * x;
    return 0.5f * x * (1.f + tanhf(0.7978845608028654f * (x + 0.044715f * x3)));
}

// ---------------- weight transpose-cast: W[K][N] f32 -> Wt[N][K] f16 ------
__global__ __launch_bounds__(256) void wcast(
    const float* __restrict__ W, f16* __restrict__ Wt, int K, int N) {
    __shared__ float T[64][65];
    const int n0 = blockIdx.x * 64, k0 = blockIdx.y * 64;
    const int tid = threadIdx.x;
    for (int e = tid; e < 4096; e += 256) {
        int r = e >> 6, c = e & 63;
        T[r][c] = W[(size_t)(k0 + r) * N + n0 + c];
    }
    __syncthreads();
    for (int e = tid; e < 2048; e += 256) {
        int r = e >> 5, c2 = (e & 31) * 2;
        half2v p;
        p[0] = (f16)T[c2][r];
        p[1] = (f16)T[c2 + 1][r];
        *(half2v*)(Wt + (size_t)(n0 + r) * K + k0 + c2) = p;
    }
}

// ---- GLU-reordered transpose-cast: W[K][2F] f32 -> Wt[2F][K] f16 ---------
// Out-row r: p=r>>5, i=r&31; src col = (i<16) ? p*16+i : F + p*16 + (i-16).
// Then GEMM cols pair (a at n even, g at n odd) within each thread.
__global__ __launch_bounds__(256) void wcast_glu(
    const float* __restrict__ W, f16* __restrict__ Wt, int K, int F2) {
    __shared__ float T[64][65];
    const int F = F2 >> 1;
    const int n0 = blockIdx.x * 64, k0 = blockIdx.y * 64;
    const int tid = threadIdx.x;
    // T cols 0..31 <- a-cols [n0/2, n0/2+32); cols 32..63 <- g-cols [F+n0/2, ...)
    for (int e = tid; e < 4096; e += 256) {
        int r = e >> 6, c = e & 63;
        int oc = (c < 32) ? (n0 / 2 + c) : (F + n0 / 2 + (c - 32));
        T[r][c] = W[(size_t)(k0 + r) * F2 + oc];
    }
    __syncthreads();
    for (int e = tid; e < 2048; e += 256) {
        int rr = e >> 5, c2 = (e & 31) * 2;
        int pl = rr >> 5, i = rr & 31;
        int tc = (i < 16) ? (pl * 16 + i) : (32 + pl * 16 + (i - 16));
        half2v p;
        p[0] = (f16)T[c2][tc];
        p[1] = (f16)T[c2 + 1][tc];
        *(half2v*)(Wt + (size_t)(n0 + rr) * K + k0 + c2) = p;
    }
}

// ---------------- MFMA GEMM: C = (res?) + A[MxK]f16 @ Bt[NxK]f16^T --------
// OUTM: 0 = f32 out (+res), 1 = f16 out, 2 = split-K f32 partial (grid.z),
//       3 = fused GLU f16 out (N=2F reordered weights, writes N/2 cols)
template<int OUTM>
__global__ __launch_bounds__(256) void gemm_h(
    const f16* __restrict__ A, const f16* __restrict__ Bt,
    const float* __restrict__ res, void* __restrict__ Cv,
    int M, int N, int K, int glumode) {
    __shared__ __align__(16) f16 As[3][4096];
    __shared__ __align__(16) f16 Bs[3][4096];
    const int tid = threadIdx.x;
    const int wv = tid >> 6, ln = tid & 63;
    int nwg = gridDim.x * gridDim.y;
    int orig = blockIdx.y * gridDim.x + blockIdx.x;
    int wg = orig;
    if (nwg >= 16) {
        int q = nwg >> 3, r = nwg & 7;
        int xcd = orig & 7, lot = orig >> 3;
        wg = (xcd < r ? xcd * (q + 1) : r * (q + 1) + (xcd - r) * q) + lot;
    }
    const int bm = (wg / gridDim.x) * 128, bn = (wg % gridDim.x) * 128;
    int Kc = K, kbase = 0;
    if (OUTM == 2) { Kc = K / gridDim.z; kbase = blockIdx.z * Kc; }
    const int nt = Kc >> 5;

    auto stage = [&](int buf, int kt) {
        int k0 = kbase + (kt << 5);
#pragma unroll
        for (int i = 0; i < 2; ++i) {
            int off = i * 4096 + wv * 1024 + ln * 16;
            int row = off >> 6, kb = (off & 63) >> 1;
            int gr = bm + row; gr = gr < M ? gr : M - 1;
            f16* gp = const_cast<f16*>(A) + (size_t)gr * K + k0 + kb;
            __builtin_amdgcn_global_load_lds(
                (__attribute__((address_space(1))) void*)gp,
                (__attribute__((address_space(3))) void*)(&As[buf][i * 2048 + wv * 512]),
                16, 0, 0);
            f16* gq = const_cast<f16*>(Bt) + (size_t)(bn + row) * K + k0 + kb;
            __builtin_amdgcn_global_load_lds(
                (__attribute__((address_space(1))) void*)gq,
                (__attribute__((address_space(3))) void*)(&Bs[buf][i * 2048 + wv * 512]),
                16, 0, 0);
        }
    };

    floatx4 acc[4][4];
#pragma unroll
    for (int m = 0; m < 4; ++m)
#pragma unroll
        for (int n = 0; n < 4; ++n) acc[m][n] = (floatx4)0.f;
    const int r = ln & 15, kc = (ln >> 4) * 8;
    const int wr = (wv >> 1) * 64, wc = (wv & 1) * 64;

    stage(0, 0);
    if (nt > 1) stage(1, 1);
    int buf = 0;
    for (int t = 0; t < nt; ++t) {
        if (t + 1 < nt) { asm volatile("s_waitcnt vmcnt(4)" ::: "memory"); }
        else            { asm volatile("s_waitcnt vmcnt(0)" ::: "memory"); }
        __builtin_amdgcn_s_barrier();
        if (t + 2 < nt) {
            int nb = buf + 2; if (nb >= 3) nb -= 3;
            stage(nb, t + 2);
        }
        half8 af[4], bf[4];
#pragma unroll
        for (int m = 0; m < 4; ++m)
            af[m] = *(const half8*)(&As[buf][(wr + m * 16 + r) * 32 + kc]);
#pragma unroll
        for (int n = 0; n < 4; ++n)
            bf[n] = *(const half8*)(&Bs[buf][(wc + n * 16 + r) * 32 + kc]);
#pragma unroll
        for (int m = 0; m < 4; ++m)
#pragma unroll
            for (int n = 0; n < 4; ++n)
                acc[m][n] = __builtin_amdgcn_mfma_f32_16x16x32_f16(af[m], bf[n], acc[m][n], 0, 0, 0);
        if (++buf >= 3) buf = 0;
    }

    float* Cf = (float*)Cv;
    f16*   Ch = (f16*)Cv;
    if (OUTM == 2) Cf += (size_t)blockIdx.z * M * N;
    const int base2 = (bn + wc) >> 1;
#pragma unroll
    for (int m = 0; m < 4; ++m) {
        int rbase = bm + wr + m * 16 + ((ln >> 4) << 2);
#pragma unroll
        for (int j = 0; j < 4; ++j) {
            int row = rbase + j;
            if (row < M) {
                if (OUTM == 3) {
                    size_t ro = (size_t)row * (N >> 1);
#pragma unroll
                    for (int k = 0; k < 2; ++k) {
                        float a = acc[m][2 * k][j], gg = acc[m][2 * k + 1][j];
                        float act = (glumode == 0) ? gelu_tanh(gg)
                                                   : gg / (1.f + __expf(-gg));
                        Ch[ro + base2 + k * 16 + (ln & 15)] = (f16)(a * act);
                    }
                } else {
                    size_t ro = (size_t)row * N;
#pragma unroll
                    for (int n = 0; n < 4; ++n) {
                        int col = bn + wc + n * 16 + (ln & 15);
                        float v = acc[m][n][j];
                        if (OUTM == 1) Ch[ro + col] = (f16)v;
                        else if (OUTM == 0) Cf[ro + col] = v + (res ? res[ro + col] : 0.f);
                        else Cf[ro + col] = v;
                    }
                }
            }
        }
    }
}

// ---------------- QKV GEMM with fused rope+split epilogue -----------------
__global__ __launch_bounds__(256) void gemm_qkv(
    const f16* __restrict__ A, const f16* __restrict__ Bt,
    const float* __restrict__ tab, f16* __restrict__ Fq,
    f16* __restrict__ Fk, f16* __restrict__ Fv,
    int M, int N, int K, int S, int H) {
    __shared__ __align__(16) f16 As[3][4096];
    __shared__ __align__(16) f16 Bs[3][4096];
    const int tid = threadIdx.x;
    const int wv = tid >> 6, ln = tid & 63;
    int nwg = gridDim.x * gridDim.y;
    int orig = blockIdx.y * gridDim.x + blockIdx.x;
    int wg = orig;
    if (nwg >= 16) {
        int q = nwg >> 3, r = nwg & 7;
        int xcd = orig & 7, lot = orig >> 3;
        wg = (xcd < r ? xcd * (q + 1) : r * (q + 1) + (xcd - r) * q) + lot;
    }
    const int bm = (wg / gridDim.x) * 128, bn = (wg % gridDim.x) * 128;
    const int nt = K >> 5;

    auto stage = [&](int buf, int kt) {
        int k0 = kt << 5;
#pragma unroll
        for (int i = 0; i < 2; ++i) {
            int off = i * 4096 + wv * 1024 + ln * 16;
            int row = off >> 6, kb = (off & 63) >> 1;
            int gr = bm + row; gr = gr < M ? gr : M - 1;
            f16* gp = const_cast<f16*>(A) + (size_t)gr * K + k0 + kb;
            __builtin_amdgcn_global_load_lds(
                (__attribute__((address_space(1))) void*)gp,
                (__attribute__((address_space(3))) void*)(&As[buf][i * 2048 + wv * 512]),
                16, 0, 0);
            f16* gq = const_cast<f16*>(Bt) + (size_t)(bn + row) * K + k0 + kb;
            __builtin_amdgcn_global_load_lds(
                (__attribute__((address_space(1))) void*)gq,
                (__attribute__((address_space(3))) void*)(&Bs[buf][i * 2048 + wv * 512]),
                16, 0, 0);
        }
    };

    floatx4 acc[4][4];
#pragma unroll
    for (int m = 0; m < 4; ++m)
#pragma unroll
        for (int n = 0; n < 4; ++n) acc[m][n] = (floatx4)0.f;
    const int r = ln & 15, kc = (ln >> 4) * 8;
    const int wr = (wv >> 1) * 64, wc = (wv & 1) * 64;

    stage(0, 0);
    if (nt > 1) stage(1, 1);
    int buf = 0;
    for (int t = 0; t < nt; ++t) {
        if (t + 1 < nt) { asm volatile("s_waitcnt vmcnt(4)" ::: "memory"); }
        else            { asm volatile("s_waitcnt vmcnt(0)" ::: "memory"); }
        __builtin_amdgcn_s_barrier();
        if (t + 2 < nt) {
            int nb = buf + 2; if (nb >= 3) nb -= 3;
            stage(nb, t + 2);
        }
        half8 af[4], bf[4];
#pragma unroll
        for (int m = 0; m < 4; ++m)
            af[m] = *(const half8*)(&As[buf][(wr + m * 16 + r) * 32 + kc]);
#pragma unroll
        for (int n = 0; n < 4; ++n)
            bf[n] = *(const half8*)(&Bs[buf][(wc + n * 16 + r) * 32 + kc]);
#pragma unroll
        for (int m = 0; m < 4; ++m)
#pragma unroll
            for (int n = 0; n < 4; ++n)
                acc[m][n] = __builtin_amdgcn_mfma_f32_16x16x32_f16(af[m], bf[n], acc[m][n], 0, 0, 0);
        if (++buf >= 3) buf = 0;
    }

    const int C = N / 3;
    const int colbase = bn + wc;
    const int reg = colbase / C;
    const int h = (colbase % C) >> 6;
#pragma unroll
    for (int m = 0; m < 4; ++m) {
        int rbase = bm + wr + m * 16 + ((ln >> 4) << 2);
#pragma unroll
        for (int j = 0; j < 4; ++j) {
            int row = rbase + j;
            if (row >= M) continue;
            int b = row / S, s = row - b * S;
            size_t ob = ((size_t)(b * H + h) * S + s) * 64;
            if (reg == 2) {
#pragma unroll
                for (int n = 0; n < 4; ++n)
                    Fv[ob + n * 16 + (ln & 15)] = (f16)acc[m][n][j];
            } else {
                const float* tb = tab + ((size_t)s << 6);
#pragma unroll
                for (int p = 0; p < 2; ++p) {
                    int i = p * 16 + (ln & 15);
                    float cs = tb[2 * i], sn = tb[2 * i + 1];
                    float x1 = acc[m][p][j], x2 = acc[m][p + 2][j];
                    float o1 = x1 * cs - x2 * sn;
                    float o2 = x2 * cs + x1 * sn;
                    if (reg == 0) {
                        Fq[ob + i]      = (f16)(o1 * 0.125f);
                        Fq[ob + i + 32] = (f16)(o2 * 0.125f);
                    } else {
                        Fk[ob + i]      = (f16)o1;
                        Fk[ob + i + 32] = (f16)o2;
                    }
                }
            }
        }
    }
}

// ---------------- rope table: tab[s][i][2] = (cos, sin) -------------------
__global__ __launch_bounds__(256) void rope_tab(float* __restrict__ tab, int S) {
    int g = blockIdx.x * 256 + threadIdx.x;
    if (g >= S * 32) return;
    int s = g >> 5, i = g & 31;
    float inv = expf(-(float)i * 0.28782313662425575f);
    float sn, cs;
    sincosf((float)s * inv, &sn, &cs);
    tab[2 * g] = cs;
    tab[2 * g + 1] = sn;
}

// ---------------- split-K reduce ------------------------------------------
template<bool HOUT>
__global__ __launch_bounds__(256) void kred(
    const float* __restrict__ P, const float* __restrict__ res,
    void* __restrict__ Cv, size_t mn, int ks) {
    size_t i = ((size_t)blockIdx.x * 256 + threadIdx.x) * 4;
    if (i >= mn) return;
    floatx4 s = res ? *(const floatx4*)(res + i) : (floatx4)0.f;
    for (int z = 0; z < ks; ++z) {
        floatx4 p = *(const floatx4*)(P + (size_t)z * mn + i);
        s += p;
    }
    if (HOUT) {
        half4v h;
#pragma unroll
        for (int j = 0; j < 4; ++j) h[j] = (f16)s[j];
        *(half4v*)((f16*)Cv + i) = h;
    } else {
        *(floatx4*)((float*)Cv + i) = s;
    }
}

// ---------------- split-K GEMV for M=2 ------------------------------------
__global__ __launch_bounds__(256) void gemv2_part(
    const float* __restrict__ A, const float* __restrict__ W,
    float* __restrict__ P, int N, int K) {
    int n = blockIdx.x * 256 + threadIdx.x;
    if (n >= N) return;
    int Kc = K / KSPL;
    int k0 = blockIdx.y * Kc;
    float acc0 = 0.f, acc1 = 0.f;
    const float* Wp = W + (size_t)k0 * N + n;
    const float* a0 = A + k0;
    const float* a1 = A + K + k0;
#pragma unroll 4
    for (int k = 0; k < Kc; ++k) {
        float w = Wp[(size_t)k * N];
        acc0 = fmaf(a0[k], w, acc0);
        acc1 = fmaf(a1[k], w, acc1);
    }
    P[((size_t)blockIdx.y * 2 + 0) * N + n] = acc0;
    P[((size_t)blockIdx.y * 2 + 1) * N + n] = acc1;
}

__global__ __launch_bounds__(256) void gemv2_red(
    const float* __restrict__ P, const float* __restrict__ res,
    float* __restrict__ C, int N) {
    int g = blockIdx.x * 256 + threadIdx.x;
    if (g >= 2 * N) return;
    int m = g / N, n = g - m * N;
    float s = res ? res[g] : 0.f;
#pragma unroll
    for (int ky = 0; ky < KSPL; ++ky)
        s += P[((size_t)ky * 2 + m) * N + n];
    C[g] = s;
}

// ------- layer-batched M=2 GEMV: W[L][K][Nper], out [L][2][Nper] ----------
__global__ __launch_bounds__(256) void gemv2L_part(
    const float* __restrict__ A, const float* __restrict__ W,
    float* __restrict__ P, int Nper, int L, int K) {
    int tot = L * Nper;
    int c = blockIdx.x * 256 + threadIdx.x;
    if (c >= tot) return;
    int l = c / Nper, n = c - l * Nper;
    int Kc = K / KSPL;
    int k0 = blockIdx.y * Kc;
    const float* Wp = W + (size_t)l * K * Nper + (size_t)k0 * Nper + n;
    const float* a0 = A + k0;
    const float* a1 = A + K + k0;
    float acc0 = 0.f, acc1 = 0.f;
#pragma unroll 4
    for (int k = 0; k < Kc; ++k) {
        float w = Wp[(size_t)k * Nper];
        acc0 = fmaf(a0[k], w, acc0);
        acc1 = fmaf(a1[k], w, acc1);
    }
    P[((size_t)blockIdx.y * 2 + 0) * tot + c] = acc0;
    P[((size_t)blockIdx.y * 2 + 1) * tot + c] = acc1;
}

__global__ __launch_bounds__(256) void gemv2L_red(
    const float* __restrict__ P, float* __restrict__ C, int Nper, int L) {
    int tot = L * Nper;
    int g = blockIdx.x * 256 + threadIdx.x;
    if (g >= 2 * tot) return;
    int m = g / tot, cc = g - m * tot;
    float s = 0.f;
#pragma unroll
    for (int ky = 0; ky < KSPL; ++ky)
        s += P[((size_t)ky * 2 + m) * tot + cc];
    int l = cc / Nper, n = cc - l * Nper;
    C[((size_t)l * 2 + m) * Nper + n] = s;
}

// ---------------- norms ----------------
__device__ __forceinline__ void stf(float* p, float v) { *p = v; }
__device__ __forceinline__ void stf(f16* p, float v)   { *p = (f16)v; }

template<typename TO>
__global__ __launch_bounds__(256) void rmsnorm_k(
    const float* __restrict__ X, const float* __restrict__ scale,
    TO* __restrict__ Y, int C, int rows_per_group, float sadd) {
    int row = blockIdx.x, tid = threadIdx.x;
    const float* x = X + (size_t)row * C;
    float v[8];
    int cnt = C >> 8;
    float ss = 0.f;
    for (int i = 0; i < cnt; ++i) { v[i] = x[tid + (i << 8)]; ss += v[i] * v[i]; }
    __shared__ float red[256];
    red[tid] = ss; __syncthreads();
    for (int s2 = 128; s2; s2 >>= 1) { if (tid < s2) red[tid] += red[tid + s2]; __syncthreads(); }
    float inv = rsqrtf(red[0] / (float)C + 1e-6f);
    const float* sc = scale + (size_t)(row / rows_per_group) * C;
    TO* y = Y + (size_t)row * C;
    for (int i = 0; i < cnt; ++i) {
        int c = tid + (i << 8);
        stf(&y[c], v[i] * (sadd + sc[c]) * inv);
    }
}

__global__ __launch_bounds__(256) void layernorm_k(
    const float* __restrict__ X, const float* __restrict__ g,
    const float* __restrict__ bta, f16* __restrict__ Y, int C) {
    int row = blockIdx.x, tid = threadIdx.x;
    const float* x = X + (size_t)row * C;
    float v[8];
    int cnt = C >> 8;
    float s = 0.f;
    for (int i = 0; i < cnt; ++i) { v[i] = x[tid + (i << 8)]; s += v[i]; }
    __shared__ float red[256];
    red[tid] = s; __syncthreads();
    for (int s2 = 128; s2; s2 >>= 1) { if (tid < s2) red[tid] += red[tid + s2]; __syncthreads(); }
    float m = red[0] / (float)C;
    __syncthreads();
    float s2s = 0.f;
    for (int i = 0; i < cnt; ++i) { float d = v[i] - m; s2s += d * d; }
    red[tid] = s2s; __syncthreads();
    for (int s2 = 128; s2; s2 >>= 1) { if (tid < s2) red[tid] += red[tid + s2]; __syncthreads(); }
    float inv = rsqrtf(red[0] / (float)C + 1e-5f);
    f16* y = Y + (size_t)row * C;
    for (int i = 0; i < cnt; ++i) {
        int c = tid + (i << 8);
        y[c] = (f16)((v[i] - m) * inv * g[c] + bta[c]);
    }
}

// ---------------- GLU (f32, tiny mapping path) ----------------
__global__ __launch_bounds__(256) void glu_k(
    const float* __restrict__ U, float* __restrict__ Yo,
    size_t total, int F, int mode) {
    size_t gidx = (size_t)blockIdx.x * 256 + threadIdx.x;
    if (gidx >= total) return;
    size_t r = gidx / (size_t)F;
    int c = (int)(gidx - r * F);
    const float* u = U + r * (size_t)(2 * F);
    float a = u[c], gg = u[F + c];
    float act = (mode == 0) ? gelu_tanh(gg) : gg / (1.f + expf(-gg));
    Yo[gidx] = a * act;
}

// ---------------- V transpose: V[bh][S][64] -> Vt[bh][64][Spad] -----------
__global__ __launch_bounds__(256) void vtrans(
    const f16* __restrict__ V, f16* __restrict__ Vt, int S, int Spad) {
    __shared__ f16 T[64][72];
    const int tid = threadIdx.x;
    const int k0 = blockIdx.x * 64;
    const f16* Vb = V + (size_t)blockIdx.y * S * 64;
    f16* Vtb = Vt + (size_t)blockIdx.y * 64 * Spad;
    for (int c = tid; c < 512; c += 256) {
        int kk = c >> 3, d8 = (c & 7) * 8;
        int kg = k0 + kk; kg = kg < S ? kg : S - 1;
        half8 v = *(const half8*)(Vb + (size_t)kg * 64 + d8);
        if (k0 + kk >= S) {
#pragma unroll
            for (int j = 0; j < 8; ++j) v[j] = (f16)0.f;
        }
        *(half8*)(&T[kk][d8]) = v;
    }
    __syncthreads();
    for (int c = tid; c < 512; c += 256) {
        int d = c >> 3, k8 = (c & 7) * 8;
        half8 o;
#pragma unroll
        for (int j = 0; j < 8; ++j) o[j] = T[k8 + j][d];
        *(half8*)(Vtb + (size_t)d * Spad + k0 + k8) = o;
    }
}

// ---------------- flash attention (MF q-frags/wave; direct or split-KV) ---
// MF=1: 64 q/block. MF=2: 128 q/block. DIRECT: write normalized O (nz==1).
template<int MF, bool DIRECT>
__global__ __launch_bounds__(256) void fattn(
    const f16* __restrict__ Q, const f16* __restrict__ K,
    const f16* __restrict__ Vt, float* __restrict__ Op,
    float* __restrict__ Mst, float* __restrict__ Lst, f16* __restrict__ O,
    int S, int Spad, int H, int win, int QR) {
    __shared__ __align__(16) f16 Ks[64][72];
    __shared__ __align__(16) f16 Vs[64][72];
    __shared__ __align__(16) f16 Ps[4][32][72];
    const int tid = threadIdx.x;
    const int wv = tid >> 6, ln = tid & 63;
    const int r15 = ln & 15, g = ln >> 4;
    const int bh = blockIdx.y;
    const int NBH = gridDim.y;
    const int z = blockIdx.z, nz = gridDim.z;
    const int q0 = (int)blockIdx.x * (MF * 64);
    const f16* Qb = Q + (size_t)bh * S * 64;
    const f16* Kb = K + (size_t)bh * S * 64;
    const f16* Vtb = Vt + (size_t)bh * 64 * Spad;

    half8 aq[MF][2];
#pragma unroll
    for (int m = 0; m < MF; ++m) {
        int q = q0 + wv * (MF * 16) + m * 16 + r15;
        q = q < S ? q : S - 1;
#pragma unroll
        for (int ks = 0; ks < 2; ++ks)
            aq[m][ks] = *(const half8*)(Qb + (size_t)q * 64 + ks * 32 + g * 8);
    }
    floatx4 o[MF][4];
#pragma unroll
    for (int m = 0; m < MF; ++m)
#pragma unroll
        for (int n = 0; n < 4; ++n) o[m][n] = (floatx4)0.f;
    float mst[MF][4], lst[MF][4];
#pragma unroll
    for (int m = 0; m < MF; ++m)
#pragma unroll
        for (int j = 0; j < 4; ++j) { mst[m][j] = -3.0e38f; lst[m][j] = 0.f; }

    int klo = 0, khi = S;
    if (win) {
        int wb = q0 >> 7;                  // window block of 128 q rows
        klo = (wb - 1) * win; if (klo < 0) klo = 0;
        khi = (wb + 2) * win; if (khi > S) khi = S;
    }
    int ntile = (khi - klo + 63) >> 6;
    int chunk = (ntile + nz - 1) / nz;
    int myLo = klo + z * chunk * 64;
    int myHi = klo + (z + 1) * chunk * 64; if (myHi > khi) myHi = khi;

    for (int kb = myLo; kb < myHi; kb += 64) {
        __syncthreads();
#pragma unroll
        for (int i = 0; i < 2; ++i) {
            int c = tid + i * 256;
            int rr = c >> 3, c8 = (c & 7) * 8;
            int kg = kb + rr; kg = kg < S ? kg : S - 1;
            *(half8*)(&Ks[rr][c8]) = *(const half8*)(Kb + (size_t)kg * 64 + c8);
            *(half8*)(&Vs[rr][c8]) = *(const half8*)(Vtb + (size_t)rr * Spad + kb + c8);
        }
        __syncthreads();
        floatx4 s[MF][4];
#pragma unroll
        for (int m = 0; m < MF; ++m)
#pragma unroll
            for (int n = 0; n < 4; ++n) s[m][n] = (floatx4)0.f;
        __builtin_amdgcn_s_setprio(1);
#pragma unroll
        for (int ks = 0; ks < 2; ++ks) {
            half8 bk[4];
#pragma unroll
            for (int n = 0; n < 4; ++n)
                bk[n] = *(const half8*)(&Ks[n * 16 + r15][ks * 32 + g * 8]);
#pragma unroll
            for (int m = 0; m < MF; ++m)
#pragma unroll
                for (int n = 0; n < 4; ++n)
                    s[m][n] = __builtin_amdgcn_mfma_f32_16x16x32_f16(aq[m][ks], bk[n], s[m][n], 0, 0, 0);
        }
        __builtin_amdgcn_s_setprio(0);
        if (kb + 64 > S) {
#pragma unroll
            for (int n = 0; n < 4; ++n)
                if (kb + n * 16 + r15 >= S) {
#pragma unroll
                    for (int m = 0; m < MF; ++m) s[m][n] = (floatx4)(-3.0e38f);
                }
        }
#pragma unroll
        for (int m = 0; m < MF; ++m) {
#pragma unroll
            for (int j = 0; j < 4; ++j) {
                float tm = fmaxf(fmaxf(s[m][0][j], s[m][1][j]), fmaxf(s[m][2][j], s[m][3][j]));
                tm = fmaxf(tm, __shfl_xor(tm, 1));
                tm = fmaxf(tm, __shfl_xor(tm, 2));
                tm = fmaxf(tm, __shfl_xor(tm, 4));
                tm = fmaxf(tm, __shfl_xor(tm, 8));
                float mn = fmaxf(mst[m][j], tm);
                float sc = __expf(mst[m][j] - mn);
                mst[m][j] = mn;
                float ts = 0.f;
#pragma unroll
                for (int n = 0; n < 4; ++n) {
                    float p = __expf(s[m][n][j] - mn);
                    s[m][n][j] = p;
                    ts += p;
                }
                ts += __shfl_xor(ts, 1);
                ts += __shfl_xor(ts, 2);
                ts += __shfl_xor(ts, 4);
                ts += __shfl_xor(ts, 8);
                lst[m][j] = lst[m][j] * sc + ts;
#pragma unroll
                for (int n = 0; n < 4; ++n) o[m][n][j] *= sc;
            }
        }
#pragma unroll
        for (int m = 0; m < MF; ++m)
#pragma unroll
            for (int n = 0; n < 4; ++n)
#pragma unroll
                for (int j = 0; j < 4; ++j)
                    Ps[wv][m * 16 + g * 4 + j][n * 16 + r15] = (f16)s[m][n][j];
        __builtin_amdgcn_s_setprio(1);
#pragma unroll
        for (int ks = 0; ks < 2; ++ks) {
            half8 pa[MF], bv[4];
#pragma unroll
            for (int m = 0; m < MF; ++m)
                pa[m] = *(const half8*)(&Ps[wv][m * 16 + r15][ks * 32 + g * 8]);
#pragma unroll
            for (int n = 0; n < 4; ++n)
                bv[n] = *(const half8*)(&Vs[n * 16 + r15][ks * 32 + g * 8]);
#pragma unroll
            for (int m = 0; m < MF; ++m)
#pragma unroll
                for (int n = 0; n < 4; ++n)
                    o[m][n] = __builtin_amdgcn_mfma_f32_16x16x32_f16(pa[m], bv[n], o[m][n], 0, 0, 0);
        }
        __builtin_amdgcn_s_setprio(0);
    }
    if (DIRECT) {
        const int HC = H * 64;
        const int b = bh / H, h = bh % H;
#pragma unroll
        for (int m = 0; m < MF; ++m)
#pragma unroll
            for (int j = 0; j < 4; ++j) {
                int q = q0 + wv * (MF * 16) + m * 16 + g * 4 + j;
                if (q < S) {
                    float inv = 1.f / lst[m][j];
                    size_t ro = ((size_t)b * S + q) * HC + h * 64;
#pragma unroll
                    for (int n = 0; n < 4; ++n)
                        O[ro + n * 16 + r15] = (f16)(o[m][n][j] * inv);
                }
            }
    } else {
        size_t zb = ((size_t)z * NBH + bh) * QR;
#pragma unroll
        for (int m = 0; m < MF; ++m)
#pragma unroll
            for (int j = 0; j < 4; ++j) {
                int qr = q0 + wv * (MF * 16) + m * 16 + g * 4 + j;
                size_t ro = (zb + qr) * 64;
#pragma unroll
                for (int n = 0; n < 4; ++n)
                    Op[ro + n * 16 + r15] = o[m][n][j];
                if (r15 == 0) {
                    Mst[zb + qr] = mst[m][j];
                    Lst[zb + qr] = lst[m][j];
                }
            }
    }
}

// ---------------- flash combine -------------------------------------------
__global__ __launch_bounds__(256) void fcomb(
    const float* __restrict__ Op, const float* __restrict__ Mst,
    const float* __restrict__ Lst, f16* __restrict__ O,
    int S, int H, int QR, int nz, int rows) {
    int g = blockIdx.x * 256 + threadIdx.x;
    int idx = g >> 4;
    int d4 = (g & 15) * 4;
    if (idx >= rows) return;
    int bh = idx / QR, q = idx - bh * QR;
    if (q >= S) return;
    float mstar = -3.0e38f;
    for (int z = 0; z < nz; ++z)
        mstar = fmaxf(mstar, Mst[(size_t)z * rows + idx]);
    float den = 0.f;
    floatx4 num = (floatx4)0.f;
    for (int z = 0; z < nz; ++z) {
        float w = __expf(Mst[(size_t)z * rows + idx] - mstar);
        den += w * Lst[(size_t)z * rows + idx];
        floatx4 ov = *(const floatx4*)(Op + ((size_t)z * rows + idx) * 64 + d4);
        num += w * ov;
    }
    float inv = 1.f / den;
    int b = bh / H, h = bh % H;
    f16* op = O + ((size_t)b * S + q) * (H * 64) + h * 64 + d4;
    half4v hv;
#pragma unroll
    for (int j = 0; j < 4; ++j) hv[j] = (f16)(num[j] * inv);
    *(half4v*)op = hv;
}

// ---------------- small glue kernels ----------------
__global__ __launch_bounds__(256) void patch_in_gather(
    const float* __restrict__ x, f16* __restrict__ out) {
    int g = blockIdx.x * 256 + threadIdx.x;
    if (g >= BB * S0 * 128) return;
    int k = g & 127;
    int n = (g >> 7) & (S0 - 1);
    int b = g >> 18;
    out[g] = (f16)x[(size_t)b * CIO * TT + (size_t)(k >> 1) * TT + 2 * n + (k & 1)];
}

__global__ __launch_bounds__(256) void time_embed(
    const float* __restrict__ t, const float* __restrict__ tw,
    float* __restrict__ te) {
    int g = blockIdx.x * 256 + threadIdx.x;
    if (g >= BB * MAPD) return;
    int b = g / MAPD, j = g % MAPD;
    float w = tw[(j < 512) ? j : j - 512];
    float ang = 6.283185307179586f * t[b] * w;
    te[g] = (j < 512) ? cosf(ang) : sinf(ang);
}

__global__ __launch_bounds__(256) void token_merge_gather(
    const float* __restrict__ A, f16* __restrict__ out) {
    int g = blockIdx.x * 256 + threadIdx.x;
    if (g >= BB * 1024 * 1024) return;
    int k = g & 1023;
    int n = (g >> 10) & 1023;
    int b = g >> 20;
    out[g] = (f16)A[((size_t)b * S0 + 2 * n + (k & 1)) * W0 + (k >> 1)];
}

__global__ __launch_bounds__(256) void concat_mid(
    const float* __restrict__ pre, const float* __restrict__ Dsrc,
    float* __restrict__ Cm) {
    int g = blockIdx.x * 256 + threadIdx.x;
    if (g >= BB * SM * W1) return;
    int c = g & 1023;
    int row = g >> 10;
    int b = row / SM, r = row % SM;
    Cm[g] = (r == 0) ? pre[b * W1 + c]
                     : Dsrc[((size_t)b * 1024 + r - 1) * W1 + c];
}

__global__ __launch_bounds__(256) void gather_drop(
    const f16* __restrict__ Dsrc, f16* __restrict__ out) {
    int g = blockIdx.x * 256 + threadIdx.x;
    if (g >= BB * 1024 * W1) return;
    int c = g & 1023;
    int n = (g >> 10) & 1023;
    int b = g >> 20;
    out[g] = Dsrc[((size_t)b * SM + 1 + n) * W1 + c];
}

__global__ __launch_bounds__(256) void split_scatter_lerp(
    const float* __restrict__ y, const float* __restrict__ skip,
    const float* __restrict__ fac, float* __restrict__ xo) {
    int g = blockIdx.x * 256 + threadIdx.x;
    if (g >= BB * S0 * W0) return;
    int c = g & 511;
    int tk = (g >> 9) & (S0 - 1);
    int b = g >> 20;
    float yv = y[((size_t)b * 1024 + (tk >> 1)) * W1 + (c * 2 + (tk & 1))];
    float sk = skip[g];
    xo[g] = sk + fac[0] * (yv - sk);
}

__global__ __launch_bounds__(256) void patch_out_scatter(
    const float* __restrict__ y, float* __restrict__ out) {
    int g = blockIdx.x * 256 + threadIdx.x;
    if (g >= BB * CIO * TT) return;
    int tk = g & (TT - 1);
    int c = (g >> 12) & 63;
    int b = g >> 18;
    out[g] = y[((size_t)b * S0 + (tk >> 1)) * 128 + (c * 2 + (tk & 1))];
}

// ---------------- host orchestration ----------------
extern "C" void kernel_launch(void* const* d_in, const int* in_sizes, int n_in,
                              void* d_out, int out_size, void* d_ws, size_t ws_size,
                              hipStream_t stream) {
    const float* x          = (const float*)d_in[0];
    const float* t          = (const float*)d_in[1];
    const float* time_w     = (const float*)d_in[2];
    const float* time_in_w  = (const float*)d_in[3];
    const float* map_in_s   = (const float*)d_in[4];
    const float* map_norm_s = (const float*)d_in[5];
    const float* map_up_w   = (const float*)d_in[6];
    const float* map_down_w = (const float*)d_in[7];
    const float* map_out_s  = (const float*)d_in[8];
    const float* patch_in_w = (const float*)d_in[9];
    const float* dn_anorm_w = (const float*)d_in[10];
    const float* dn_qkv_w   = (const float*)d_in[11];
    const float* dn_o_w     = (const float*)d_in[12];
    const float* dn_fnorm_w = (const float*)d_in[13];
    const float* dn_ff1_w   = (const float*)d_in[14];
    const float* dn_ff2_w   = (const float*)d_in[15];
    const float* merge_w    = (const float*)d_in[16];
    const float* mid_map_w  = (const float*)d_in[17];
    const float* mid_pin_w  = (const float*)d_in[18];
    const float* mid_pout_w = (const float*)d_in[19];
    const float* mid_ln1_g  = (const float*)d_in[20];
    const float* mid_ln1_b  = (const float*)d_in[21];
    const float* mid_qkv_w  = (const float*)d_in[22];
    const float* mid_o_w    = (const float*)d_in[23];
    const float* mid_ln2_g  = (const float*)d_in[24];
    const float* mid_ln2_b  = (const float*)d_in[25];
    const float* mid_ff1_w  = (const float*)d_in[26];
    const float* mid_ff2_w  = (const float*)d_in[27];
    const float* mid_fn_g   = (const float*)d_in[28];
    const float* mid_fn_b   = (const float*)d_in[29];
    const float* split_w    = (const float*)d_in[30];
    const float* split_fac  = (const float*)d_in[31];
    const float* up_anorm_w = (const float*)d_in[32];
    const float* up_qkv_w   = (const float*)d_in[33];
    const float* up_o_w     = (const float*)d_in[34];
    const float* up_fnorm_w = (const float*)d_in[35];
    const float* up_ff1_w   = (const float*)d_in[36];
    const float* up_ff2_w   = (const float*)d_in[37];
    const float* out_norm_s = (const float*)d_in[38];
    const float* patch_out_w= (const float*)d_in[39];

    float* Wp = (float*)d_ws;
    size_t off = 0;
    auto alloc = [&](size_t n) { float* p = Wp + off; off += n; return p; };
    float* A    = alloc((size_t)4096 * 512);
    float* Bsk  = alloc((size_t)4096 * 512);
    float* Cm   = alloc((size_t)2050 * 1024);
    float* Df   = alloc((size_t)2050 * 1024);
    f16*  Fq    = (f16*)alloc((size_t)1049600);
    f16*  Fk    = (f16*)alloc((size_t)1049600);
    f16*  Fv    = (f16*)alloc((size_t)1049600);
    f16*  Fvt   = (f16*)alloc((size_t)1114112);
    f16*  H1    = (f16*)alloc((size_t)8396800);
    f16*  H2    = (f16*)alloc((size_t)4198400);
    f16*  Wh    = (f16*)alloc((size_t)4194304);
    float* Pk   = alloc((size_t)PKCAP);
    float* ML   = alloc((size_t)262144);
    float* Pb   = alloc((size_t)KSPL * 2 * 2048);
    float* tabL = alloc((size_t)S0 * 64);
    float* tabM = alloc((size_t)SM * 64);
    float* Sma  = alloc((size_t)32768);
    (void)ws_size; (void)in_sizes; (void)n_in; (void)out_size;

    float* te   = Sma;
    float* temb = Sma + 2048;
    float* mapx = Sma + 4096;
    float* maph = Sma + 6144;
    float* mapu = Sma + 8192;
    float* mapg = Sma + 12288;
    float* cond = Sma + 14336;
    float* pre  = Sma + 18432;
    float* sAdn = Sma + 20480;   // [2][2][512]
    float* sFdn = Sma + 22528;
    float* sAup = Sma + 24576;
    float* sFup = Sma + 26624;

    auto WC = [&](const float* W, int K, int N) {
        wcast<<<dim3(N / 64, K / 64), 256, 0, stream>>>(W, Wh, K, N);
    };
    auto WCG = [&](const float* W, int K, int N2) {
        wcast_glu<<<dim3(N2 / 64, K / 64), 256, 0, stream>>>(W, Wh, K, N2);
    };
    auto pick_ks = [](int M, int N, int K) {
        long gx = N / 128, gy = (M + 127) / 128;
        int ks = 1;
        while (gx * gy * ks < 512 && ks < 8) {
            int nk = ks * 2;
            if ((K / nk) % 32 != 0 || (long)M * N * nk > PKCAP) break;
            ks = nk;
        }
        return ks;
    };
    auto GF = [&](const f16* Aa, const float* res, float* C, int M, int N, int K) {
        int ks = pick_ks(M, N, K);
        dim3 g(N / 128, (M + 127) / 128, ks);
        if (ks == 1) {
            gemm_h<0><<<g, 256, 0, stream>>>(Aa, Wh, res, C, M, N, K, 0);
        } else {
            gemm_h<2><<<g, 256, 0, stream>>>(Aa, Wh, nullptr, Pk, M, N, K, 0);
            size_t mn = (size_t)M * N;
            kred<false><<<(int)((mn / 4 + 255) / 256), 256, 0, stream>>>(Pk, res, C, mn, ks);
        }
    };
    auto GH = [&](const f16* Aa, f16* C, int M, int N, int K) {
        int ks = pick_ks(M, N, K);
        dim3 g(N / 128, (M + 127) / 128, ks);
        if (ks == 1) {
            gemm_h<1><<<g, 256, 0, stream>>>(Aa, Wh, nullptr, C, M, N, K, 0);
        } else {
            gemm_h<2><<<g, 256, 0, stream>>>(Aa, Wh, nullptr, Pk, M, N, K, 0);
            size_t mn = (size_t)M * N;
            kred<true><<<(int)((mn / 4 + 255) / 256), 256, 0, stream>>>(Pk, nullptr, C, mn, ks);
        }
    };
    // fused GLU FF1: N2 = 2F cols of reordered weight, writes F cols f16
    auto GGLU = [&](const f16* Aa, f16* C, int M, int N2, int K, int mode) {
        dim3 g(N2 / 128, (M + 127) / 128);
        gemm_h<3><<<g, 256, 0, stream>>>(Aa, Wh, nullptr, C, M, N2, K, mode);
    };
    auto GQKV = [&](const f16* Aa, const float* tab, int M, int N, int K, int S, int H) {
        dim3 g(N / 128, (M + 127) / 128);
        gemm_qkv<<<g, 256, 0, stream>>>(Aa, Wh, tab, Fq, Fk, Fv, M, N, K, S, H);
    };
    auto gemv2 = [&](const float* Aa, const float* W, const float* res,
                     float* C, int N, int K) {
        gemv2_part<<<dim3((N + 255) / 256, KSPL), 256, 0, stream>>>(Aa, W, Pb, N, K);
        gemv2_red<<<(2 * N + 255) / 256, 256, 0, stream>>>(Pb, res, C, N);
    };
    auto gemv2L = [&](const float* Aa, const float* W, float* C, int Nper, int L, int K) {
        int tot = L * Nper;
        gemv2L_part<<<dim3((tot + 255) / 256, KSPL), 256, 0, stream>>>(Aa, W, Pb, Nper, L, K);
        gemv2L_red<<<(2 * tot + 255) / 256, 256, 0, stream>>>(Pb, C, Nper, L);
    };

    // ---- rope tables (once) ----
    rope_tab<<<(S0 * 32 + 255) / 256, 256, 0, stream>>>(tabL, S0);
    rope_tab<<<(SM * 32 + 255) / 256, 256, 0, stream>>>(tabM, SM);

    // ---- patch in ----
    patch_in_gather<<<(BB * S0 * 128 + 255) / 256, 256, 0, stream>>>(x, H2);
    WC(patch_in_w, 128, 512);
    GF(H2, nullptr, A, 4096, 512, 128);

    // ---- time embedding + mapping (tiny, f32) ----
    time_embed<<<(BB * MAPD + 255) / 256, 256, 0, stream>>>(t, time_w, te);
    gemv2(te, time_in_w, nullptr, temb, 1024, 1024);
    rmsnorm_k<float><<<2, 256, 0, stream>>>(temb, map_in_s, mapx, 1024, 2, 0.f);
    for (int l = 0; l < 2; ++l) {
        rmsnorm_k<float><<<2, 256, 0, stream>>>(mapx, map_norm_s + (size_t)l * 1024, maph, 1024, 2, 0.f);
        gemv2(maph, map_up_w + (size_t)l * 1024 * 2048, nullptr, mapu, 2048, 1024);
        glu_k<<<(2 * 1024 + 255) / 256, 256, 0, stream>>>(mapu, mapg, 2 * 1024, 1024, 0);
        gemv2(mapg, map_down_w + (size_t)l * 1024 * 1024, mapx, mapx, 1024, 1024);
    }
    rmsnorm_k<float><<<2, 256, 0, stream>>>(mapx, map_out_s, cond, 1024, 2, 0.f);

    // ---- all cond projections (batched, once) ----
    gemv2L(cond, dn_anorm_w, sAdn, 512, 2, 1024);
    gemv2L(cond, dn_fnorm_w, sFdn, 512, 2, 1024);
    gemv2L(cond, up_anorm_w, sAup, 512, 2, 1024);
    gemv2L(cond, up_fnorm_w, sFup, 512, 2, 1024);
    gemv2L(cond, mid_map_w,  pre, 1024, 1, 1024);

    // ---- local level (shared for down/up) ----
    auto run_local = [&](const float* qkvw, const float* ow,
                         const float* ff1, const float* ff2,
                         const float* sAall, const float* sFall) {
        for (int l = 0; l < 2; ++l) {
            rmsnorm_k<f16><<<4096, 256, 0, stream>>>(A, sAall + (size_t)l * 1024, H2, 512, 2048, 1.f);
            WC(qkvw + (size_t)l * 512 * 1536, 512, 1536);
            GQKV(H2, tabL, 4096, 1536, 512, S0, HDN);
            vtrans<<<dim3(S0 / 64, BB * HDN), 256, 0, stream>>>(Fv, Fvt, S0, S0);
            fattn<1, true><<<dim3(S0 / 64, BB * HDN, 1), 256, 0, stream>>>(
                Fq, Fk, Fvt, nullptr, nullptr, nullptr, H2, S0, S0, HDN, WIN, 0);
            WC(ow + (size_t)l * 512 * 512, 512, 512);
            GF(H2, A, A, 4096, 512, 512);
            rmsnorm_k<f16><<<4096, 256, 0, stream>>>(A, sFall + (size_t)l * 1024, H2, 512, 2048, 1.f);
            WCG(ff1 + (size_t)l * 512 * 2048, 512, 2048);
            GGLU(H2, H1, 4096, 2048, 512, 0);
            WC(ff2 + (size_t)l * 1024 * 512, 1024, 512);
            GF(H1, A, A, 4096, 512, 1024);
        }
    };
    run_local(dn_qkv_w, dn_o_w, dn_ff1_w, dn_ff2_w, sAdn, sFdn);

    // ---- skip save, merge, mid prep ----
    hipMemcpyAsync(Bsk, A, (size_t)4096 * 512 * 4, hipMemcpyDeviceToDevice, stream);
    token_merge_gather<<<(BB * 1024 * 1024 + 255) / 256, 256, 0, stream>>>(A, H2);
    WC(merge_w, 1024, 1024);
    GH(H2, H1, 2048, 1024, 1024);
    WC(mid_pin_w, 1024, 1024);
    GF(H1, nullptr, Df, 2048, 1024, 1024);
    concat_mid<<<(BB * SM * W1 + 255) / 256, 256, 0, stream>>>(pre, Df, Cm);

    // ---- mid level ----
    for (int l = 0; l < 4; ++l) {
        layernorm_k<<<2050, 256, 0, stream>>>(Cm, mid_ln1_g + (size_t)l * 1024,
                                              mid_ln1_b + (size_t)l * 1024, H2, 1024);
        WC(mid_qkv_w + (size_t)l * 1024 * 3072, 1024, 3072);
        GQKV(H2, tabM, 2050, 3072, 1024, SM, HMID);
        vtrans<<<dim3(SMP / 64, BB * HMID), 256, 0, stream>>>(Fv, Fvt, SM, SMP);
        {
            int QR = 9 * 128, rows = BB * HMID * QR, nz = 3;
            fattn<2, false><<<dim3(9, BB * HMID, nz), 256, 0, stream>>>(
                Fq, Fk, Fvt, Pk, ML, ML + (size_t)nz * rows, nullptr, SM, SMP, HMID, 0, QR);
            fcomb<<<(rows * 16 + 255) / 256, 256, 0, stream>>>(
                Pk, ML, ML + (size_t)nz * rows, H2, SM, HMID, QR, nz, rows);
        }
        WC(mid_o_w + (size_t)l * 1024 * 1024, 1024, 1024);
        GF(H2, Cm, Cm, 2050, 1024, 1024);
        layernorm_k<<<2050, 256, 0, stream>>>(Cm, mid_ln2_g + (size_t)l * 1024,
                                              mid_ln2_b + (size_t)l * 1024, H2, 1024);
        WCG(mid_ff1_w + (size_t)l * 1024 * 8192, 1024, 8192);
        GGLU(H2, H1, 2050, 8192, 1024, 1);
        WC(mid_ff2_w + (size_t)l * 4096 * 1024, 4096, 1024);
        GF(H1, Cm, Cm, 2050, 1024, 4096);
    }
    layernorm_k<<<2050, 256, 0, stream>>>(Cm, mid_fn_g, mid_fn_b, H2, 1024);

    // ---- pout + token split + lerp skip ----
    WC(mid_pout_w, 1024, 1024);
    GH(H2, H1, 2050, 1024, 1024);
    gather_drop<<<(BB * 1024 * W1 + 255) / 256, 256, 0, stream>>>(H1, H2);
    WC(split_w, 1024, 1024);
    GF(H2, nullptr, Df, 2048, 1024, 1024);
    split_scatter_lerp<<<(BB * S0 * W0 + 255) / 256, 256, 0, stream>>>(Df, Bsk, split_fac, A);

    // ---- up level ----
    run_local(up_qkv_w, up_o_w, up_ff1_w, up_ff2_w, sAup, sFup);

    // ---- out ----
    rmsnorm_k<f16><<<4096, 256, 0, stream>>>(A, out_norm_s, H2, 512, 4096, 0.f);
    WC(patch_out_w, 512, 128);
    GF(H2, nullptr, Df, 4096, 128, 512);
    patch_out_scatter<<<(BB * CIO * TT + 255) / 256, 256, 0, stream>>>(Df, (float*)d_out);
}